// Round 1
// baseline (3493.028 us; speedup 1.0000x reference)
//
#include <hip/hip_runtime.h>
#include <hip/hip_bf16.h>
#include <math.h>

#define NB 4
#define NN 1500
#define KNB 30
#define H 128
#define DH 32
#define NHEADS 4
#define FFH 512
#define NODE_FEAT 1024
#define NROWS (NB*NN)
#define LN_EPS 1e-6f

// ---------------------------------------------------------------- topk
__global__ __launch_bounds__(256) void topk_kernel(
    const float* __restrict__ X, const float* __restrict__ mask,
    int* __restrict__ E_idx, float* __restrict__ D_nb)
{
    int row = blockIdx.x;            // b*NN + i
    int b = row / NN;
    int t = threadIdx.x;
    __shared__ float d_adj[NN];
    __shared__ float red_v[256];
    __shared__ int   red_i[256];

    float xi0 = X[row*3+0], xi1 = X[row*3+1], xi2 = X[row*3+2];
    float mi = mask[row];

    // pass 1: masked distances + row max
    float lmax = -1e30f;
    for (int j = t; j < NN; j += 256) {
        float dx = xi0 - X[(b*NN+j)*3+0];
        float dy = xi1 - X[(b*NN+j)*3+1];
        float dz = xi2 - X[(b*NN+j)*3+2];
        float d  = sqrtf(dx*dx + dy*dy + dz*dz + 1e-6f);
        float m2 = mi * mask[b*NN+j];
        float dm = m2 * d;
        d_adj[j] = dm;
        lmax = fmaxf(lmax, dm);
    }
    red_v[t] = lmax;
    __syncthreads();
    for (int s = 128; s > 0; s >>= 1) {
        if (t < s) red_v[t] = fmaxf(red_v[t], red_v[t+s]);
        __syncthreads();
    }
    float rowmax = red_v[0];
    __syncthreads();

    // pass 2: D_adj = D + (1-m2)*rowmax
    for (int j = t; j < NN; j += 256) {
        float m2 = mi * mask[b*NN+j];
        d_adj[j] = d_adj[j] + (1.0f - m2) * rowmax;
    }
    __syncthreads();

    // iterative selection of 30 smallest (tie -> lower index)
    for (int kk = 0; kk < KNB; kk++) {
        float bv = 1e30f; int bi = NN;
        for (int j = t; j < NN; j += 256) {
            float v = d_adj[j];
            if (v < bv || (v == bv && j < bi)) { bv = v; bi = j; }
        }
        red_v[t] = bv; red_i[t] = bi;
        __syncthreads();
        for (int s = 128; s > 0; s >>= 1) {
            if (t < s) {
                float v2 = red_v[t+s]; int i2 = red_i[t+s];
                if (v2 < red_v[t] || (v2 == red_v[t] && i2 < red_i[t])) {
                    red_v[t] = v2; red_i[t] = i2;
                }
            }
            __syncthreads();
        }
        if (t == 0) {
            int sel = red_i[0];
            E_idx[row*KNB+kk] = sel;
            D_nb[row*KNB+kk]  = red_v[0];
            d_adj[sel] = 1e30f;
        }
        __syncthreads();
    }
}

// ---------------------------------------------------------------- edge features -> h_E (bf16)
__global__ __launch_bounds__(128) void edge_kernel(
    const int* __restrict__ E_idx, const float* __restrict__ D_nb,
    const float* __restrict__ W_edge, const float* __restrict__ ln_g,
    const float* __restrict__ ln_b, const float* __restrict__ W_e,
    const float* __restrict__ b_e, __hip_bfloat16* __restrict__ h_E)
{
    int node = blockIdx.x;
    int i = node % NN;
    int t = threadIdx.x;             // 128 threads, t = output channel
    __shared__ float feat[KNB*32];   // [k][f]
    __shared__ float eall[KNB*132];  // [k][c], pitch 132 (16B aligned rows)
    __shared__ float mu_s[KNB], rs_s[KNB];

    // 32 features per edge: 8 cos, 8 sin, 16 rbf
    for (int q = t; q < KNB*32; q += 128) {
        int k = q >> 5, f = q & 31;
        int e = node*KNB + k;
        float val;
        if (f < 16) {
            int ff = f & 7;
            float drel = (float)E_idx[e] - (float)i;
            float fr = expf(-(float)ff * 1.15129254649702284f); // 2*ln(1e4)/16 * ff
            float ang = drel * fr;
            val = (f < 8) ? cosf(ang) : sinf(ang);
        } else {
            float mu = (20.0f/15.0f) * (float)(f-16);
            float z = (D_nb[e] - mu) * 0.8f;   // / 1.25
            val = expf(-z*z);
        }
        feat[q] = val;
    }
    __syncthreads();

    // E = feat @ W_edge (32 -> 128)
    float acc[KNB];
#pragma unroll
    for (int k = 0; k < KNB; k++) acc[k] = 0.f;
    for (int p = 0; p < 32; p += 4) {
        float w0 = W_edge[(p+0)*H+t];
        float w1 = W_edge[(p+1)*H+t];
        float w2 = W_edge[(p+2)*H+t];
        float w3 = W_edge[(p+3)*H+t];
#pragma unroll
        for (int k = 0; k < KNB; k++) {
            float4 f4 = *(const float4*)&feat[k*32+p];
            acc[k] += f4.x*w0 + f4.y*w1 + f4.z*w2 + f4.w*w3;
        }
    }
#pragma unroll
    for (int k = 0; k < KNB; k++) eall[k*132+t] = acc[k];
    __syncthreads();

    // LN stats, one row per thread (t<30)
    if (t < KNB) {
        float s = 0.f;
        for (int c = 0; c < H; c++) s += eall[t*132+c];
        float mu = s * (1.0f/H);
        float v = 0.f;
        for (int c = 0; c < H; c++) { float d = eall[t*132+c] - mu; v += d*d; }
        mu_s[t] = mu;
        rs_s[t] = rsqrtf(v*(1.0f/H) + LN_EPS);
    }
    __syncthreads();
    float g = ln_g[t], bb = ln_b[t];
#pragma unroll
    for (int k = 0; k < KNB; k++)
        eall[k*132+t] = g*(eall[k*132+t]-mu_s[k])*rs_s[k] + bb;
    __syncthreads();

    // h_E = E_ln @ W_e + b_e (128 -> 128)
    float be = b_e[t];
    float acc2[KNB];
#pragma unroll
    for (int k = 0; k < KNB; k++) acc2[k] = be;
    for (int p = 0; p < H; p += 4) {
        float w0 = W_e[(p+0)*H+t];
        float w1 = W_e[(p+1)*H+t];
        float w2 = W_e[(p+2)*H+t];
        float w3 = W_e[(p+3)*H+t];
#pragma unroll
        for (int k = 0; k < KNB; k++) {
            float4 f4 = *(const float4*)&eall[k*132+p];
            acc2[k] += f4.x*w0 + f4.y*w1 + f4.z*w2 + f4.w*w3;
        }
    }
    for (int k = 0; k < KNB; k++)
        h_E[(node*KNB+k)*H+t] = __float2bfloat16(acc2[k]);
}

// ---------------------------------------------------------------- h_V = V @ W_v + b_v
__global__ __launch_bounds__(128) void hv_init_kernel(
    const float* __restrict__ V, const float* __restrict__ W_v,
    const float* __restrict__ b_v, float* __restrict__ hv)
{
    int row0 = blockIdx.x * 8;
    int t = threadIdx.x;
    __shared__ float vs[8*NODE_FEAT];
    for (int q = t; q < 8*NODE_FEAT; q += 128) vs[q] = V[row0*NODE_FEAT + q];
    __syncthreads();
    float acc[8];
#pragma unroll
    for (int r = 0; r < 8; r++) acc[r] = 0.f;
    for (int p = 0; p < NODE_FEAT; p += 4) {
        float w0 = W_v[(p+0)*H+t];
        float w1 = W_v[(p+1)*H+t];
        float w2 = W_v[(p+2)*H+t];
        float w3 = W_v[(p+3)*H+t];
#pragma unroll
        for (int r = 0; r < 8; r++) {
            float4 v4 = *(const float4*)&vs[r*NODE_FEAT+p];
            acc[r] += v4.x*w0 + v4.y*w1 + v4.z*w2 + v4.w*w3;
        }
    }
    float bv = b_v[t];
#pragma unroll
    for (int r = 0; r < 8; r++) hv[(row0+r)*H+t] = acc[r] + bv;
}

// ---------------------------------------------------------------- block-wide sum (256 threads)
__device__ __forceinline__ float block_sum256(float* red, float v, int t)
{
    red[t] = v;
    __syncthreads();
#pragma unroll
    for (int s = 128; s > 0; s >>= 1) {
        if (t < s) red[t] += red[t+s];
        __syncthreads();
    }
    float r = red[0];
    __syncthreads();
    return r;
}

// ---------------------------------------------------------------- one transformer layer, one block per node
__global__ __launch_bounds__(256) void layer_kernel(
    const float* __restrict__ hv_in, float* __restrict__ hv_out,
    const __hip_bfloat16* __restrict__ h_E, const int* __restrict__ E_idx,
    const float* __restrict__ mask,
    const float* __restrict__ Wq, const float* __restrict__ Wk,
    const float* __restrict__ Wv, const float* __restrict__ Wo,
    const float* __restrict__ ln1g, const float* __restrict__ ln1b,
    const float* __restrict__ ln2g, const float* __restrict__ ln2b,
    const float* __restrict__ Wf1, const float* __restrict__ bf1,
    const float* __restrict__ Wf2, const float* __restrict__ bf2)
{
    int node = blockIdx.x;
    int b = node / NN;
    int t = threadIdx.x;

    __shared__ float sm[16180];          // 64,720 B
    float* X_all = sm;                   // 30*256
    float* Kh    = sm + 7680;            // 30*128
    float* Vh    = sm + 11520;           // 30*128
    float* qv    = sm + 15360;           // 128
    float* hvi   = sm + 15488;           // 128
    float* hv1s  = sm + 15616;           // 128
    float* red   = sm + 15744;           // 256
    float* att   = sm + 16000;           // 120
    float* mvals = sm + 16120;           // 30
    int*   selidx= (int*)(sm + 16150);   // 30
    float* upd   = sm;                   // alias X_all[0:128]  (X_all dead after projections)
    float* t1    = sm + 256;             // alias X_all[256:768]

    if (t < KNB) {
        int idx = E_idx[node*KNB + t];
        selidx[t] = idx;
        mvals[t] = mask[node] * mask[b*NN + idx];
    }
    if (t < H) hvi[t] = hv_in[node*H + t];
    __syncthreads();

    // stage all 30 concat vectors [h_E | h_V[nbr]]
    for (int q = t; q < KNB*256; q += 256) {
        int k = q >> 8, c = q & 255;
        float v;
        if (c < H) v = __bfloat162float(h_E[(node*KNB+k)*H + c]);
        else       v = hv_in[(b*NN + selidx[k])*H + (c - H)];
        X_all[k*256 + c] = v;
    }
    __syncthreads();

    // Q projection (threads < 128)
    if (t < H) {
        float a = 0.f;
        for (int p = 0; p < H; p += 4) {
            float4 h4 = *(const float4*)&hvi[p];
            a += h4.x*Wq[(p+0)*H+t] + h4.y*Wq[(p+1)*H+t]
               + h4.z*Wq[(p+2)*H+t] + h4.w*Wq[(p+3)*H+t];
        }
        qv[t] = a;
    }

    // K projection (threads 0..127) / V projection (threads 128..255)
    {
        int j = t & 127;
        const float* W = (t < 128) ? Wk : Wv;
        float acc[KNB];
#pragma unroll
        for (int k = 0; k < KNB; k++) acc[k] = 0.f;
        for (int p = 0; p < 2*H; p += 4) {
            float w0 = W[(p+0)*H+j];
            float w1 = W[(p+1)*H+j];
            float w2 = W[(p+2)*H+j];
            float w3 = W[(p+3)*H+j];
#pragma unroll
            for (int k = 0; k < KNB; k++) {
                float4 x4 = *(const float4*)&X_all[k*256+p];
                acc[k] += x4.x*w0 + x4.y*w1 + x4.z*w2 + x4.w*w3;
            }
        }
        float* outp = (t < 128) ? Kh : Vh;
#pragma unroll
        for (int k = 0; k < KNB; k++) outp[k*H+j] = acc[k];
    }
    __syncthreads();

    // logits (120 of them)
    if (t < NHEADS*KNB) {
        int h = t / KNB, kk = t % KNB;
        const float* qh = &qv[h*DH];
        const float* kh = &Kh[kk*H + h*DH];
        float a = 0.f;
#pragma unroll
        for (int d = 0; d < DH; d += 4) {
            float4 q4 = *(const float4*)&qh[d];
            float4 k4 = *(const float4*)&kh[d];
            a += q4.x*k4.x + q4.y*k4.y + q4.z*k4.z + q4.w*k4.w;
        }
        a *= 0.17677669529663687f;  // 1/sqrt(32)
        att[h*KNB+kk] = (mvals[kk] > 0.f) ? a : -3.4028235e38f;
    }
    __syncthreads();

    // softmax per head (4 threads, 2-pass to keep regs low)
    if (t < NHEADS) {
        float mx = -3.4028235e38f;
        for (int kk = 0; kk < KNB; kk++) mx = fmaxf(mx, att[t*KNB+kk]);
        float s = 0.f;
        for (int kk = 0; kk < KNB; kk++) s += __expf(att[t*KNB+kk] - mx);
        float inv = 1.0f / s;
        for (int kk = 0; kk < KNB; kk++)
            att[t*KNB+kk] = __expf(att[t*KNB+kk] - mx) * inv * mvals[kk];
    }
    __syncthreads();

    // upd = sum_k att * Vh
    if (t < H) {
        int h = t >> 5;
        float u = 0.f;
        for (int kk = 0; kk < KNB; kk++)
            u += att[h*KNB+kk] * Vh[kk*H + t];
        upd[t] = u;
    }
    __syncthreads();

    // o = upd @ Wo ; residual ; LN1
    float x = 0.f;
    if (t < H) {
        float a = 0.f;
        for (int p = 0; p < H; p += 4) {
            float4 u4 = *(const float4*)&upd[p];
            a += u4.x*Wo[(p+0)*H+t] + u4.y*Wo[(p+1)*H+t]
               + u4.z*Wo[(p+2)*H+t] + u4.w*Wo[(p+3)*H+t];
        }
        x = hvi[t] + a;
    }
    {
        float s  = block_sum256(red, (t < H) ? x : 0.f, t);
        float mu = s * (1.0f/H);
        float d  = (t < H) ? (x - mu) : 0.f;
        float v  = block_sum256(red, d*d, t);
        float rs = rsqrtf(v*(1.0f/H) + LN_EPS);
        if (t < H) hv1s[t] = ln1g[t]*(x-mu)*rs + ln1b[t];
    }
    __syncthreads();

    // FF1: 512 outputs, 2 per thread
    {
        float a0 = bf1[t], a1 = bf1[t+256];
        for (int p = 0; p < H; p += 4) {
            float4 h4 = *(const float4*)&hv1s[p];
            a0 += h4.x*Wf1[(p+0)*FFH+t]     + h4.y*Wf1[(p+1)*FFH+t]
                + h4.z*Wf1[(p+2)*FFH+t]     + h4.w*Wf1[(p+3)*FFH+t];
            a1 += h4.x*Wf1[(p+0)*FFH+t+256] + h4.y*Wf1[(p+1)*FFH+t+256]
                + h4.z*Wf1[(p+2)*FFH+t+256] + h4.w*Wf1[(p+3)*FFH+t+256];
        }
        t1[t]     = fmaxf(a0, 0.f);
        t1[t+256] = fmaxf(a1, 0.f);
    }
    __syncthreads();

    // FF2 + residual + LN2 + mask
    float x2 = 0.f;
    if (t < H) {
        float a = bf2[t];
        for (int p = 0; p < FFH; p += 4) {
            float4 t4 = *(const float4*)&t1[p];
            a += t4.x*Wf2[(p+0)*H+t] + t4.y*Wf2[(p+1)*H+t]
               + t4.z*Wf2[(p+2)*H+t] + t4.w*Wf2[(p+3)*H+t];
        }
        x2 = hv1s[t] + a;
    }
    {
        float s  = block_sum256(red, (t < H) ? x2 : 0.f, t);
        float mu = s * (1.0f/H);
        float d  = (t < H) ? (x2 - mu) : 0.f;
        float v  = block_sum256(red, d*d, t);
        float rs = rsqrtf(v*(1.0f/H) + LN_EPS);
        if (t < H)
            hv_out[node*H+t] = mask[node] * (ln2g[t]*(x2-mu)*rs + ln2b[t]);
    }
}

// ---------------------------------------------------------------- final projection
__global__ __launch_bounds__(64) void out_kernel(
    const float* __restrict__ hv, const float* __restrict__ W_out,
    const float* __restrict__ b_out, float* __restrict__ out)
{
    int row = blockIdx.x;
    int t = threadIdx.x;
    float a = hv[row*H+t]*W_out[t] + hv[row*H+t+64]*W_out[t+64];
#pragma unroll
    for (int s = 32; s > 0; s >>= 1) a += __shfl_down(a, s, 64);
    if (t == 0) out[row] = a + b_out[0];
}

// ---------------------------------------------------------------- launch
extern "C" void kernel_launch(void* const* d_in, const int* in_sizes, int n_in,
                              void* d_out, int out_size, void* d_ws, size_t ws_size,
                              hipStream_t stream)
{
    const float* X      = (const float*)d_in[0];
    const float* V      = (const float*)d_in[1];
    const float* mask   = (const float*)d_in[2];
    const float* W_v    = (const float*)d_in[3];
    const float* b_v    = (const float*)d_in[4];
    const float* W_e    = (const float*)d_in[5];
    const float* b_e    = (const float*)d_in[6];
    const float* W_edge = (const float*)d_in[7];
    const float* ln_e_g = (const float*)d_in[8];
    const float* ln_e_b = (const float*)d_in[9];
    const float* Wq     = (const float*)d_in[10];
    const float* Wk     = (const float*)d_in[11];
    const float* Wv_a   = (const float*)d_in[12];
    const float* Wo     = (const float*)d_in[13];
    const float* ln1g   = (const float*)d_in[14];
    const float* ln1b   = (const float*)d_in[15];
    const float* ln2g   = (const float*)d_in[16];
    const float* ln2b   = (const float*)d_in[17];
    const float* Wf1    = (const float*)d_in[18];
    const float* bf1    = (const float*)d_in[19];
    const float* Wf2    = (const float*)d_in[20];
    const float* bf2    = (const float*)d_in[21];
    const float* W_out  = (const float*)d_in[22];
    const float* b_out  = (const float*)d_in[23];
    float* out = (float*)d_out;

    // workspace layout (all 16B aligned):
    //   E_idx   :        0 ..   720,000   (int,  6000*30)
    //   D_nb    :  720,000 .. 1,440,000   (f32,  6000*30)
    //   h_E     : 1,440,000 .. 47,520,000 (bf16, 6000*30*128)
    //   hv ping : 47,520,000 .. 50,592,000 (f32, 6000*128)
    //   hv pong : 50,592,000 .. 53,664,000 (f32, 6000*128)
    char* ws = (char*)d_ws;
    int*            E_idx = (int*)ws;
    float*          D_nb  = (float*)(ws + 720000);
    __hip_bfloat16* h_E   = (__hip_bfloat16*)(ws + 1440000);
    float*          hva   = (float*)(ws + 47520000);
    float*          hvb   = (float*)(ws + 50592000);

    topk_kernel<<<NROWS, 256, 0, stream>>>(X, mask, E_idx, D_nb);
    edge_kernel<<<NROWS, 128, 0, stream>>>(E_idx, D_nb, W_edge, ln_e_g, ln_e_b, W_e, b_e, h_E);
    hv_init_kernel<<<NROWS/8, 128, 0, stream>>>(V, W_v, b_v, hva);

    float* bufs[2] = { hva, hvb };
    for (int l = 0; l < 4; l++) {
        layer_kernel<<<NROWS, 256, 0, stream>>>(
            bufs[l & 1], bufs[(l+1) & 1], h_E, E_idx, mask,
            Wq + l*H*H, Wk + l*2*H*H, Wv_a + l*2*H*H, Wo + l*H*H,
            ln1g + l*H, ln1b + l*H, ln2g + l*H, ln2b + l*H,
            Wf1 + l*H*FFH, bf1 + l*FFH, Wf2 + l*FFH*H, bf2 + l*H);
    }
    out_kernel<<<NROWS, 64, 0, stream>>>(bufs[0], W_out, b_out, out);
}

// Round 2
// 1097.759 us; speedup vs baseline: 3.1820x; 3.1820x over previous
//
#include <hip/hip_runtime.h>
#include <hip/hip_bf16.h>
#include <math.h>

#define NB 4
#define NN 1500
#define KNB 30
#define H 128
#define NHEADS 4
#define FFH 512
#define NODE_FEAT 1024
#define NROWS (NB*NN)
#define LN_EPS 1e-6f

typedef __attribute__((ext_vector_type(8))) short s8v;   // 8 bf16 = 4 VGPRs (MFMA A/B frag)
typedef __attribute__((ext_vector_type(4))) float f4v;   // MFMA C/D frag

__device__ __forceinline__ float bf_lo(unsigned u){ union{unsigned i; float f;} v; v.i = u<<16; return v.f; }
__device__ __forceinline__ float bf_hi(unsigned u){ union{unsigned i; float f;} v; v.i = u & 0xffff0000u; return v.f; }

// ---------------------------------------------------------------- topk
__global__ __launch_bounds__(256) void topk_kernel(
    const float* __restrict__ X, const float* __restrict__ mask,
    int* __restrict__ E_idx, float* __restrict__ D_nb)
{
    int row = blockIdx.x;            // b*NN + i
    int b = row / NN;
    int t = threadIdx.x;
    __shared__ float d_adj[NN];
    __shared__ float red_v[256];
    __shared__ int   red_i[256];

    float xi0 = X[row*3+0], xi1 = X[row*3+1], xi2 = X[row*3+2];
    float mi = mask[row];

    float lmax = -1e30f;
    for (int j = t; j < NN; j += 256) {
        float dx = xi0 - X[(b*NN+j)*3+0];
        float dy = xi1 - X[(b*NN+j)*3+1];
        float dz = xi2 - X[(b*NN+j)*3+2];
        float d  = sqrtf(dx*dx + dy*dy + dz*dz + 1e-6f);
        float m2 = mi * mask[b*NN+j];
        float dm = m2 * d;
        d_adj[j] = dm;
        lmax = fmaxf(lmax, dm);
    }
    red_v[t] = lmax;
    __syncthreads();
    for (int s = 128; s > 0; s >>= 1) {
        if (t < s) red_v[t] = fmaxf(red_v[t], red_v[t+s]);
        __syncthreads();
    }
    float rowmax = red_v[0];
    __syncthreads();

    for (int j = t; j < NN; j += 256) {
        float m2 = mi * mask[b*NN+j];
        d_adj[j] = d_adj[j] + (1.0f - m2) * rowmax;
    }
    __syncthreads();

    for (int kk = 0; kk < KNB; kk++) {
        float bv = 1e30f; int bi = NN;
        for (int j = t; j < NN; j += 256) {
            float v = d_adj[j];
            if (v < bv || (v == bv && j < bi)) { bv = v; bi = j; }
        }
        red_v[t] = bv; red_i[t] = bi;
        __syncthreads();
        for (int s = 128; s > 0; s >>= 1) {
            if (t < s) {
                float v2 = red_v[t+s]; int i2 = red_i[t+s];
                if (v2 < red_v[t] || (v2 == red_v[t] && i2 < red_i[t])) {
                    red_v[t] = v2; red_i[t] = i2;
                }
            }
            __syncthreads();
        }
        if (t == 0) {
            int sel = red_i[0];
            E_idx[row*KNB+kk] = sel;
            D_nb[row*KNB+kk]  = red_v[0];
            d_adj[sel] = 1e30f;
        }
        __syncthreads();
    }
}

// ---------------------------------------------------------------- edge features -> h_E (bf16)
__global__ __launch_bounds__(128) void edge_kernel(
    const int* __restrict__ E_idx, const float* __restrict__ D_nb,
    const float* __restrict__ W_edge, const float* __restrict__ ln_g,
    const float* __restrict__ ln_b, const float* __restrict__ W_e,
    const float* __restrict__ b_e, __hip_bfloat16* __restrict__ h_E)
{
    int node = blockIdx.x;
    int i = node % NN;
    int t = threadIdx.x;             // 128 threads, t = output channel
    __shared__ float feat[KNB*32];
    __shared__ float eall[KNB*132];
    __shared__ float mu_s[KNB], rs_s[KNB];

    for (int q = t; q < KNB*32; q += 128) {
        int k = q >> 5, f = q & 31;
        int e = node*KNB + k;
        float val;
        if (f < 16) {
            int ff = f & 7;
            float drel = (float)E_idx[e] - (float)i;
            float fr = expf(-(float)ff * 1.15129254649702284f);
            float ang = drel * fr;
            val = (f < 8) ? cosf(ang) : sinf(ang);
        } else {
            float mu = (20.0f/15.0f) * (float)(f-16);
            float z = (D_nb[e] - mu) * 0.8f;
            val = expf(-z*z);
        }
        feat[q] = val;
    }
    __syncthreads();

    float acc[KNB];
#pragma unroll
    for (int k = 0; k < KNB; k++) acc[k] = 0.f;
    for (int p = 0; p < 32; p += 4) {
        float w0 = W_edge[(p+0)*H+t];
        float w1 = W_edge[(p+1)*H+t];
        float w2 = W_edge[(p+2)*H+t];
        float w3 = W_edge[(p+3)*H+t];
#pragma unroll
        for (int k = 0; k < KNB; k++) {
            float4 f4 = *(const float4*)&feat[k*32+p];
            acc[k] += f4.x*w0 + f4.y*w1 + f4.z*w2 + f4.w*w3;
        }
    }
#pragma unroll
    for (int k = 0; k < KNB; k++) eall[k*132+t] = acc[k];
    __syncthreads();

    if (t < KNB) {
        float s = 0.f;
        for (int c = 0; c < H; c++) s += eall[t*132+c];
        float mu = s * (1.0f/H);
        float v = 0.f;
        for (int c = 0; c < H; c++) { float d = eall[t*132+c] - mu; v += d*d; }
        mu_s[t] = mu;
        rs_s[t] = rsqrtf(v*(1.0f/H) + LN_EPS);
    }
    __syncthreads();
    float g = ln_g[t], bb = ln_b[t];
#pragma unroll
    for (int k = 0; k < KNB; k++)
        eall[k*132+t] = g*(eall[k*132+t]-mu_s[k])*rs_s[k] + bb;
    __syncthreads();

    float be = b_e[t];
    float acc2[KNB];
#pragma unroll
    for (int k = 0; k < KNB; k++) acc2[k] = be;
    for (int p = 0; p < H; p += 4) {
        float w0 = W_e[(p+0)*H+t];
        float w1 = W_e[(p+1)*H+t];
        float w2 = W_e[(p+2)*H+t];
        float w3 = W_e[(p+3)*H+t];
#pragma unroll
        for (int k = 0; k < KNB; k++) {
            float4 f4 = *(const float4*)&eall[k*132+p];
            acc2[k] += f4.x*w0 + f4.y*w1 + f4.z*w2 + f4.w*w3;
        }
    }
    for (int k = 0; k < KNB; k++)
        h_E[(node*KNB+k)*H+t] = __float2bfloat16(acc2[k]);
}

// ---------------------------------------------------------------- h_V = V @ W_v + b_v
__global__ __launch_bounds__(128) void hv_init_kernel(
    const float* __restrict__ V, const float* __restrict__ W_v,
    const float* __restrict__ b_v, float* __restrict__ hv)
{
    int row0 = blockIdx.x * 8;
    int t = threadIdx.x;
    __shared__ float vs[8*NODE_FEAT];
    for (int q = t; q < 8*NODE_FEAT; q += 128) vs[q] = V[row0*NODE_FEAT + q];
    __syncthreads();
    float acc[8];
#pragma unroll
    for (int r = 0; r < 8; r++) acc[r] = 0.f;
    for (int p = 0; p < NODE_FEAT; p += 4) {
        float w0 = W_v[(p+0)*H+t];
        float w1 = W_v[(p+1)*H+t];
        float w2 = W_v[(p+2)*H+t];
        float w3 = W_v[(p+3)*H+t];
#pragma unroll
        for (int r = 0; r < 8; r++) {
            float4 v4 = *(const float4*)&vs[r*NODE_FEAT+p];
            acc[r] += v4.x*w0 + v4.y*w1 + v4.z*w2 + v4.w*w3;
        }
    }
    float bv = b_v[t];
#pragma unroll
    for (int r = 0; r < 8; r++) hv[(row0+r)*H+t] = acc[r] + bv;
}

// ---------------------------------------------------------------- per-layer weight prep:
// Wt[l][n][k] bf16, n<128: Wk[l][k][n] (h_E rows), n>=128: Wv[l][k][n-128]
__global__ __launch_bounds__(256) void wprep_kernel(
    const float* __restrict__ Wk, const float* __restrict__ Wv,
    __hip_bfloat16* __restrict__ Wt)
{
    int tid = blockIdx.x*256 + threadIdx.x;  // 4*256*128 = 131072
    int l = tid >> 15;
    int n = (tid >> 7) & 255;
    int k = tid & 127;
    const float* W = (n < 128) ? (Wk + l*2*H*H) : (Wv + l*2*H*H);
    Wt[tid] = __float2bfloat16(W[k*H + (n & 127)]);
}

// ---------------------------------------------------------------- node-side projections:
// P[row][0:128]=Q, [128:256]=Pk=hv@Wk_bot, [256:384]=Pv=hv@Wv_bot
__global__ __launch_bounds__(384) void node_proj_kernel(
    const float* __restrict__ hv, const float* __restrict__ Wq,
    const float* __restrict__ Wk, const float* __restrict__ Wv,
    float* __restrict__ P)
{
    int row0 = blockIdx.x * 8;
    int t = threadIdx.x;  // 0..383
    __shared__ float xs[8*H];
    for (int q = t; q < 8*H; q += 384) xs[q] = hv[row0*H + q];
    __syncthreads();
    const float* base;
    if (t < 128)      base = Wq + t;
    else if (t < 256) base = Wk + H*H + (t-128);   // h_V rows of Wk
    else              base = Wv + H*H + (t-256);
    float acc[8];
#pragma unroll
    for (int r = 0; r < 8; r++) acc[r] = 0.f;
    for (int p = 0; p < H; p += 4) {
        float w0 = base[(p+0)*H];
        float w1 = base[(p+1)*H];
        float w2 = base[(p+2)*H];
        float w3 = base[(p+3)*H];
#pragma unroll
        for (int r = 0; r < 8; r++) {
            float4 x4 = *(const float4*)&xs[r*H+p];
            acc[r] += x4.x*w0 + x4.y*w1 + x4.z*w2 + x4.w*w3;
        }
    }
#pragma unroll
    for (int r = 0; r < 8; r++) P[(size_t)(row0+r)*384 + t] = acc[r];
}

// ---------------------------------------------------------------- attention: 2 nodes/block
// MFMA edge GEMM KV[60x256] = h_E_rows[60x128] @ Wkv[128x256], then gather-add node
// terms, logits, softmax, upd. Writes upd into P's Q slots (cols 0..127).
__global__ __launch_bounds__(256) void attn_kernel(
    const __hip_bfloat16* __restrict__ h_E, const __hip_bfloat16* __restrict__ Wt,
    float* __restrict__ P, const int* __restrict__ E_idx,
    const float* __restrict__ mask)
{
    int g0 = blockIdx.x * 2;
    int t = threadIdx.x;
    __shared__ __hip_bfloat16 Ae[64*136];     // A tile, pitch 136 bf16
    __shared__ __hip_bfloat16 KVs[60*264];    // K|V rows, pitch 264 bf16
    __shared__ float Qs[2*H];
    __shared__ float att_s[2*120];
    __shared__ float mv_s[60];
    __shared__ int   nbr[60];

    // stage A: h_E rows g0*30 .. g0*30+59 (contiguous since g1=g0+1)
    const __hip_bfloat16* hebase = h_E + (size_t)g0*KNB*H;
    for (int q = t; q < 960; q += 256) {
        int r = q >> 4, c8 = (q & 15) * 8;
        *(s8v*)&Ae[r*136 + c8] = *(const s8v*)&hebase[r*H + c8];
    }
    if (t < 60) {
        int gn = g0 + t/30;
        int b = gn / NN;
        int idx = E_idx[gn*KNB + (t%30)];
        nbr[t]  = b*NN + idx;
        mv_s[t] = mask[gn] * mask[b*NN + idx];
    }
    {
        int node = t >> 7, c = t & 127;
        Qs[t] = P[(size_t)(g0+node)*384 + c];
    }
    __syncthreads();

    // MFMA: wave w handles n-tiles 4w..4w+3, all 4 m-tiles
    {
        int wave = t >> 6, lane = t & 63;
        int lm = lane & 15, lq = lane >> 4;
        const __hip_bfloat16* wb = Wt + (size_t)(wave*64 + lm)*H + lq*8;
        s8v bfr[4][4];
#pragma unroll
        for (int nt = 0; nt < 4; nt++)
#pragma unroll
            for (int ks = 0; ks < 4; ks++)
                bfr[nt][ks] = *(const s8v*)(wb + nt*16*H + ks*32);
#pragma unroll
        for (int mt = 0; mt < 4; mt++) {
            f4v a0 = {0.f,0.f,0.f,0.f}, a1 = a0, a2 = a0, a3 = a0;
#pragma unroll
            for (int ks = 0; ks < 4; ks++) {
                s8v af = *(const s8v*)&Ae[(mt*16+lm)*136 + ks*32 + lq*8];
                a0 = __builtin_amdgcn_mfma_f32_16x16x32_bf16(af, bfr[0][ks], a0, 0,0,0);
                a1 = __builtin_amdgcn_mfma_f32_16x16x32_bf16(af, bfr[1][ks], a1, 0,0,0);
                a2 = __builtin_amdgcn_mfma_f32_16x16x32_bf16(af, bfr[2][ks], a2, 0,0,0);
                a3 = __builtin_amdgcn_mfma_f32_16x16x32_bf16(af, bfr[3][ks], a3, 0,0,0);
            }
            int rbase = mt*16 + lq*4;
            int cb = wave*64 + lm;
#pragma unroll
            for (int r = 0; r < 4; r++) {
                int row = rbase + r;
                if (row < 60) {
                    KVs[row*264 + cb     ] = __float2bfloat16(a0[r]);
                    KVs[row*264 + cb + 16] = __float2bfloat16(a1[r]);
                    KVs[row*264 + cb + 32] = __float2bfloat16(a2[r]);
                    KVs[row*264 + cb + 48] = __float2bfloat16(a3[r]);
                }
            }
        }
    }
    __syncthreads();

    // add gathered node terms: K += Pk[nbr], V += Pv[nbr]
    // (offset 128+c works for both halves: c<128 -> Pk, c>=128 -> 256+(c-128))
    for (int q = t; q < 60*256; q += 256) {
        int r = q >> 8, c = q & 255;
        float add = P[(size_t)nbr[r]*384 + 128 + c];
        int a = r*264 + c;
        KVs[a] = __float2bfloat16(__bfloat162float(KVs[a]) + add);
    }
    __syncthreads();

    // logits
    if (t < 240) {
        int node = t / 120, tt = t % 120;
        int h = tt / 30, kk = tt % 30;
        int r = node*30 + kk;
        const unsigned* kp = (const unsigned*)&KVs[r*264 + h*32];
        const float* qp = &Qs[node*128 + h*32];
        float a = 0.f;
#pragma unroll
        for (int d = 0; d < 16; d++) {
            unsigned u = kp[d];
            a += qp[2*d]*bf_lo(u) + qp[2*d+1]*bf_hi(u);
        }
        att_s[node*120 + h*30 + kk] =
            (mv_s[r] > 0.f) ? a*0.17677669529663687f : -3.4028235e38f;
    }
    __syncthreads();
    if (t < 8) {
        int node = t >> 2, h = t & 3;
        float* ap = &att_s[node*120 + h*30];
        const float* mp = &mv_s[node*30];
        float mx = -3.4028235e38f;
        for (int kk = 0; kk < KNB; kk++) mx = fmaxf(mx, ap[kk]);
        float s = 0.f;
        for (int kk = 0; kk < KNB; kk++) s += __expf(ap[kk]-mx);
        float inv = 1.0f/s;
        for (int kk = 0; kk < KNB; kk++) ap[kk] = __expf(ap[kk]-mx)*inv*mp[kk];
    }
    __syncthreads();

    // upd = sum_k att * Vfull; write into P Q-slots
    {
        int node = t >> 7, c = t & 127;
        const float* ap = &att_s[node*120 + (c>>5)*30];
        float u = 0.f;
        for (int kk = 0; kk < KNB; kk++)
            u += ap[kk] * __bfloat162float(KVs[(node*30+kk)*264 + 128 + c]);
        P[(size_t)(g0+node)*384 + c] = u;
    }
}

// ---------------------------------------------------------------- Wo + LN1 + FF + LN2
__global__ __launch_bounds__(256) void post_kernel(
    const float* __restrict__ hv_in, const float* __restrict__ P,
    const float* __restrict__ mask, const float* __restrict__ Wo,
    const float* __restrict__ ln1g, const float* __restrict__ ln1b,
    const float* __restrict__ ln2g, const float* __restrict__ ln2b,
    const float* __restrict__ Wf1, const float* __restrict__ bf1,
    const float* __restrict__ Wf2, const float* __restrict__ bf2,
    float* __restrict__ hv_out)
{
    int row0 = blockIdx.x * 8;
    int t = threadIdx.x;
    int c = t & 127, half = t >> 7;
    __shared__ float us[8*H];
    __shared__ float xs[8*H];
    __shared__ float ys[8*H];
    __shared__ float t1[8*FFH];
    __shared__ float mu8[8], rs8[8];

    for (int q = t; q < 8*H; q += 256) {
        int r = q >> 7;
        us[q] = P[(size_t)(row0+r)*384 + (q & 127)];   // upd in Q slots
    }
    __syncthreads();

    // x = hv + us @ Wo
    {
        float acc[4] = {0.f,0.f,0.f,0.f};
        for (int p = 0; p < H; p += 4) {
            float w0 = Wo[(p+0)*H+c], w1 = Wo[(p+1)*H+c];
            float w2 = Wo[(p+2)*H+c], w3 = Wo[(p+3)*H+c];
#pragma unroll
            for (int r = 0; r < 4; r++) {
                float4 u4 = *(const float4*)&us[(half*4+r)*H + p];
                acc[r] += u4.x*w0 + u4.y*w1 + u4.z*w2 + u4.w*w3;
            }
        }
#pragma unroll
        for (int r = 0; r < 4; r++) {
            int rr = half*4+r;
            xs[rr*H+c] = hv_in[(size_t)(row0+rr)*H + c] + acc[r];
        }
    }
    __syncthreads();
    if (t < 8) {
        float s = 0.f, s2 = 0.f;
        for (int p = 0; p < H; p += 4) {
            float4 x4 = *(const float4*)&xs[t*H+p];
            s  += x4.x+x4.y+x4.z+x4.w;
            s2 += x4.x*x4.x + x4.y*x4.y + x4.z*x4.z + x4.w*x4.w;
        }
        float mu = s*(1.0f/H);
        mu8[t] = mu;
        rs8[t] = rsqrtf(s2*(1.0f/H) - mu*mu + LN_EPS);
    }
    __syncthreads();
    {
        float g = ln1g[c], bb = ln1b[c];
#pragma unroll
        for (int r = 0; r < 4; r++) {
            int rr = half*4+r;
            ys[rr*H+c] = g*(xs[rr*H+c]-mu8[rr])*rs8[rr] + bb;
        }
    }
    __syncthreads();

    // FF1: thread t -> cols t and t+256, all 8 rows
    {
        float a1[8], a2[8];
#pragma unroll
        for (int r = 0; r < 8; r++) { a1[r] = 0.f; a2[r] = 0.f; }
        for (int p = 0; p < H; p += 4) {
            float w10 = Wf1[(p+0)*FFH+t],     w11 = Wf1[(p+1)*FFH+t];
            float w12 = Wf1[(p+2)*FFH+t],     w13 = Wf1[(p+3)*FFH+t];
            float w20 = Wf1[(p+0)*FFH+t+256], w21 = Wf1[(p+1)*FFH+t+256];
            float w22 = Wf1[(p+2)*FFH+t+256], w23 = Wf1[(p+3)*FFH+t+256];
#pragma unroll
            for (int r = 0; r < 8; r++) {
                float4 y4 = *(const float4*)&ys[r*H+p];
                a1[r] += y4.x*w10 + y4.y*w11 + y4.z*w12 + y4.w*w13;
                a2[r] += y4.x*w20 + y4.y*w21 + y4.z*w22 + y4.w*w23;
            }
        }
        float b1v = bf1[t], b2v = bf1[t+256];
#pragma unroll
        for (int r = 0; r < 8; r++) {
            t1[r*FFH + t]       = fmaxf(a1[r]+b1v, 0.f);
            t1[r*FFH + t + 256] = fmaxf(a2[r]+b2v, 0.f);
        }
    }
    __syncthreads();

    // FF2 + residual
    {
        float acc[4] = {0.f,0.f,0.f,0.f};
        for (int p = 0; p < FFH; p += 4) {
            float w0 = Wf2[(p+0)*H+c], w1 = Wf2[(p+1)*H+c];
            float w2 = Wf2[(p+2)*H+c], w3 = Wf2[(p+3)*H+c];
#pragma unroll
            for (int r = 0; r < 4; r++) {
                float4 t4 = *(const float4*)&t1[(half*4+r)*FFH + p];
                acc[r] += t4.x*w0 + t4.y*w1 + t4.z*w2 + t4.w*w3;
            }
        }
        float bb = bf2[c];
#pragma unroll
        for (int r = 0; r < 4; r++) {
            int rr = half*4+r;
            xs[rr*H+c] = ys[rr*H+c] + acc[r] + bb;
        }
    }
    __syncthreads();
    if (t < 8) {
        float s = 0.f, s2 = 0.f;
        for (int p = 0; p < H; p += 4) {
            float4 x4 = *(const float4*)&xs[t*H+p];
            s  += x4.x+x4.y+x4.z+x4.w;
            s2 += x4.x*x4.x + x4.y*x4.y + x4.z*x4.z + x4.w*x4.w;
        }
        float mu = s*(1.0f/H);
        mu8[t] = mu;
        rs8[t] = rsqrtf(s2*(1.0f/H) - mu*mu + LN_EPS);
    }
    __syncthreads();
    {
        float g = ln2g[c], bb = ln2b[c];
#pragma unroll
        for (int r = 0; r < 4; r++) {
            int rr = half*4+r;
            hv_out[(size_t)(row0+rr)*H + c] =
                mask[row0+rr]*(g*(xs[rr*H+c]-mu8[rr])*rs8[rr] + bb);
        }
    }
}

// ---------------------------------------------------------------- final projection
__global__ __launch_bounds__(64) void out_kernel(
    const float* __restrict__ hv, const float* __restrict__ W_out,
    const float* __restrict__ b_out, float* __restrict__ out)
{
    int row = blockIdx.x;
    int t = threadIdx.x;
    float a = hv[row*H+t]*W_out[t] + hv[row*H+t+64]*W_out[t+64];
#pragma unroll
    for (int s = 32; s > 0; s >>= 1) a += __shfl_down(a, s, 64);
    if (t == 0) out[row] = a + b_out[0];
}

// ---------------------------------------------------------------- launch
extern "C" void kernel_launch(void* const* d_in, const int* in_sizes, int n_in,
                              void* d_out, int out_size, void* d_ws, size_t ws_size,
                              hipStream_t stream)
{
    const float* X      = (const float*)d_in[0];
    const float* V      = (const float*)d_in[1];
    const float* mask   = (const float*)d_in[2];
    const float* W_v    = (const float*)d_in[3];
    const float* b_v    = (const float*)d_in[4];
    const float* W_e    = (const float*)d_in[5];
    const float* b_e    = (const float*)d_in[6];
    const float* W_edge = (const float*)d_in[7];
    const float* ln_e_g = (const float*)d_in[8];
    const float* ln_e_b = (const float*)d_in[9];
    const float* Wq     = (const float*)d_in[10];
    const float* Wk     = (const float*)d_in[11];
    const float* Wv_a   = (const float*)d_in[12];
    const float* Wo     = (const float*)d_in[13];
    const float* ln1g   = (const float*)d_in[14];
    const float* ln1b   = (const float*)d_in[15];
    const float* ln2g   = (const float*)d_in[16];
    const float* ln2b   = (const float*)d_in[17];
    const float* Wf1    = (const float*)d_in[18];
    const float* bf1    = (const float*)d_in[19];
    const float* Wf2    = (const float*)d_in[20];
    const float* bf2    = (const float*)d_in[21];
    const float* W_out  = (const float*)d_in[22];
    const float* b_out  = (const float*)d_in[23];
    float* out = (float*)d_out;

    // workspace layout:
    //   E_idx :        0 ..   720,000   (int,  180000)
    //   D_nb  :  720,000 .. 1,440,000   (f32; dead after edge_kernel, reused for Wt)
    //   Wt    :  720,000 ..   982,144   (bf16, 4*256*128)  [after edge_kernel]
    //   h_E   : 1,440,000 .. 47,520,000 (bf16, 180000*128)
    //   hva   : 47,520,000 (f32 6000*128)
    //   hvb   : 50,592,000 (f32 6000*128)
    //   P     : 53,664,000 .. 62,880,000 (f32 6000*384: Q|Pk|Pv; Q slots reused as upd)
    char* ws = (char*)d_ws;
    int*            E_idx = (int*)ws;
    float*          D_nb  = (float*)(ws + 720000);
    __hip_bfloat16* Wt    = (__hip_bfloat16*)(ws + 720000);
    __hip_bfloat16* h_E   = (__hip_bfloat16*)(ws + 1440000);
    float*          hva   = (float*)(ws + 47520000);
    float*          hvb   = (float*)(ws + 50592000);
    float*          P     = (float*)(ws + 53664000);

    topk_kernel<<<NROWS, 256, 0, stream>>>(X, mask, E_idx, D_nb);
    edge_kernel<<<NROWS, 128, 0, stream>>>(E_idx, D_nb, W_edge, ln_e_g, ln_e_b, W_e, b_e, h_E);
    wprep_kernel<<<512, 256, 0, stream>>>(Wk, Wv_a, Wt);   // after edge (overwrites D_nb)
    hv_init_kernel<<<NROWS/8, 128, 0, stream>>>(V, W_v, b_v, hva);

    float* bufs[2] = { hva, hvb };
    for (int l = 0; l < 4; l++) {
        const float* hin = bufs[l & 1];
        float* hout = bufs[(l+1) & 1];
        node_proj_kernel<<<NROWS/8, 384, 0, stream>>>(hin, Wq + l*H*H, Wk + l*2*H*H, Wv_a + l*2*H*H, P);
        attn_kernel<<<NROWS/2, 256, 0, stream>>>(h_E, Wt + l*256*H, P, E_idx, mask);
        post_kernel<<<NROWS/8, 256, 0, stream>>>(hin, P, mask, Wo + l*H*H,
            ln1g + l*H, ln1b + l*H, ln2g + l*H, ln2b + l*H,
            Wf1 + l*H*FFH, bf1 + l*FFH, Wf2 + l*FFH*H, bf2 + l*H, hout);
    }
    out_kernel<<<NROWS, 64, 0, stream>>>(bufs[0], W_out, b_out, out);
}

// Round 3
// 853.678 us; speedup vs baseline: 4.0917x; 1.2859x over previous
//
#include <hip/hip_runtime.h>
#include <hip/hip_bf16.h>
#include <math.h>

#define NB 4
#define NN 1500
#define KNB 30
#define H 128
#define NHEADS 4
#define FFH 512
#define NODE_FEAT 1024
#define NROWS (NB*NN)
#define LN_EPS 1e-6f

typedef __attribute__((ext_vector_type(8))) short s8v;   // 8 bf16 = 4 VGPRs (MFMA A/B frag)
typedef __attribute__((ext_vector_type(4))) float f4v;   // MFMA C/D frag

__device__ __forceinline__ float bf_lo(unsigned u){ union{unsigned i; float f;} v; v.i = u<<16; return v.f; }
__device__ __forceinline__ float bf_hi(unsigned u){ union{unsigned i; float f;} v; v.i = u & 0xffff0000u; return v.f; }

// ---------------------------------------------------------------- topk
__global__ __launch_bounds__(256) void topk_kernel(
    const float* __restrict__ X, const float* __restrict__ mask,
    int* __restrict__ E_idx, float* __restrict__ D_nb)
{
    int row = blockIdx.x;            // b*NN + i
    int b = row / NN;
    int t = threadIdx.x;
    __shared__ float d_adj[NN];
    __shared__ float red_v[256];
    __shared__ int   red_i[256];

    float xi0 = X[row*3+0], xi1 = X[row*3+1], xi2 = X[row*3+2];
    float mi = mask[row];

    float lmax = -1e30f;
    for (int j = t; j < NN; j += 256) {
        float dx = xi0 - X[(b*NN+j)*3+0];
        float dy = xi1 - X[(b*NN+j)*3+1];
        float dz = xi2 - X[(b*NN+j)*3+2];
        float d  = sqrtf(dx*dx + dy*dy + dz*dz + 1e-6f);
        float m2 = mi * mask[b*NN+j];
        float dm = m2 * d;
        d_adj[j] = dm;
        lmax = fmaxf(lmax, dm);
    }
    red_v[t] = lmax;
    __syncthreads();
    for (int s = 128; s > 0; s >>= 1) {
        if (t < s) red_v[t] = fmaxf(red_v[t], red_v[t+s]);
        __syncthreads();
    }
    float rowmax = red_v[0];
    __syncthreads();

    for (int j = t; j < NN; j += 256) {
        float m2 = mi * mask[b*NN+j];
        d_adj[j] = d_adj[j] + (1.0f - m2) * rowmax;
    }
    __syncthreads();

    for (int kk = 0; kk < KNB; kk++) {
        float bv = 1e30f; int bi = NN;
        for (int j = t; j < NN; j += 256) {
            float v = d_adj[j];
            if (v < bv || (v == bv && j < bi)) { bv = v; bi = j; }
        }
        red_v[t] = bv; red_i[t] = bi;
        __syncthreads();
        for (int s = 128; s > 0; s >>= 1) {
            if (t < s) {
                float v2 = red_v[t+s]; int i2 = red_i[t+s];
                if (v2 < red_v[t] || (v2 == red_v[t] && i2 < red_i[t])) {
                    red_v[t] = v2; red_i[t] = i2;
                }
            }
            __syncthreads();
        }
        if (t == 0) {
            int sel = red_i[0];
            E_idx[row*KNB+kk] = sel;
            D_nb[row*KNB+kk]  = red_v[0];
            d_adj[sel] = 1e30f;
        }
        __syncthreads();
    }
}

// ---------------------------------------------------------------- edge features -> E_ln (bf16)
// (W_e/b_e are algebraically folded into the per-layer K/V weights by wprep_kv)
__global__ __launch_bounds__(128) void edge_kernel(
    const int* __restrict__ E_idx, const float* __restrict__ D_nb,
    const float* __restrict__ W_edge, const float* __restrict__ ln_g,
    const float* __restrict__ ln_b, __hip_bfloat16* __restrict__ E_ln)
{
    int node = blockIdx.x;
    int i = node % NN;
    int t = threadIdx.x;             // 128 threads, t = output channel
    __shared__ float feat[KNB*32];
    __shared__ float eall[KNB*132];
    __shared__ float mu_s[KNB], rs_s[KNB];

    for (int q = t; q < KNB*32; q += 128) {
        int k = q >> 5, f = q & 31;
        int e = node*KNB + k;
        float val;
        if (f < 16) {
            int ff = f & 7;
            float drel = (float)E_idx[e] - (float)i;
            float fr = expf(-(float)ff * 1.15129254649702284f);
            float ang = drel * fr;
            val = (f < 8) ? cosf(ang) : sinf(ang);
        } else {
            float mu = (20.0f/15.0f) * (float)(f-16);
            float z = (D_nb[e] - mu) * 0.8f;
            val = expf(-z*z);
        }
        feat[q] = val;
    }
    __syncthreads();

    float acc[KNB];
#pragma unroll
    for (int k = 0; k < KNB; k++) acc[k] = 0.f;
    for (int p = 0; p < 32; p += 4) {
        float w0 = W_edge[(p+0)*H+t];
        float w1 = W_edge[(p+1)*H+t];
        float w2 = W_edge[(p+2)*H+t];
        float w3 = W_edge[(p+3)*H+t];
#pragma unroll
        for (int k = 0; k < KNB; k++) {
            float4 f4 = *(const float4*)&feat[k*32+p];
            acc[k] += f4.x*w0 + f4.y*w1 + f4.z*w2 + f4.w*w3;
        }
    }
#pragma unroll
    for (int k = 0; k < KNB; k++) eall[k*132+t] = acc[k];
    __syncthreads();

    if (t < KNB) {
        float s = 0.f;
        for (int c = 0; c < H; c++) s += eall[t*132+c];
        float mu = s * (1.0f/H);
        float v = 0.f;
        for (int c = 0; c < H; c++) { float d = eall[t*132+c] - mu; v += d*d; }
        mu_s[t] = mu;
        rs_s[t] = rsqrtf(v*(1.0f/H) + LN_EPS);
    }
    __syncthreads();
    float g = ln_g[t], bb = ln_b[t];
#pragma unroll
    for (int k = 0; k < KNB; k++)
        E_ln[(node*KNB+k)*H+t] =
            __float2bfloat16(g*(eall[k*132+t]-mu_s[k])*rs_s[k] + bb);
}

// ---------------------------------------------------------------- h_V = V @ W_v + b_v
__global__ __launch_bounds__(128) void hv_init_kernel(
    const float* __restrict__ V, const float* __restrict__ W_v,
    const float* __restrict__ b_v, float* __restrict__ hv)
{
    int row0 = blockIdx.x * 8;
    int t = threadIdx.x;
    __shared__ float vs[8*NODE_FEAT];
    for (int q = t; q < 8*NODE_FEAT; q += 128) vs[q] = V[row0*NODE_FEAT + q];
    __syncthreads();
    float acc[8];
#pragma unroll
    for (int r = 0; r < 8; r++) acc[r] = 0.f;
    for (int p = 0; p < NODE_FEAT; p += 4) {
        float w0 = W_v[(p+0)*H+t];
        float w1 = W_v[(p+1)*H+t];
        float w2 = W_v[(p+2)*H+t];
        float w3 = W_v[(p+3)*H+t];
#pragma unroll
        for (int r = 0; r < 8; r++) {
            float4 v4 = *(const float4*)&vs[r*NODE_FEAT+p];
            acc[r] += v4.x*w0 + v4.y*w1 + v4.z*w2 + v4.w*w3;
        }
    }
    float bv = b_v[t];
#pragma unroll
    for (int r = 0; r < 8; r++) hv[(row0+r)*H+t] = acc[r] + bv;
}

// ---------------------------------------------------------------- fold W_e into per-layer edge K/V:
// Wt_kv[l][n][k] = (W_e @ W{k,v}_top)[k][n]  (n<128: K, n>=128: V), bf16
// bias_kv[l][n]  = (b_e @ W{k,v}_top)[n]
__global__ __launch_bounds__(128) void wprep_kv_kernel(
    const float* __restrict__ W_e, const float* __restrict__ b_e,
    const float* __restrict__ Wk, const float* __restrict__ Wv,
    __hip_bfloat16* __restrict__ Wt_kv, float* __restrict__ bias_kv)
{
    int l = blockIdx.x >> 8;
    int n = blockIdx.x & 255;
    int t = threadIdx.x;             // t = k (0..127)
    int col = n & 127;
    const float* W = (n < 128) ? (Wk + l*2*H*H) : (Wv + l*2*H*H);
    __shared__ float wcol[128];
    wcol[t] = W[t*H + col];          // rows 0..127 = h_E block
    __syncthreads();
    float a = 0.f;
    for (int c = 0; c < H; c += 4) {
        float4 we = *(const float4*)&W_e[t*H + c];
        a += we.x*wcol[c] + we.y*wcol[c+1] + we.z*wcol[c+2] + we.w*wcol[c+3];
    }
    Wt_kv[(size_t)(l*256 + n)*H + t] = __float2bfloat16(a);
    if (t == 0) {
        float bsum = 0.f;
        for (int c = 0; c < H; c++) bsum += b_e[c]*wcol[c];
        bias_kv[l*256 + n] = bsum;
    }
}

// ---------------------------------------------------------------- transpose+cast weights to bf16 [n][k]:
// Wo_t[l][128][128], Wf1_t[l][512][128], Wf2_t[l][128][512], Wn_t[l][384][128] (Q|Kbot|Vbot)
__global__ __launch_bounds__(256) void wprep_post_kernel(
    const float* __restrict__ Wo, const float* __restrict__ Wf1,
    const float* __restrict__ Wf2, const float* __restrict__ Wq,
    const float* __restrict__ Wk, const float* __restrict__ Wv,
    __hip_bfloat16* __restrict__ Wo_t, __hip_bfloat16* __restrict__ Wf1_t,
    __hip_bfloat16* __restrict__ Wf2_t, __hip_bfloat16* __restrict__ Wn_t)
{
    int id = blockIdx.x*256 + threadIdx.x;   // < 786432
    int l = id / 196608;
    int r = id - l*196608;
    float v; __hip_bfloat16* dst;
    if (r < 16384) {
        int n = r >> 7, k = r & 127;
        v = Wo[l*16384 + k*128 + n];
        dst = Wo_t + l*16384 + r;
    } else if (r < 81920) {
        int rr = r - 16384;
        int n = rr >> 7, k = rr & 127;
        v = Wf1[l*65536 + k*512 + n];
        dst = Wf1_t + l*65536 + rr;
    } else if (r < 147456) {
        int rr = r - 81920;
        int n = rr >> 9, k = rr & 511;
        v = Wf2[l*65536 + k*128 + n];
        dst = Wf2_t + l*65536 + rr;
    } else {
        int rr = r - 147456;
        int n = rr >> 7, k = rr & 127;
        if (n < 128)      v = Wq[l*16384 + k*128 + n];
        else if (n < 256) v = Wk[l*32768 + (128+k)*128 + (n-128)];
        else              v = Wv[l*32768 + (128+k)*128 + (n-256)];
        dst = Wn_t + l*49152 + rr;
    }
    *dst = __float2bfloat16(v);
}

// ---------------------------------------------------------------- layer-0 node projections (fp32):
// P[row][0:128]=Q, [128:256]=Pk, [256:384]=Pv
__global__ __launch_bounds__(384) void node_proj_kernel(
    const float* __restrict__ hv, const float* __restrict__ Wq,
    const float* __restrict__ Wk, const float* __restrict__ Wv,
    float* __restrict__ P)
{
    int row0 = blockIdx.x * 8;
    int t = threadIdx.x;  // 0..383
    __shared__ float xs[8*H];
    for (int q = t; q < 8*H; q += 384) xs[q] = hv[row0*H + q];
    __syncthreads();
    const float* base;
    if (t < 128)      base = Wq + t;
    else if (t < 256) base = Wk + H*H + (t-128);
    else              base = Wv + H*H + (t-256);
    float acc[8];
#pragma unroll
    for (int r = 0; r < 8; r++) acc[r] = 0.f;
    for (int p = 0; p < H; p += 4) {
        float w0 = base[(p+0)*H];
        float w1 = base[(p+1)*H];
        float w2 = base[(p+2)*H];
        float w3 = base[(p+3)*H];
#pragma unroll
        for (int r = 0; r < 8; r++) {
            float4 x4 = *(const float4*)&xs[r*H+p];
            acc[r] += x4.x*w0 + x4.y*w1 + x4.z*w2 + x4.w*w3;
        }
    }
#pragma unroll
    for (int r = 0; r < 8; r++) P[(size_t)(row0+r)*384 + t] = acc[r];
}

// ---------------------------------------------------------------- attention: 2 nodes/block
__global__ __launch_bounds__(256) void attn_kernel(
    const __hip_bfloat16* __restrict__ E_ln, const __hip_bfloat16* __restrict__ Wt,
    const float* __restrict__ bias_kv,
    float* __restrict__ P, const int* __restrict__ E_idx,
    const float* __restrict__ mask)
{
    int g0 = blockIdx.x * 2;
    int t = threadIdx.x;
    __shared__ __hip_bfloat16 Ae[64*136];     // A tile, pitch 136 bf16
    __shared__ __hip_bfloat16 KVs[60*264];    // K|V rows, pitch 264 bf16
    __shared__ float Qs[2*H];
    __shared__ float att_s[2*120];
    __shared__ float mv_s[60];
    __shared__ int   nbr[60];

    const __hip_bfloat16* hebase = E_ln + (size_t)g0*KNB*H;
    for (int q = t; q < 960; q += 256) {
        int r = q >> 4, c8 = (q & 15) * 8;
        *(s8v*)&Ae[r*136 + c8] = *(const s8v*)&hebase[r*H + c8];
    }
    if (t < 60) {
        int gn = g0 + t/30;
        int b = gn / NN;
        int idx = E_idx[gn*KNB + (t%30)];
        nbr[t]  = b*NN + idx;
        mv_s[t] = mask[gn] * mask[b*NN + idx];
    }
    {
        int node = t >> 7, c = t & 127;
        Qs[t] = P[(size_t)(g0+node)*384 + c];
    }
    __syncthreads();

    // MFMA: wave w handles n-tiles 4w..4w+3, all 4 m-tiles
    {
        int wave = t >> 6, lane = t & 63;
        int lm = lane & 15, lq = lane >> 4;
        const __hip_bfloat16* wb = Wt + (size_t)(wave*64 + lm)*H + lq*8;
        s8v bfr[4][4];
#pragma unroll
        for (int nt = 0; nt < 4; nt++)
#pragma unroll
            for (int ks = 0; ks < 4; ks++)
                bfr[nt][ks] = *(const s8v*)(wb + nt*16*H + ks*32);
#pragma unroll
        for (int mt = 0; mt < 4; mt++) {
            f4v a0 = {0.f,0.f,0.f,0.f}, a1 = a0, a2 = a0, a3 = a0;
#pragma unroll
            for (int ks = 0; ks < 4; ks++) {
                s8v af = *(const s8v*)&Ae[(mt*16+lm)*136 + ks*32 + lq*8];
                a0 = __builtin_amdgcn_mfma_f32_16x16x32_bf16(af, bfr[0][ks], a0, 0,0,0);
                a1 = __builtin_amdgcn_mfma_f32_16x16x32_bf16(af, bfr[1][ks], a1, 0,0,0);
                a2 = __builtin_amdgcn_mfma_f32_16x16x32_bf16(af, bfr[2][ks], a2, 0,0,0);
                a3 = __builtin_amdgcn_mfma_f32_16x16x32_bf16(af, bfr[3][ks], a3, 0,0,0);
            }
            int rbase = mt*16 + lq*4;
            int cb = wave*64 + lm;
#pragma unroll
            for (int r = 0; r < 4; r++) {
                int row = rbase + r;
                if (row < 60) {
                    KVs[row*264 + cb     ] = __float2bfloat16(a0[r]);
                    KVs[row*264 + cb + 16] = __float2bfloat16(a1[r]);
                    KVs[row*264 + cb + 32] = __float2bfloat16(a2[r]);
                    KVs[row*264 + cb + 48] = __float2bfloat16(a3[r]);
                }
            }
        }
    }
    __syncthreads();

    // add folded bias + gathered node terms: K += bk + Pk[nbr], V += bv + Pv[nbr]
    {
        float addb = bias_kv[t];     // t<256 = column
        for (int r = 0; r < 60; r++) {
            int a = r*264 + t;
            float add = P[(size_t)nbr[r]*384 + 128 + t] + addb;
            KVs[a] = __float2bfloat16(__bfloat162float(KVs[a]) + add);
        }
    }
    __syncthreads();

    // logits
    if (t < 240) {
        int node = t / 120, tt = t % 120;
        int h = tt / 30, kk = tt % 30;
        int r = node*30 + kk;
        const unsigned* kp = (const unsigned*)&KVs[r*264 + h*32];
        const float* qp = &Qs[node*128 + h*32];
        float a = 0.f;
#pragma unroll
        for (int d = 0; d < 16; d++) {
            unsigned u = kp[d];
            a += qp[2*d]*bf_lo(u) + qp[2*d+1]*bf_hi(u);
        }
        att_s[node*120 + h*30 + kk] =
            (mv_s[r] > 0.f) ? a*0.17677669529663687f : -3.4028235e38f;
    }
    __syncthreads();
    if (t < 8) {
        int node = t >> 2, h = t & 3;
        float* ap = &att_s[node*120 + h*30];
        const float* mp = &mv_s[node*30];
        float mx = -3.4028235e38f;
        for (int kk = 0; kk < KNB; kk++) mx = fmaxf(mx, ap[kk]);
        float s = 0.f;
        for (int kk = 0; kk < KNB; kk++) s += __expf(ap[kk]-mx);
        float inv = 1.0f/s;
        for (int kk = 0; kk < KNB; kk++) ap[kk] = __expf(ap[kk]-mx)*inv*mp[kk];
    }
    __syncthreads();

    // upd = sum_k att * V; write into P Q-slots
    {
        int node = t >> 7, c = t & 127;
        const float* ap = &att_s[node*120 + (c>>5)*30];
        float u = 0.f;
        for (int kk = 0; kk < KNB; kk++)
            u += ap[kk] * __bfloat162float(KVs[(node*30+kk)*264 + 128 + c]);
        P[(size_t)(g0+node)*384 + c] = u;
    }
}

// ---------------------------------------------------------------- Wo + LN1 + FF + LN2 (+ next-layer node proj), MFMA
// hv updated IN-PLACE; if Wn_t != null, writes next layer's Q|Pk|Pv into P.
__global__ __launch_bounds__(256) void post_kernel(
    float* __restrict__ hv, float* __restrict__ P,
    const float* __restrict__ mask,
    const __hip_bfloat16* __restrict__ Wo_t,
    const float* __restrict__ ln1g, const float* __restrict__ ln1b,
    const float* __restrict__ ln2g, const float* __restrict__ ln2b,
    const __hip_bfloat16* __restrict__ Wf1_t, const float* __restrict__ bf1,
    const __hip_bfloat16* __restrict__ Wf2_t, const float* __restrict__ bf2,
    const __hip_bfloat16* __restrict__ Wn_t)
{
    int row0 = blockIdx.x * 16;
    int t = threadIdx.x;
    int wave = t >> 6, lane = t & 63, lm = lane & 15, lq = lane >> 4;

    __shared__ __hip_bfloat16 Aus[16*136];   // upd bf16
    __shared__ float xs[16*132];             // fp32 working rows
    __shared__ __hip_bfloat16 ys[16*136];    // LN1 out bf16
    __shared__ __hip_bfloat16 t1[16*520];    // relu(FF1) bf16
    __shared__ __hip_bfloat16 zs[16*136];    // hv_out bf16
    __shared__ float ps[256], pq[256];
    __shared__ float mu_s[16], rs_s[16];

    // 1. load upd (attn output, in P's Q slots)
    for (int q = t; q < 2048; q += 256) {
        int r = q >> 7, c = q & 127;
        Aus[r*136+c] = __float2bfloat16(P[(size_t)(row0+r)*384 + c]);
    }
    __syncthreads();

    // 2. x = hv + upd @ Wo
    for (int ntl = 0; ntl < 2; ntl++) {
        int nt = wave*2 + ntl;
        f4v acc = {0.f,0.f,0.f,0.f};
#pragma unroll
        for (int ks = 0; ks < 4; ks++) {
            s8v af = *(const s8v*)&Aus[lm*136 + ks*32 + lq*8];
            s8v bf = *(const s8v*)&Wo_t[(nt*16+lm)*128 + ks*32 + lq*8];
            acc = __builtin_amdgcn_mfma_f32_16x16x32_bf16(af, bf, acc, 0,0,0);
        }
        int cc = nt*16 + lm;
#pragma unroll
        for (int r = 0; r < 4; r++) {
            int rr = lq*4 + r;
            xs[rr*132+cc] = hv[(size_t)(row0+rr)*128 + cc] + acc[r];
        }
    }
    __syncthreads();

    // 3. LN1 -> xs (fp32) and ys (bf16)
    {
        int r = t >> 4, s = t & 15;
        float4 a = *(const float4*)&xs[r*132 + s*8];
        float4 b = *(const float4*)&xs[r*132 + s*8 + 4];
        ps[t] = a.x+a.y+a.z+a.w + b.x+b.y+b.z+b.w;
        pq[t] = a.x*a.x+a.y*a.y+a.z*a.z+a.w*a.w + b.x*b.x+b.y*b.y+b.z*b.z+b.w*b.w;
    }
    __syncthreads();
    if (t < 16) {
        float sm = 0.f, sq = 0.f;
        for (int s = 0; s < 16; s++) { sm += ps[t*16+s]; sq += pq[t*16+s]; }
        float mu = sm*(1.0f/H);
        mu_s[t] = mu;
        rs_s[t] = rsqrtf(sq*(1.0f/H) - mu*mu + LN_EPS);
    }
    __syncthreads();
    for (int q = t; q < 2048; q += 256) {
        int r = q >> 7, c = q & 127;
        float v = ln1g[c]*(xs[r*132+c]-mu_s[r])*rs_s[r] + ln1b[c];
        xs[r*132+c] = v;
        ys[r*136+c] = __float2bfloat16(v);
    }
    __syncthreads();

    // 4. FF1 + ReLU -> t1 (bf16)
    for (int ntl = 0; ntl < 8; ntl++) {
        int nt = wave*8 + ntl;
        f4v acc = {0.f,0.f,0.f,0.f};
#pragma unroll
        for (int ks = 0; ks < 4; ks++) {
            s8v af = *(const s8v*)&ys[lm*136 + ks*32 + lq*8];
            s8v bf = *(const s8v*)&Wf1_t[(size_t)(nt*16+lm)*128 + ks*32 + lq*8];
            acc = __builtin_amdgcn_mfma_f32_16x16x32_bf16(af, bf, acc, 0,0,0);
        }
        int cc = nt*16 + lm;
        float b = bf1[cc];
#pragma unroll
        for (int r = 0; r < 4; r++)
            t1[(lq*4+r)*520 + cc] = __float2bfloat16(fmaxf(acc[r]+b, 0.f));
    }
    __syncthreads();

    // 5. x2 = LN1out + FF2(t1) + b
    for (int ntl = 0; ntl < 2; ntl++) {
        int nt = wave*2 + ntl;
        f4v acc = {0.f,0.f,0.f,0.f};
#pragma unroll
        for (int ks = 0; ks < 16; ks++) {
            s8v af = *(const s8v*)&t1[lm*520 + ks*32 + lq*8];
            s8v bf = *(const s8v*)&Wf2_t[(size_t)(nt*16+lm)*512 + ks*32 + lq*8];
            acc = __builtin_amdgcn_mfma_f32_16x16x32_bf16(af, bf, acc, 0,0,0);
        }
        int cc = nt*16 + lm;
        float b = bf2[cc];
#pragma unroll
        for (int r = 0; r < 4; r++) {
            int rr = lq*4 + r;
            xs[rr*132+cc] = xs[rr*132+cc] + acc[r] + b;
        }
    }
    __syncthreads();

    // 6. LN2 + mask -> hv (global) and zs (bf16)
    {
        int r = t >> 4, s = t & 15;
        float4 a = *(const float4*)&xs[r*132 + s*8];
        float4 b = *(const float4*)&xs[r*132 + s*8 + 4];
        ps[t] = a.x+a.y+a.z+a.w + b.x+b.y+b.z+b.w;
        pq[t] = a.x*a.x+a.y*a.y+a.z*a.z+a.w*a.w + b.x*b.x+b.y*b.y+b.z*b.z+b.w*b.w;
    }
    __syncthreads();
    if (t < 16) {
        float sm = 0.f, sq = 0.f;
        for (int s = 0; s < 16; s++) { sm += ps[t*16+s]; sq += pq[t*16+s]; }
        float mu = sm*(1.0f/H);
        mu_s[t] = mu;
        rs_s[t] = rsqrtf(sq*(1.0f/H) - mu*mu + LN_EPS);
    }
    __syncthreads();
    for (int q = t; q < 2048; q += 256) {
        int r = q >> 7, c = q & 127;
        float v = mask[row0+r]*(ln2g[c]*(xs[r*132+c]-mu_s[r])*rs_s[r] + ln2b[c]);
        hv[(size_t)(row0+r)*128 + c] = v;
        zs[r*136+c] = __float2bfloat16(v);
    }
    __syncthreads();

    // 7. next-layer node projections: P = hv_out @ [Wq|Wk_bot|Wv_bot]
    if (Wn_t) {
        for (int ntl = 0; ntl < 6; ntl++) {
            int nt = wave*6 + ntl;
            f4v acc = {0.f,0.f,0.f,0.f};
#pragma unroll
            for (int ks = 0; ks < 4; ks++) {
                s8v af = *(const s8v*)&zs[lm*136 + ks*32 + lq*8];
                s8v bf = *(const s8v*)&Wn_t[(size_t)(nt*16+lm)*128 + ks*32 + lq*8];
                acc = __builtin_amdgcn_mfma_f32_16x16x32_bf16(af, bf, acc, 0,0,0);
            }
            int cc = nt*16 + lm;
#pragma unroll
            for (int r = 0; r < 4; r++)
                P[(size_t)(row0 + lq*4 + r)*384 + cc] = acc[r];
        }
    }
}

// ---------------------------------------------------------------- final projection
__global__ __launch_bounds__(64) void out_kernel(
    const float* __restrict__ hv, const float* __restrict__ W_out,
    const float* __restrict__ b_out, float* __restrict__ out)
{
    int row = blockIdx.x;
    int t = threadIdx.x;
    float a = hv[row*H+t]*W_out[t] + hv[row*H+t+64]*W_out[t+64];
#pragma unroll
    for (int s = 32; s > 0; s >>= 1) a += __shfl_down(a, s, 64);
    if (t == 0) out[row] = a + b_out[0];
}

// ---------------------------------------------------------------- launch
extern "C" void kernel_launch(void* const* d_in, const int* in_sizes, int n_in,
                              void* d_out, int out_size, void* d_ws, size_t ws_size,
                              hipStream_t stream)
{
    const float* X      = (const float*)d_in[0];
    const float* V      = (const float*)d_in[1];
    const float* mask   = (const float*)d_in[2];
    const float* W_v    = (const float*)d_in[3];
    const float* b_v    = (const float*)d_in[4];
    const float* W_e    = (const float*)d_in[5];
    const float* b_e    = (const float*)d_in[6];
    const float* W_edge = (const float*)d_in[7];
    const float* ln_e_g = (const float*)d_in[8];
    const float* ln_e_b = (const float*)d_in[9];
    const float* Wq     = (const float*)d_in[10];
    const float* Wk     = (const float*)d_in[11];
    const float* Wv_a   = (const float*)d_in[12];
    const float* Wo     = (const float*)d_in[13];
    const float* ln1g   = (const float*)d_in[14];
    const float* ln1b   = (const float*)d_in[15];
    const float* ln2g   = (const float*)d_in[16];
    const float* ln2b   = (const float*)d_in[17];
    const float* Wf1    = (const float*)d_in[18];
    const float* bf1    = (const float*)d_in[19];
    const float* Wf2    = (const float*)d_in[20];
    const float* bf2    = (const float*)d_in[21];
    const float* W_out  = (const float*)d_in[22];
    const float* b_out  = (const float*)d_in[23];
    float* out = (float*)d_out;

    // workspace layout:
    //   E_idx   :        0 ..   720,000   (int 180000)
    //   D_nb    :  720,000 .. 1,440,000   (f32 180000)
    //   E_ln    : 1,440,000 .. 47,520,000 (bf16 180000*128)
    //   hv      : 47,520,000 .. 50,592,000 (f32 6000*128, in-place across layers)
    //   Wt_kv   : 50,592,000 .. 50,854,144 (bf16 4*256*128)
    //   bias_kv : 50,854,144 .. 50,858,240 (f32 4*256)
    //   Wn_t    : 50,858,240 .. 51,251,456 (bf16 4*384*128)
    //   Wo_t    : 51,251,456 .. 51,382,528 (bf16 4*128*128)
    //   Wf1_t   : 51,382,528 .. 51,906,816 (bf16 4*512*128)
    //   Wf2_t   : 51,906,816 .. 52,431,104 (bf16 4*128*512)
    //   P       : 53,664,000 .. 62,880,000 (f32 6000*384: Q|Pk|Pv)
    char* ws = (char*)d_ws;
    int*            E_idx   = (int*)ws;
    float*          D_nb    = (float*)(ws + 720000);
    __hip_bfloat16* E_ln    = (__hip_bfloat16*)(ws + 1440000);
    float*          hv      = (float*)(ws + 47520000);
    __hip_bfloat16* Wt_kv   = (__hip_bfloat16*)(ws + 50592000);
    float*          bias_kv = (float*)(ws + 50854144);
    __hip_bfloat16* Wn_t    = (__hip_bfloat16*)(ws + 50858240);
    __hip_bfloat16* Wo_t    = (__hip_bfloat16*)(ws + 51251456);
    __hip_bfloat16* Wf1_t   = (__hip_bfloat16*)(ws + 51382528);
    __hip_bfloat16* Wf2_t   = (__hip_bfloat16*)(ws + 51906816);
    float*          P       = (float*)(ws + 53664000);

    topk_kernel<<<NROWS, 256, 0, stream>>>(X, mask, E_idx, D_nb);
    edge_kernel<<<NROWS, 128, 0, stream>>>(E_idx, D_nb, W_edge, ln_e_g, ln_e_b, E_ln);
    wprep_kv_kernel<<<1024, 128, 0, stream>>>(W_e, b_e, Wk, Wv_a, Wt_kv, bias_kv);
    wprep_post_kernel<<<3072, 256, 0, stream>>>(Wo, Wf1, Wf2, Wq, Wk, Wv_a,
                                                Wo_t, Wf1_t, Wf2_t, Wn_t);
    hv_init_kernel<<<NROWS/8, 128, 0, stream>>>(V, W_v, b_v, hv);
    node_proj_kernel<<<NROWS/8, 384, 0, stream>>>(hv, Wq, Wk, Wv_a, P);

    for (int l = 0; l < 4; l++) {
        attn_kernel<<<NROWS/2, 256, 0, stream>>>(
            E_ln, Wt_kv + (size_t)l*256*H, bias_kv + l*256, P, E_idx, mask);
        post_kernel<<<NROWS/16, 256, 0, stream>>>(
            hv, P, mask, Wo_t + l*16384,
            ln1g + l*H, ln1b + l*H, ln2g + l*H, ln2b + l*H,
            Wf1_t + (size_t)l*65536, bf1 + l*FFH,
            Wf2_t + (size_t)l*65536, bf2 + l*H,
            (l < 3) ? (Wn_t + (size_t)(l+1)*49152) : (const __hip_bfloat16*)nullptr);
    }
    out_kernel<<<NROWS, 64, 0, stream>>>(hv, W_out, b_out, out);
}

// Round 4
// 772.284 us; speedup vs baseline: 4.5230x; 1.1054x over previous
//
#include <hip/hip_runtime.h>
#include <hip/hip_bf16.h>
#include <math.h>

#define NB 4
#define NN 1500
#define KNB 30
#define H 128
#define NHEADS 4
#define FFH 512
#define NODE_FEAT 1024
#define NROWS (NB*NN)
#define LN_EPS 1e-6f

typedef __attribute__((ext_vector_type(8))) short s8v;   // 8 bf16 = 4 VGPRs (MFMA A/B frag)
typedef __attribute__((ext_vector_type(4))) float f4v;   // MFMA C/D frag

__device__ __forceinline__ float bf_lo(unsigned u){ union{unsigned i; float f;} v; v.i = u<<16; return v.f; }
__device__ __forceinline__ float bf_hi(unsigned u){ union{unsigned i; float f;} v; v.i = u & 0xffff0000u; return v.f; }

// ---------------------------------------------------------------- topk
// wave-hierarchical exact top-30 (min value, tie -> min index), ~3 barriers total
__global__ __launch_bounds__(256) void topk_kernel(
    const float* __restrict__ X, const float* __restrict__ mask,
    int* __restrict__ E_idx, float* __restrict__ D_nb)
{
    int row = blockIdx.x;            // b*NN + i
    int b = row / NN;
    int t = threadIdx.x;
    int wave = t >> 6, lane = t & 63;
    __shared__ float d_adj[NN];
    __shared__ float redw[4];
    __shared__ float cand_v[128];
    __shared__ int   cand_i[128];

    float xi0 = X[row*3+0], xi1 = X[row*3+1], xi2 = X[row*3+2];
    float mi = mask[row];

    // pass 1: masked distances + block max (wave shfl + 4-slot LDS)
    float lmax = -1e30f;
    for (int j = t; j < NN; j += 256) {
        float dx = xi0 - X[(b*NN+j)*3+0];
        float dy = xi1 - X[(b*NN+j)*3+1];
        float dz = xi2 - X[(b*NN+j)*3+2];
        float d  = sqrtf(dx*dx + dy*dy + dz*dz + 1e-6f);
        float m2 = mi * mask[b*NN+j];
        float dm = m2 * d;
        d_adj[j] = dm;
        lmax = fmaxf(lmax, dm);
    }
#pragma unroll
    for (int off = 32; off > 0; off >>= 1)
        lmax = fmaxf(lmax, __shfl_xor(lmax, off, 64));
    if (lane == 0) redw[wave] = lmax;
    if (t < 128) { cand_v[t] = 1e30f; cand_i[t] = 0x7fffffff; }
    __syncthreads();
    float rowmax = fmaxf(fmaxf(redw[0], redw[1]), fmaxf(redw[2], redw[3]));

    // pass 2: D_adj = D + (1-m2)*rowmax
    for (int j = t; j < NN; j += 256) {
        float m2 = mi * mask[b*NN+j];
        d_adj[j] = d_adj[j] + (1.0f - m2) * rowmax;
    }
    __syncthreads();

    // per-wave segment [wave*375, wave*375+375) -> registers (6 per lane)
    float v[6]; int jj[6];
    int jb = wave*375;
#pragma unroll
    for (int q = 0; q < 6; q++) {
        int rel = lane + q*64;
        bool ok = rel < 375;
        int j = jb + (ok ? rel : 0);
        v[q]  = ok ? d_adj[j] : 1e30f;
        jj[q] = ok ? j : 0x7fffffff;
    }

    // 30 wave-local argmin iterations (no barriers)
    for (int kk = 0; kk < KNB; kk++) {
        float bv = v[0]; int bj = jj[0];
#pragma unroll
        for (int q = 1; q < 6; q++)
            if (v[q] < bv || (v[q] == bv && jj[q] < bj)) { bv = v[q]; bj = jj[q]; }
#pragma unroll
        for (int off = 32; off > 0; off >>= 1) {
            float ov = __shfl_xor(bv, off, 64);
            int   oj = __shfl_xor(bj, off, 64);
            if (ov < bv || (ov == bv && oj < bj)) { bv = ov; bj = oj; }
        }
        if (lane == 0) { cand_v[wave*32+kk] = bv; cand_i[wave*32+kk] = bj; }
#pragma unroll
        for (int q = 0; q < 6; q++)
            if (jj[q] == bj) v[q] = 1e30f;
    }
    __syncthreads();

    // wave 0 merges 128 candidate slots (8 are +inf padding)
    if (wave == 0) {
        float m0 = cand_v[lane],    m1 = cand_v[lane+64];
        int   i0 = cand_i[lane],   i1 = cand_i[lane+64];
        for (int kk = 0; kk < KNB; kk++) {
            float bv; int bj;
            if (m0 < m1 || (m0 == m1 && i0 < i1)) { bv = m0; bj = i0; }
            else                                  { bv = m1; bj = i1; }
#pragma unroll
            for (int off = 32; off > 0; off >>= 1) {
                float ov = __shfl_xor(bv, off, 64);
                int   oj = __shfl_xor(bj, off, 64);
                if (ov < bv || (ov == bv && oj < bj)) { bv = ov; bj = oj; }
            }
            if (lane == 0) {
                E_idx[row*KNB+kk] = bv < 1e29f ? bj : 0;   // always real in practice
                D_nb[row*KNB+kk]  = bv;
            }
            if (i0 == bj) m0 = 1e30f;
            if (i1 == bj) m1 = 1e30f;
        }
    }
}

// ---------------------------------------------------------------- edge features -> E_ln (bf16)
// (W_e/b_e are algebraically folded into the per-layer K/V weights by wprep_kv)
__global__ __launch_bounds__(128) void edge_kernel(
    const int* __restrict__ E_idx, const float* __restrict__ D_nb,
    const float* __restrict__ W_edge, const float* __restrict__ ln_g,
    const float* __restrict__ ln_b, __hip_bfloat16* __restrict__ E_ln)
{
    int node = blockIdx.x;
    int i = node % NN;
    int t = threadIdx.x;             // 128 threads, t = output channel
    __shared__ float feat[KNB*32];
    __shared__ float eall[KNB*132];
    __shared__ float mu_s[KNB], rs_s[KNB];

    for (int q = t; q < KNB*32; q += 128) {
        int k = q >> 5, f = q & 31;
        int e = node*KNB + k;
        float val;
        if (f < 16) {
            int ff = f & 7;
            float drel = (float)E_idx[e] - (float)i;
            float fr = expf(-(float)ff * 1.15129254649702284f);
            float ang = drel * fr;
            val = (f < 8) ? cosf(ang) : sinf(ang);
        } else {
            float mu = (20.0f/15.0f) * (float)(f-16);
            float z = (D_nb[e] - mu) * 0.8f;
            val = expf(-z*z);
        }
        feat[q] = val;
    }
    __syncthreads();

    float acc[KNB];
#pragma unroll
    for (int k = 0; k < KNB; k++) acc[k] = 0.f;
    for (int p = 0; p < 32; p += 4) {
        float w0 = W_edge[(p+0)*H+t];
        float w1 = W_edge[(p+1)*H+t];
        float w2 = W_edge[(p+2)*H+t];
        float w3 = W_edge[(p+3)*H+t];
#pragma unroll
        for (int k = 0; k < KNB; k++) {
            float4 f4 = *(const float4*)&feat[k*32+p];
            acc[k] += f4.x*w0 + f4.y*w1 + f4.z*w2 + f4.w*w3;
        }
    }
#pragma unroll
    for (int k = 0; k < KNB; k++) eall[k*132+t] = acc[k];
    __syncthreads();

    if (t < KNB) {
        float s = 0.f;
        for (int c = 0; c < H; c++) s += eall[t*132+c];
        float mu = s * (1.0f/H);
        float v = 0.f;
        for (int c = 0; c < H; c++) { float d = eall[t*132+c] - mu; v += d*d; }
        mu_s[t] = mu;
        rs_s[t] = rsqrtf(v*(1.0f/H) + LN_EPS);
    }
    __syncthreads();
    float g = ln_g[t], bb = ln_b[t];
#pragma unroll
    for (int k = 0; k < KNB; k++)
        E_ln[(node*KNB+k)*H+t] =
            __float2bfloat16(g*(eall[k*132+t]-mu_s[k])*rs_s[k] + bb);
}

// ---------------------------------------------------------------- h_V = V @ W_v + b_v
__global__ __launch_bounds__(128) void hv_init_kernel(
    const float* __restrict__ V, const float* __restrict__ W_v,
    const float* __restrict__ b_v, float* __restrict__ hv)
{
    int row0 = blockIdx.x * 8;
    int t = threadIdx.x;
    __shared__ float vs[8*NODE_FEAT];
    for (int q = t; q < 8*NODE_FEAT; q += 128) vs[q] = V[row0*NODE_FEAT + q];
    __syncthreads();
    float acc[8];
#pragma unroll
    for (int r = 0; r < 8; r++) acc[r] = 0.f;
    for (int p = 0; p < NODE_FEAT; p += 4) {
        float w0 = W_v[(p+0)*H+t];
        float w1 = W_v[(p+1)*H+t];
        float w2 = W_v[(p+2)*H+t];
        float w3 = W_v[(p+3)*H+t];
#pragma unroll
        for (int r = 0; r < 8; r++) {
            float4 v4 = *(const float4*)&vs[r*NODE_FEAT+p];
            acc[r] += v4.x*w0 + v4.y*w1 + v4.z*w2 + v4.w*w3;
        }
    }
    float bv = b_v[t];
#pragma unroll
    for (int r = 0; r < 8; r++) hv[(row0+r)*H+t] = acc[r] + bv;
}

// ---------------------------------------------------------------- fold W_e into per-layer edge K/V:
// Wt_kv[l][n][k] = (W_e @ W{k,v}_top)[k][n]  (n<128: K, n>=128: V), bf16
// bias_kv[l][n]  = (b_e @ W{k,v}_top)[n]
__global__ __launch_bounds__(128) void wprep_kv_kernel(
    const float* __restrict__ W_e, const float* __restrict__ b_e,
    const float* __restrict__ Wk, const float* __restrict__ Wv,
    __hip_bfloat16* __restrict__ Wt_kv, float* __restrict__ bias_kv)
{
    int l = blockIdx.x >> 8;
    int n = blockIdx.x & 255;
    int t = threadIdx.x;             // t = k (0..127)
    int col = n & 127;
    const float* W = (n < 128) ? (Wk + l*2*H*H) : (Wv + l*2*H*H);
    __shared__ float wcol[128];
    wcol[t] = W[t*H + col];          // rows 0..127 = h_E block
    __syncthreads();
    float a = 0.f;
    for (int c = 0; c < H; c += 4) {
        float4 we = *(const float4*)&W_e[t*H + c];
        a += we.x*wcol[c] + we.y*wcol[c+1] + we.z*wcol[c+2] + we.w*wcol[c+3];
    }
    Wt_kv[(size_t)(l*256 + n)*H + t] = __float2bfloat16(a);
    if (t == 0) {
        float bsum = 0.f;
        for (int c = 0; c < H; c++) bsum += b_e[c]*wcol[c];
        bias_kv[l*256 + n] = bsum;
    }
}

// ---------------------------------------------------------------- transpose+cast weights to bf16 [n][k]:
// Wo_t[l][128][128], Wf1_t[l][512][128], Wf2_t[l][128][512], Wn_t[l][384][128] (Q|Kbot|Vbot)
__global__ __launch_bounds__(256) void wprep_post_kernel(
    const float* __restrict__ Wo, const float* __restrict__ Wf1,
    const float* __restrict__ Wf2, const float* __restrict__ Wq,
    const float* __restrict__ Wk, const float* __restrict__ Wv,
    __hip_bfloat16* __restrict__ Wo_t, __hip_bfloat16* __restrict__ Wf1_t,
    __hip_bfloat16* __restrict__ Wf2_t, __hip_bfloat16* __restrict__ Wn_t)
{
    int id = blockIdx.x*256 + threadIdx.x;   // < 786432
    int l = id / 196608;
    int r = id - l*196608;
    float v; __hip_bfloat16* dst;
    if (r < 16384) {
        int n = r >> 7, k = r & 127;
        v = Wo[l*16384 + k*128 + n];
        dst = Wo_t + l*16384 + r;
    } else if (r < 81920) {
        int rr = r - 16384;
        int n = rr >> 7, k = rr & 127;
        v = Wf1[l*65536 + k*512 + n];
        dst = Wf1_t + l*65536 + rr;
    } else if (r < 147456) {
        int rr = r - 81920;
        int n = rr >> 9, k = rr & 511;
        v = Wf2[l*65536 + k*128 + n];
        dst = Wf2_t + l*65536 + rr;
    } else {
        int rr = r - 147456;
        int n = rr >> 7, k = rr & 127;
        if (n < 128)      v = Wq[l*16384 + k*128 + n];
        else if (n < 256) v = Wk[l*32768 + (128+k)*128 + (n-128)];
        else              v = Wv[l*32768 + (128+k)*128 + (n-256)];
        dst = Wn_t + l*49152 + rr;
    }
    *dst = __float2bfloat16(v);
}

// ---------------------------------------------------------------- layer-0 node projections (fp32):
// P[row][0:128]=Q, [128:256]=Pk, [256:384]=Pv
__global__ __launch_bounds__(384) void node_proj_kernel(
    const float* __restrict__ hv, const float* __restrict__ Wq,
    const float* __restrict__ Wk, const float* __restrict__ Wv,
    float* __restrict__ P)
{
    int row0 = blockIdx.x * 8;
    int t = threadIdx.x;  // 0..383
    __shared__ float xs[8*H];
    for (int q = t; q < 8*H; q += 384) xs[q] = hv[row0*H + q];
    __syncthreads();
    const float* base;
    if (t < 128)      base = Wq + t;
    else if (t < 256) base = Wk + H*H + (t-128);
    else              base = Wv + H*H + (t-256);
    float acc[8];
#pragma unroll
    for (int r = 0; r < 8; r++) acc[r] = 0.f;
    for (int p = 0; p < H; p += 4) {
        float w0 = base[(p+0)*H];
        float w1 = base[(p+1)*H];
        float w2 = base[(p+2)*H];
        float w3 = base[(p+3)*H];
#pragma unroll
        for (int r = 0; r < 8; r++) {
            float4 x4 = *(const float4*)&xs[r*H+p];
            acc[r] += x4.x*w0 + x4.y*w1 + x4.z*w2 + x4.w*w3;
        }
    }
#pragma unroll
    for (int r = 0; r < 8; r++) P[(size_t)(row0+r)*384 + t] = acc[r];
}

// ---------------------------------------------------------------- attention: 2 nodes/block
// bias + node-term gather fused into MFMA epilogue (single bf16 rounding).
__global__ __launch_bounds__(256) void attn_kernel(
    const __hip_bfloat16* __restrict__ E_ln, const __hip_bfloat16* __restrict__ Wt,
    const float* __restrict__ bias_kv,
    float* __restrict__ P, const int* __restrict__ E_idx,
    const float* __restrict__ mask)
{
    int g0 = blockIdx.x * 2;
    int t = threadIdx.x;
    __shared__ __hip_bfloat16 Ae[64*136];     // A tile, pitch 136 bf16
    __shared__ __hip_bfloat16 KVs[60*264];    // K|V rows, pitch 264 bf16
    __shared__ float Qs[2*H];
    __shared__ float att_s[2*120];
    __shared__ float mv_s[60];
    __shared__ int   nbr[60];

    const __hip_bfloat16* hebase = E_ln + (size_t)g0*KNB*H;
    for (int q = t; q < 960; q += 256) {
        int r = q >> 4, c8 = (q & 15) * 8;
        *(s8v*)&Ae[r*136 + c8] = *(const s8v*)&hebase[r*H + c8];
    }
    if (t < 60) {
        int gn = g0 + t/30;
        int b = gn / NN;
        int idx = E_idx[gn*KNB + (t%30)];
        nbr[t]  = b*NN + idx;
        mv_s[t] = mask[gn] * mask[b*NN + idx];
    }
    {
        int node = t >> 7, c = t & 127;
        Qs[t] = P[(size_t)(g0+node)*384 + c];
    }
    __syncthreads();

    // MFMA: wave w handles n-tiles 4w..4w+3, all 4 m-tiles; epilogue fuses bias+gather
    {
        int wave = t >> 6, lane = t & 63;
        int lm = lane & 15, lq = lane >> 4;
        int cb = wave*64 + lm;
        const __hip_bfloat16* wb = Wt + (size_t)cb*H + lq*8;
        s8v bfr[4][4];
#pragma unroll
        for (int nt = 0; nt < 4; nt++)
#pragma unroll
            for (int ks = 0; ks < 4; ks++)
                bfr[nt][ks] = *(const s8v*)(wb + nt*16*H + ks*32);
        float bias0 = bias_kv[cb], bias1 = bias_kv[cb+16];
        float bias2 = bias_kv[cb+32], bias3 = bias_kv[cb+48];
#pragma unroll
        for (int mt = 0; mt < 4; mt++) {
            f4v a0 = {0.f,0.f,0.f,0.f}, a1 = a0, a2 = a0, a3 = a0;
#pragma unroll
            for (int ks = 0; ks < 4; ks++) {
                s8v af = *(const s8v*)&Ae[(mt*16+lm)*136 + ks*32 + lq*8];
                a0 = __builtin_amdgcn_mfma_f32_16x16x32_bf16(af, bfr[0][ks], a0, 0,0,0);
                a1 = __builtin_amdgcn_mfma_f32_16x16x32_bf16(af, bfr[1][ks], a1, 0,0,0);
                a2 = __builtin_amdgcn_mfma_f32_16x16x32_bf16(af, bfr[2][ks], a2, 0,0,0);
                a3 = __builtin_amdgcn_mfma_f32_16x16x32_bf16(af, bfr[3][ks], a3, 0,0,0);
            }
            int rbase = mt*16 + lq*4;
#pragma unroll
            for (int r = 0; r < 4; r++) {
                int row = rbase + r;
                if (row < 60) {
                    const float* pb = P + (size_t)nbr[row]*384 + 128 + cb;
                    KVs[row*264 + cb     ] = __float2bfloat16(a0[r] + bias0 + pb[0]);
                    KVs[row*264 + cb + 16] = __float2bfloat16(a1[r] + bias1 + pb[16]);
                    KVs[row*264 + cb + 32] = __float2bfloat16(a2[r] + bias2 + pb[32]);
                    KVs[row*264 + cb + 48] = __float2bfloat16(a3[r] + bias3 + pb[48]);
                }
            }
        }
    }
    __syncthreads();

    // logits (b128 LDS reads)
    if (t < 240) {
        int node = t / 120, tt = t % 120;
        int h = tt / 30, kk = tt % 30;
        int r = node*30 + kk;
        const uint4* kp = (const uint4*)&KVs[r*264 + h*32];
        const float* qp = &Qs[node*128 + h*32];
        float a = 0.f;
#pragma unroll
        for (int j = 0; j < 4; j++) {
            uint4 u = kp[j];
            const float* q8 = qp + j*8;
            a += q8[0]*bf_lo(u.x) + q8[1]*bf_hi(u.x)
               + q8[2]*bf_lo(u.y) + q8[3]*bf_hi(u.y)
               + q8[4]*bf_lo(u.z) + q8[5]*bf_hi(u.z)
               + q8[6]*bf_lo(u.w) + q8[7]*bf_hi(u.w);
        }
        att_s[node*120 + h*30 + kk] =
            (mv_s[r] > 0.f) ? a*0.17677669529663687f : -3.4028235e38f;
    }
    __syncthreads();
    if (t < 8) {
        int node = t >> 2, h = t & 3;
        float* ap = &att_s[node*120 + h*30];
        const float* mp = &mv_s[node*30];
        float mx = -3.4028235e38f;
        for (int kk = 0; kk < KNB; kk++) mx = fmaxf(mx, ap[kk]);
        float s = 0.f;
        for (int kk = 0; kk < KNB; kk++) s += __expf(ap[kk]-mx);
        float inv = 1.0f/s;
        for (int kk = 0; kk < KNB; kk++) ap[kk] = __expf(ap[kk]-mx)*inv*mp[kk];
    }
    __syncthreads();

    // upd = sum_k att * V; write into P Q-slots
    {
        int node = t >> 7, c = t & 127;
        const float* ap = &att_s[node*120 + (c>>5)*30];
        float u = 0.f;
        for (int kk = 0; kk < KNB; kk++)
            u += ap[kk] * __bfloat162float(KVs[(node*30+kk)*264 + 128 + c]);
        P[(size_t)(g0+node)*384 + c] = u;
    }
}

// ---------------------------------------------------------------- Wo + LN1 + FF + LN2 (+ next-layer node proj), MFMA
// hv updated IN-PLACE; if Wn_t != null, writes next layer's Q|Pk|Pv into P.
__global__ __launch_bounds__(256) void post_kernel(
    float* __restrict__ hv, float* __restrict__ P,
    const float* __restrict__ mask,
    const __hip_bfloat16* __restrict__ Wo_t,
    const float* __restrict__ ln1g, const float* __restrict__ ln1b,
    const float* __restrict__ ln2g, const float* __restrict__ ln2b,
    const __hip_bfloat16* __restrict__ Wf1_t, const float* __restrict__ bf1,
    const __hip_bfloat16* __restrict__ Wf2_t, const float* __restrict__ bf2,
    const __hip_bfloat16* __restrict__ Wn_t)
{
    int row0 = blockIdx.x * 16;
    int t = threadIdx.x;
    int wave = t >> 6, lane = t & 63, lm = lane & 15, lq = lane >> 4;

    __shared__ __hip_bfloat16 Aus[16*136];   // upd bf16
    __shared__ float xs[16*132];             // fp32 working rows
    __shared__ __hip_bfloat16 ys[16*136];    // LN1 out bf16
    __shared__ __hip_bfloat16 t1[16*520];    // relu(FF1) bf16
    __shared__ __hip_bfloat16 zs[16*136];    // hv_out bf16
    __shared__ float ps[256], pq[256];
    __shared__ float mu_s[16], rs_s[16];

    // 1. load upd (attn output, in P's Q slots)
    for (int q = t; q < 2048; q += 256) {
        int r = q >> 7, c = q & 127;
        Aus[r*136+c] = __float2bfloat16(P[(size_t)(row0+r)*384 + c]);
    }
    __syncthreads();

    // 2. x = hv + upd @ Wo
    for (int ntl = 0; ntl < 2; ntl++) {
        int nt = wave*2 + ntl;
        f4v acc = {0.f,0.f,0.f,0.f};
#pragma unroll
        for (int ks = 0; ks < 4; ks++) {
            s8v af = *(const s8v*)&Aus[lm*136 + ks*32 + lq*8];
            s8v bf = *(const s8v*)&Wo_t[(nt*16+lm)*128 + ks*32 + lq*8];
            acc = __builtin_amdgcn_mfma_f32_16x16x32_bf16(af, bf, acc, 0,0,0);
        }
        int cc = nt*16 + lm;
#pragma unroll
        for (int r = 0; r < 4; r++) {
            int rr = lq*4 + r;
            xs[rr*132+cc] = hv[(size_t)(row0+rr)*128 + cc] + acc[r];
        }
    }
    __syncthreads();

    // 3. LN1 -> xs (fp32) and ys (bf16)
    {
        int r = t >> 4, s = t & 15;
        float4 a = *(const float4*)&xs[r*132 + s*8];
        float4 b = *(const float4*)&xs[r*132 + s*8 + 4];
        ps[t] = a.x+a.y+a.z+a.w + b.x+b.y+b.z+b.w;
        pq[t] = a.x*a.x+a.y*a.y+a.z*a.z+a.w*a.w + b.x*b.x+b.y*b.y+b.z*b.z+b.w*b.w;
    }
    __syncthreads();
    if (t < 16) {
        float sm = 0.f, sq = 0.f;
        for (int s = 0; s < 16; s++) { sm += ps[t*16+s]; sq += pq[t*16+s]; }
        float mu = sm*(1.0f/H);
        mu_s[t] = mu;
        rs_s[t] = rsqrtf(sq*(1.0f/H) - mu*mu + LN_EPS);
    }
    __syncthreads();
    for (int q = t; q < 2048; q += 256) {
        int r = q >> 7, c = q & 127;
        float v = ln1g[c]*(xs[r*132+c]-mu_s[r])*rs_s[r] + ln1b[c];
        xs[r*132+c] = v;
        ys[r*136+c] = __float2bfloat16(v);
    }
    __syncthreads();

    // 4. FF1 + ReLU -> t1 (bf16)
    for (int ntl = 0; ntl < 8; ntl++) {
        int nt = wave*8 + ntl;
        f4v acc = {0.f,0.f,0.f,0.f};
#pragma unroll
        for (int ks = 0; ks < 4; ks++) {
            s8v af = *(const s8v*)&ys[lm*136 + ks*32 + lq*8];
            s8v bf = *(const s8v*)&Wf1_t[(size_t)(nt*16+lm)*128 + ks*32 + lq*8];
            acc = __builtin_amdgcn_mfma_f32_16x16x32_bf16(af, bf, acc, 0,0,0);
        }
        int cc = nt*16 + lm;
        float b = bf1[cc];
#pragma unroll
        for (int r = 0; r < 4; r++)
            t1[(lq*4+r)*520 + cc] = __float2bfloat16(fmaxf(acc[r]+b, 0.f));
    }
    __syncthreads();

    // 5. x2 = LN1out + FF2(t1) + b
    for (int ntl = 0; ntl < 2; ntl++) {
        int nt = wave*2 + ntl;
        f4v acc = {0.f,0.f,0.f,0.f};
#pragma unroll
        for (int ks = 0; ks < 16; ks++) {
            s8v af = *(const s8v*)&t1[lm*520 + ks*32 + lq*8];
            s8v bf = *(const s8v*)&Wf2_t[(size_t)(nt*16+lm)*512 + ks*32 + lq*8];
            acc = __builtin_amdgcn_mfma_f32_16x16x32_bf16(af, bf, acc, 0,0,0);
        }
        int cc = nt*16 + lm;
        float b = bf2[cc];
#pragma unroll
        for (int r = 0; r < 4; r++) {
            int rr = lq*4 + r;
            xs[rr*132+cc] = xs[rr*132+cc] + acc[r] + b;
        }
    }
    __syncthreads();

    // 6. LN2 + mask -> hv (global) and zs (bf16)
    {
        int r = t >> 4, s = t & 15;
        float4 a = *(const float4*)&xs[r*132 + s*8];
        float4 b = *(const float4*)&xs[r*132 + s*8 + 4];
        ps[t] = a.x+a.y+a.z+a.w + b.x+b.y+b.z+b.w;
        pq[t] = a.x*a.x+a.y*a.y+a.z*a.z+a.w*a.w + b.x*b.x+b.y*b.y+b.z*b.z+b.w*b.w;
    }
    __syncthreads();
    if (t < 16) {
        float sm = 0.f, sq = 0.f;
        for (int s = 0; s < 16; s++) { sm += ps[t*16+s]; sq += pq[t*16+s]; }
        float mu = sm*(1.0f/H);
        mu_s[t] = mu;
        rs_s[t] = rsqrtf(sq*(1.0f/H) - mu*mu + LN_EPS);
    }
    __syncthreads();
    for (int q = t; q < 2048; q += 256) {
        int r = q >> 7, c = q & 127;
        float v = mask[row0+r]*(ln2g[c]*(xs[r*132+c]-mu_s[r])*rs_s[r] + ln2b[c]);
        hv[(size_t)(row0+r)*128 + c] = v;
        zs[r*136+c] = __float2bfloat16(v);
    }
    __syncthreads();

    // 7. next-layer node projections: P = hv_out @ [Wq|Wk_bot|Wv_bot]
    if (Wn_t) {
        for (int ntl = 0; ntl < 6; ntl++) {
            int nt = wave*6 + ntl;
            f4v acc = {0.f,0.f,0.f,0.f};
#pragma unroll
            for (int ks = 0; ks < 4; ks++) {
                s8v af = *(const s8v*)&zs[lm*136 + ks*32 + lq*8];
                s8v bf = *(const s8v*)&Wn_t[(size_t)(nt*16+lm)*128 + ks*32 + lq*8];
                acc = __builtin_amdgcn_mfma_f32_16x16x32_bf16(af, bf, acc, 0,0,0);
            }
            int cc = nt*16 + lm;
#pragma unroll
            for (int r = 0; r < 4; r++)
                P[(size_t)(row0 + lq*4 + r)*384 + cc] = acc[r];
        }
    }
}

// ---------------------------------------------------------------- final projection
__global__ __launch_bounds__(64) void out_kernel(
    const float* __restrict__ hv, const float* __restrict__ W_out,
    const float* __restrict__ b_out, float* __restrict__ out)
{
    int row = blockIdx.x;
    int t = threadIdx.x;
    float a = hv[row*H+t]*W_out[t] + hv[row*H+t+64]*W_out[t+64];
#pragma unroll
    for (int s = 32; s > 0; s >>= 1) a += __shfl_down(a, s, 64);
    if (t == 0) out[row] = a + b_out[0];
}

// ---------------------------------------------------------------- launch
extern "C" void kernel_launch(void* const* d_in, const int* in_sizes, int n_in,
                              void* d_out, int out_size, void* d_ws, size_t ws_size,
                              hipStream_t stream)
{
    const float* X      = (const float*)d_in[0];
    const float* V      = (const float*)d_in[1];
    const float* mask   = (const float*)d_in[2];
    const float* W_v    = (const float*)d_in[3];
    const float* b_v    = (const float*)d_in[4];
    const float* W_e    = (const float*)d_in[5];
    const float* b_e    = (const float*)d_in[6];
    const float* W_edge = (const float*)d_in[7];
    const float* ln_e_g = (const float*)d_in[8];
    const float* ln_e_b = (const float*)d_in[9];
    const float* Wq     = (const float*)d_in[10];
    const float* Wk     = (const float*)d_in[11];
    const float* Wv_a   = (const float*)d_in[12];
    const float* Wo     = (const float*)d_in[13];
    const float* ln1g   = (const float*)d_in[14];
    const float* ln1b   = (const float*)d_in[15];
    const float* ln2g   = (const float*)d_in[16];
    const float* ln2b   = (const float*)d_in[17];
    const float* Wf1    = (const float*)d_in[18];
    const float* bf1    = (const float*)d_in[19];
    const float* Wf2    = (const float*)d_in[20];
    const float* bf2    = (const float*)d_in[21];
    const float* W_out  = (const float*)d_in[22];
    const float* b_out  = (const float*)d_in[23];
    float* out = (float*)d_out;

    // workspace layout (same as R3)
    char* ws = (char*)d_ws;
    int*            E_idx   = (int*)ws;
    float*          D_nb    = (float*)(ws + 720000);
    __hip_bfloat16* E_ln    = (__hip_bfloat16*)(ws + 1440000);
    float*          hv      = (float*)(ws + 47520000);
    __hip_bfloat16* Wt_kv   = (__hip_bfloat16*)(ws + 50592000);
    float*          bias_kv = (float*)(ws + 50854144);
    __hip_bfloat16* Wn_t    = (__hip_bfloat16*)(ws + 50858240);
    __hip_bfloat16* Wo_t    = (__hip_bfloat16*)(ws + 51251456);
    __hip_bfloat16* Wf1_t   = (__hip_bfloat16*)(ws + 51382528);
    __hip_bfloat16* Wf2_t   = (__hip_bfloat16*)(ws + 51906816);
    float*          P       = (float*)(ws + 53664000);

    topk_kernel<<<NROWS, 256, 0, stream>>>(X, mask, E_idx, D_nb);
    edge_kernel<<<NROWS, 128, 0, stream>>>(E_idx, D_nb, W_edge, ln_e_g, ln_e_b, E_ln);
    wprep_kv_kernel<<<1024, 128, 0, stream>>>(W_e, b_e, Wk, Wv_a, Wt_kv, bias_kv);
    wprep_post_kernel<<<3072, 256, 0, stream>>>(Wo, Wf1, Wf2, Wq, Wk, Wv_a,
                                                Wo_t, Wf1_t, Wf2_t, Wn_t);
    hv_init_kernel<<<NROWS/8, 128, 0, stream>>>(V, W_v, b_v, hv);
    node_proj_kernel<<<NROWS/8, 384, 0, stream>>>(hv, Wq, Wk, Wv_a, P);

    for (int l = 0; l < 4; l++) {
        attn_kernel<<<NROWS/2, 256, 0, stream>>>(
            E_ln, Wt_kv + (size_t)l*256*H, bias_kv + l*256, P, E_idx, mask);
        post_kernel<<<NROWS/16, 256, 0, stream>>>(
            hv, P, mask, Wo_t + l*16384,
            ln1g + l*H, ln1b + l*H, ln2g + l*H, ln2b + l*H,
            Wf1_t + (size_t)l*65536, bf1 + l*FFH,
            Wf2_t + (size_t)l*65536, bf2 + l*H,
            (l < 3) ? (Wn_t + (size_t)(l+1)*49152) : (const __hip_bfloat16*)nullptr);
    }
    out_kernel<<<NROWS, 64, 0, stream>>>(hv, W_out, b_out, out);
}

// Round 5
// 650.792 us; speedup vs baseline: 5.3673x; 1.1867x over previous
//
#include <hip/hip_runtime.h>
#include <hip/hip_bf16.h>
#include <math.h>

#define NB 4
#define NN 1500
#define KNB 30
#define H 128
#define NHEADS 4
#define FFH 512
#define NODE_FEAT 1024
#define NROWS (NB*NN)
#define LN_EPS 1e-6f

typedef __attribute__((ext_vector_type(8))) short s8v;   // 8 bf16 = 4 VGPRs (MFMA A/B frag)
typedef __attribute__((ext_vector_type(4))) float f4v;   // MFMA C/D frag

__device__ __forceinline__ float bf_lo(unsigned u){ union{unsigned i; float f;} v; v.i = u<<16; return v.f; }
__device__ __forceinline__ float bf_hi(unsigned u){ union{unsigned i; float f;} v; v.i = u & 0xffff0000u; return v.f; }

// ---------------------------------------------------------------- topk (radix select)
// hist is stored bucket-transposed: bucket b lives at LDS index ((b&15)<<8)|(b>>4)
// so thread t's 16 contiguous buckets [16t,16t+16) are read at (i<<8)|t -> conflict-free.
__device__ __forceinline__ void find_bucket30(
    const int* hist, int base0, int t, int lane, int wave,
    int* wsum, int* res)
{
    int h[16], s = 0;
#pragma unroll
    for (int i = 0; i < 16; i++) { h[i] = hist[(i<<8)|t]; s += h[i]; }
    int inc = s;
#pragma unroll
    for (int off = 1; off < 64; off <<= 1) {
        int o = __shfl_up(inc, off, 64);
        if (lane >= off) inc += o;
    }
    if (lane == 63) wsum[wave] = inc;
    __syncthreads();
    int base = base0 + inc - s;
    for (int w = 0; w < wave; w++) base += wsum[w];
    if (base < KNB && base + s >= KNB) {
        int running = base;
#pragma unroll
        for (int i = 0; i < 16; i++) {
            if (running < KNB && running + h[i] >= KNB) { res[0] = (t<<4)|i; res[1] = running; break; }
            running += h[i];
        }
    }
    __syncthreads();
}

__global__ __launch_bounds__(256) void topk_kernel(
    const float* __restrict__ X, const float* __restrict__ mask,
    int* __restrict__ E_idx, float* __restrict__ D_nb)
{
    int row = blockIdx.x;            // b*NN + i
    int b = row / NN;
    int t = threadIdx.x;
    int wave = t >> 6, lane = t & 63;
    __shared__ float d_adj[NN];
    __shared__ int   hist[4096];
    __shared__ float redw[4];
    __shared__ int   wsum[4];
    __shared__ int   res[2];
    __shared__ int   cand[64];
    __shared__ int   ncand;

    float xi0 = X[row*3+0], xi1 = X[row*3+1], xi2 = X[row*3+2];
    float mi = mask[row];

    // pass 1: distances (kept in regs), block max
    float dr[6], m2r[6];
    float lmax = -1e30f;
#pragma unroll
    for (int q = 0; q < 6; q++) {
        int j = t + q*256;
        float d = 0.f, m2 = 0.f;
        if (j < NN) {
            float dx = xi0 - X[(b*NN+j)*3+0];
            float dy = xi1 - X[(b*NN+j)*3+1];
            float dz = xi2 - X[(b*NN+j)*3+2];
            d  = sqrtf(dx*dx + dy*dy + dz*dz + 1e-6f);
            m2 = mi * mask[b*NN+j];
            lmax = fmaxf(lmax, m2*d);
        }
        dr[q] = d; m2r[q] = m2;
    }
    for (int q = t; q < 4096; q += 256) hist[q] = 0;
#pragma unroll
    for (int off = 32; off > 0; off >>= 1)
        lmax = fmaxf(lmax, __shfl_xor(lmax, off, 64));
    if (lane == 0) redw[wave] = lmax;
    if (t == 0) ncand = 0;
    __syncthreads();
    float rowmax = fmaxf(fmaxf(redw[0], redw[1]), fmaxf(redw[2], redw[3]));

    // finalize d_adj, write LDS, histogram top 12 bits
    unsigned kreg[6];
#pragma unroll
    for (int q = 0; q < 6; q++) {
        int j = t + q*256;
        if (j < NN) {
            float dv = m2r[q]*dr[q] + (1.0f - m2r[q])*rowmax;   // >= 0
            d_adj[j] = dv;
            unsigned key = __float_as_uint(dv);
            kreg[q] = key;
            unsigned bkt = key >> 20;
            atomicAdd(&hist[((bkt & 15) << 8) | (bkt >> 4)], 1);
        } else kreg[q] = 0xFFFFFFFFu;
    }
    __syncthreads();

    find_bucket30(hist, 0, t, lane, wave, wsum, res);
    int B1 = res[0], nb1 = res[1];

    // pass 2: refine next 12 bits within group B1
    for (int q = t; q < 4096; q += 256) hist[q] = 0;
    __syncthreads();
#pragma unroll
    for (int q = 0; q < 6; q++) {
        if ((kreg[q] >> 20) == (unsigned)B1) {
            unsigned bkt = (kreg[q] >> 8) & 0xFFF;
            atomicAdd(&hist[((bkt & 15) << 8) | (bkt >> 4)], 1);
        }
    }
    __syncthreads();

    find_bucket30(hist, nb1, t, lane, wave, wsum, res);
    unsigned Bfull = ((unsigned)B1 << 12) | (unsigned)res[0];   // 24-bit prefix of 30th value

    // collect candidates (all elements with 24-bit prefix <= Bfull); generically ~31
#pragma unroll
    for (int q = 0; q < 6; q++) {
        if ((kreg[q] >> 8) <= Bfull) {
            int slot = atomicAdd(&ncand, 1);
            if (slot < 64) cand[slot] = t + q*256;
        }
    }
    __syncthreads();

    // wave 0: exact rank sort of candidates, (value, index) lexicographic (= jax top_k order)
    if (wave == 0) {
        int nc = min(ncand, 64);
        if (lane < nc) {
            int j = cand[lane];
            float v = d_adj[j];
            int rank = 0;
            for (int m = 0; m < nc; m++) {
                int jm = cand[m];
                float vm = d_adj[jm];
                rank += (vm < v || (vm == v && jm < j)) ? 1 : 0;
            }
            if (rank < KNB) {
                E_idx[row*KNB + rank] = j;
                D_nb[row*KNB + rank]  = v;
            }
        }
    }
}

// ---------------------------------------------------------------- edge features -> E_ln (bf16)
// (W_e/b_e are algebraically folded into the per-layer K/V weights by wprep_kv)
__global__ __launch_bounds__(128) void edge_kernel(
    const int* __restrict__ E_idx, const float* __restrict__ D_nb,
    const float* __restrict__ W_edge, const float* __restrict__ ln_g,
    const float* __restrict__ ln_b, __hip_bfloat16* __restrict__ E_ln)
{
    int node = blockIdx.x;
    int i = node % NN;
    int t = threadIdx.x;             // 128 threads, t = output channel
    __shared__ float feat[KNB*32];
    __shared__ float eall[KNB*132];
    __shared__ float mu_s[KNB], rs_s[KNB];

    for (int q = t; q < KNB*32; q += 128) {
        int k = q >> 5, f = q & 31;
        int e = node*KNB + k;
        float val;
        if (f < 16) {
            int ff = f & 7;
            float drel = (float)E_idx[e] - (float)i;
            float fr = expf(-(float)ff * 1.15129254649702284f);
            float ang = drel * fr;
            val = (f < 8) ? cosf(ang) : sinf(ang);
        } else {
            float mu = (20.0f/15.0f) * (float)(f-16);
            float z = (D_nb[e] - mu) * 0.8f;
            val = expf(-z*z);
        }
        feat[q] = val;
    }
    __syncthreads();

    float acc[KNB];
#pragma unroll
    for (int k = 0; k < KNB; k++) acc[k] = 0.f;
    for (int p = 0; p < 32; p += 4) {
        float w0 = W_edge[(p+0)*H+t];
        float w1 = W_edge[(p+1)*H+t];
        float w2 = W_edge[(p+2)*H+t];
        float w3 = W_edge[(p+3)*H+t];
#pragma unroll
        for (int k = 0; k < KNB; k++) {
            float4 f4 = *(const float4*)&feat[k*32+p];
            acc[k] += f4.x*w0 + f4.y*w1 + f4.z*w2 + f4.w*w3;
        }
    }
#pragma unroll
    for (int k = 0; k < KNB; k++) eall[k*132+t] = acc[k];
    __syncthreads();

    if (t < KNB) {
        float s = 0.f;
        for (int c = 0; c < H; c++) s += eall[t*132+c];
        float mu = s * (1.0f/H);
        float v = 0.f;
        for (int c = 0; c < H; c++) { float d = eall[t*132+c] - mu; v += d*d; }
        mu_s[t] = mu;
        rs_s[t] = rsqrtf(v*(1.0f/H) + LN_EPS);
    }
    __syncthreads();
    float g = ln_g[t], bb = ln_b[t];
#pragma unroll
    for (int k = 0; k < KNB; k++)
        E_ln[(node*KNB+k)*H+t] =
            __float2bfloat16(g*(eall[k*132+t]-mu_s[k])*rs_s[k] + bb);
}

// ---------------------------------------------------------------- h_V = V @ W_v + b_v
__global__ __launch_bounds__(128) void hv_init_kernel(
    const float* __restrict__ V, const float* __restrict__ W_v,
    const float* __restrict__ b_v, float* __restrict__ hv)
{
    int row0 = blockIdx.x * 8;
    int t = threadIdx.x;
    __shared__ float vs[8*NODE_FEAT];
    for (int q = t; q < 8*NODE_FEAT; q += 128) vs[q] = V[row0*NODE_FEAT + q];
    __syncthreads();
    float acc[8];
#pragma unroll
    for (int r = 0; r < 8; r++) acc[r] = 0.f;
    for (int p = 0; p < NODE_FEAT; p += 4) {
        float w0 = W_v[(p+0)*H+t];
        float w1 = W_v[(p+1)*H+t];
        float w2 = W_v[(p+2)*H+t];
        float w3 = W_v[(p+3)*H+t];
#pragma unroll
        for (int r = 0; r < 8; r++) {
            float4 v4 = *(const float4*)&vs[r*NODE_FEAT+p];
            acc[r] += v4.x*w0 + v4.y*w1 + v4.z*w2 + v4.w*w3;
        }
    }
    float bv = b_v[t];
#pragma unroll
    for (int r = 0; r < 8; r++) hv[(row0+r)*H+t] = acc[r] + bv;
}

// ---------------------------------------------------------------- fold W_e into per-layer edge K/V:
// Wt_kv[l][n][k] = (W_e @ W{k,v}_top)[k][n]  (n<128: K, n>=128: V), bf16
// bias_kv[l][n]  = (b_e @ W{k,v}_top)[n]
__global__ __launch_bounds__(128) void wprep_kv_kernel(
    const float* __restrict__ W_e, const float* __restrict__ b_e,
    const float* __restrict__ Wk, const float* __restrict__ Wv,
    __hip_bfloat16* __restrict__ Wt_kv, float* __restrict__ bias_kv)
{
    int l = blockIdx.x >> 8;
    int n = blockIdx.x & 255;
    int t = threadIdx.x;             // t = k (0..127)
    int col = n & 127;
    const float* W = (n < 128) ? (Wk + l*2*H*H) : (Wv + l*2*H*H);
    __shared__ float wcol[128];
    wcol[t] = W[t*H + col];          // rows 0..127 = h_E block
    __syncthreads();
    float a = 0.f;
    for (int c = 0; c < H; c += 4) {
        float4 we = *(const float4*)&W_e[t*H + c];
        a += we.x*wcol[c] + we.y*wcol[c+1] + we.z*wcol[c+2] + we.w*wcol[c+3];
    }
    Wt_kv[(size_t)(l*256 + n)*H + t] = __float2bfloat16(a);
    if (t == 0) {
        float bsum = 0.f;
        for (int c = 0; c < H; c++) bsum += b_e[c]*wcol[c];
        bias_kv[l*256 + n] = bsum;
    }
}

// ---------------------------------------------------------------- transpose+cast weights to bf16 [n][k]:
// Wo_t[l][128][128], Wf1_t[l][512][128], Wf2_t[l][128][512], Wn_t[l][384][128] (Q|Kbot|Vbot)
__global__ __launch_bounds__(256) void wprep_post_kernel(
    const float* __restrict__ Wo, const float* __restrict__ Wf1,
    const float* __restrict__ Wf2, const float* __restrict__ Wq,
    const float* __restrict__ Wk, const float* __restrict__ Wv,
    __hip_bfloat16* __restrict__ Wo_t, __hip_bfloat16* __restrict__ Wf1_t,
    __hip_bfloat16* __restrict__ Wf2_t, __hip_bfloat16* __restrict__ Wn_t)
{
    int id = blockIdx.x*256 + threadIdx.x;   // < 786432
    int l = id / 196608;
    int r = id - l*196608;
    float v; __hip_bfloat16* dst;
    if (r < 16384) {
        int n = r >> 7, k = r & 127;
        v = Wo[l*16384 + k*128 + n];
        dst = Wo_t + l*16384 + r;
    } else if (r < 81920) {
        int rr = r - 16384;
        int n = rr >> 7, k = rr & 127;
        v = Wf1[l*65536 + k*512 + n];
        dst = Wf1_t + l*65536 + rr;
    } else if (r < 147456) {
        int rr = r - 81920;
        int n = rr >> 9, k = rr & 511;
        v = Wf2[l*65536 + k*128 + n];
        dst = Wf2_t + l*65536 + rr;
    } else {
        int rr = r - 147456;
        int n = rr >> 7, k = rr & 127;
        if (n < 128)      v = Wq[l*16384 + k*128 + n];
        else if (n < 256) v = Wk[l*32768 + (128+k)*128 + (n-128)];
        else              v = Wv[l*32768 + (128+k)*128 + (n-256)];
        dst = Wn_t + l*49152 + rr;
    }
    *dst = __float2bfloat16(v);
}

// ---------------------------------------------------------------- layer-0 node projections (fp32):
// P[row][0:128]=Q, [128:256]=Pk, [256:384]=Pv
__global__ __launch_bounds__(384) void node_proj_kernel(
    const float* __restrict__ hv, const float* __restrict__ Wq,
    const float* __restrict__ Wk, const float* __restrict__ Wv,
    float* __restrict__ P)
{
    int row0 = blockIdx.x * 8;
    int t = threadIdx.x;  // 0..383
    __shared__ float xs[8*H];
    for (int q = t; q < 8*H; q += 384) xs[q] = hv[row0*H + q];
    __syncthreads();
    const float* base;
    if (t < 128)      base = Wq + t;
    else if (t < 256) base = Wk + H*H + (t-128);
    else              base = Wv + H*H + (t-256);
    float acc[8];
#pragma unroll
    for (int r = 0; r < 8; r++) acc[r] = 0.f;
    for (int p = 0; p < H; p += 4) {
        float w0 = base[(p+0)*H];
        float w1 = base[(p+1)*H];
        float w2 = base[(p+2)*H];
        float w3 = base[(p+3)*H];
#pragma unroll
        for (int r = 0; r < 8; r++) {
            float4 x4 = *(const float4*)&xs[r*H+p];
            acc[r] += x4.x*w0 + x4.y*w1 + x4.z*w2 + x4.w*w3;
        }
    }
#pragma unroll
    for (int r = 0; r < 8; r++) P[(size_t)(row0+r)*384 + t] = acc[r];
}

// ---------------------------------------------------------------- attention: 2 nodes/block
// bias + node-term gather fused into MFMA epilogue (single bf16 rounding).
__global__ __launch_bounds__(256) void attn_kernel(
    const __hip_bfloat16* __restrict__ E_ln, const __hip_bfloat16* __restrict__ Wt,
    const float* __restrict__ bias_kv,
    float* __restrict__ P, const int* __restrict__ E_idx,
    const float* __restrict__ mask)
{
    int g0 = blockIdx.x * 2;
    int t = threadIdx.x;
    __shared__ __hip_bfloat16 Ae[64*136];     // A tile, pitch 136 bf16
    __shared__ __hip_bfloat16 KVs[60*264];    // K|V rows, pitch 264 bf16
    __shared__ float Qs[2*H];
    __shared__ float att_s[2*120];
    __shared__ float mv_s[60];
    __shared__ int   nbr[60];

    const __hip_bfloat16* hebase = E_ln + (size_t)g0*KNB*H;
    for (int q = t; q < 960; q += 256) {
        int r = q >> 4, c8 = (q & 15) * 8;
        *(s8v*)&Ae[r*136 + c8] = *(const s8v*)&hebase[r*H + c8];
    }
    if (t < 60) {
        int gn = g0 + t/30;
        int b = gn / NN;
        int idx = E_idx[gn*KNB + (t%30)];
        nbr[t]  = b*NN + idx;
        mv_s[t] = mask[gn] * mask[b*NN + idx];
    }
    {
        int node = t >> 7, c = t & 127;
        Qs[t] = P[(size_t)(g0+node)*384 + c];
    }
    __syncthreads();

    // MFMA: wave w handles n-tiles 4w..4w+3, all 4 m-tiles; epilogue fuses bias+gather
    {
        int wave = t >> 6, lane = t & 63;
        int lm = lane & 15, lq = lane >> 4;
        int cb = wave*64 + lm;
        const __hip_bfloat16* wb = Wt + (size_t)cb*H + lq*8;
        s8v bfr[4][4];
#pragma unroll
        for (int nt = 0; nt < 4; nt++)
#pragma unroll
            for (int ks = 0; ks < 4; ks++)
                bfr[nt][ks] = *(const s8v*)(wb + nt*16*H + ks*32);
        float bias0 = bias_kv[cb], bias1 = bias_kv[cb+16];
        float bias2 = bias_kv[cb+32], bias3 = bias_kv[cb+48];
#pragma unroll
        for (int mt = 0; mt < 4; mt++) {
            f4v a0 = {0.f,0.f,0.f,0.f}, a1 = a0, a2 = a0, a3 = a0;
#pragma unroll
            for (int ks = 0; ks < 4; ks++) {
                s8v af = *(const s8v*)&Ae[(mt*16+lm)*136 + ks*32 + lq*8];
                a0 = __builtin_amdgcn_mfma_f32_16x16x32_bf16(af, bfr[0][ks], a0, 0,0,0);
                a1 = __builtin_amdgcn_mfma_f32_16x16x32_bf16(af, bfr[1][ks], a1, 0,0,0);
                a2 = __builtin_amdgcn_mfma_f32_16x16x32_bf16(af, bfr[2][ks], a2, 0,0,0);
                a3 = __builtin_amdgcn_mfma_f32_16x16x32_bf16(af, bfr[3][ks], a3, 0,0,0);
            }
            int rbase = mt*16 + lq*4;
#pragma unroll
            for (int r = 0; r < 4; r++) {
                int row = rbase + r;
                if (row < 60) {
                    const float* pb = P + (size_t)nbr[row]*384 + 128 + cb;
                    KVs[row*264 + cb     ] = __float2bfloat16(a0[r] + bias0 + pb[0]);
                    KVs[row*264 + cb + 16] = __float2bfloat16(a1[r] + bias1 + pb[16]);
                    KVs[row*264 + cb + 32] = __float2bfloat16(a2[r] + bias2 + pb[32]);
                    KVs[row*264 + cb + 48] = __float2bfloat16(a3[r] + bias3 + pb[48]);
                }
            }
        }
    }
    __syncthreads();

    // logits (b128 LDS reads)
    if (t < 240) {
        int node = t / 120, tt = t % 120;
        int h = tt / 30, kk = tt % 30;
        int r = node*30 + kk;
        const uint4* kp = (const uint4*)&KVs[r*264 + h*32];
        const float* qp = &Qs[node*128 + h*32];
        float a = 0.f;
#pragma unroll
        for (int j = 0; j < 4; j++) {
            uint4 u = kp[j];
            const float* q8 = qp + j*8;
            a += q8[0]*bf_lo(u.x) + q8[1]*bf_hi(u.x)
               + q8[2]*bf_lo(u.y) + q8[3]*bf_hi(u.y)
               + q8[4]*bf_lo(u.z) + q8[5]*bf_hi(u.z)
               + q8[6]*bf_lo(u.w) + q8[7]*bf_hi(u.w);
        }
        att_s[node*120 + h*30 + kk] =
            (mv_s[r] > 0.f) ? a*0.17677669529663687f : -3.4028235e38f;
    }
    __syncthreads();
    if (t < 8) {
        int node = t >> 2, h = t & 3;
        float* ap = &att_s[node*120 + h*30];
        const float* mp = &mv_s[node*30];
        float mx = -3.4028235e38f;
        for (int kk = 0; kk < KNB; kk++) mx = fmaxf(mx, ap[kk]);
        float s = 0.f;
        for (int kk = 0; kk < KNB; kk++) s += __expf(ap[kk]-mx);
        float inv = 1.0f/s;
        for (int kk = 0; kk < KNB; kk++) ap[kk] = __expf(ap[kk]-mx)*inv*mp[kk];
    }
    __syncthreads();

    // upd = sum_k att * V; write into P Q-slots
    {
        int node = t >> 7, c = t & 127;
        const float* ap = &att_s[node*120 + (c>>5)*30];
        float u = 0.f;
        for (int kk = 0; kk < KNB; kk++)
            u += ap[kk] * __bfloat162float(KVs[(node*30+kk)*264 + 128 + c]);
        P[(size_t)(g0+node)*384 + c] = u;
    }
}

// ---------------------------------------------------------------- Wo + LN1 + FF + LN2 (+ next-layer node proj), MFMA
// hv updated IN-PLACE; if Wn_t != null, writes next layer's Q|Pk|Pv into P.
__global__ __launch_bounds__(256) void post_kernel(
    float* __restrict__ hv, float* __restrict__ P,
    const float* __restrict__ mask,
    const __hip_bfloat16* __restrict__ Wo_t,
    const float* __restrict__ ln1g, const float* __restrict__ ln1b,
    const float* __restrict__ ln2g, const float* __restrict__ ln2b,
    const __hip_bfloat16* __restrict__ Wf1_t, const float* __restrict__ bf1,
    const __hip_bfloat16* __restrict__ Wf2_t, const float* __restrict__ bf2,
    const __hip_bfloat16* __restrict__ Wn_t)
{
    int row0 = blockIdx.x * 16;
    int t = threadIdx.x;
    int wave = t >> 6, lane = t & 63, lm = lane & 15, lq = lane >> 4;

    __shared__ __hip_bfloat16 Aus[16*136];   // upd bf16
    __shared__ float xs[16*132];             // fp32 working rows
    __shared__ __hip_bfloat16 ys[16*136];    // LN1 out bf16
    __shared__ __hip_bfloat16 t1[16*520];    // relu(FF1) bf16
    __shared__ __hip_bfloat16 zs[16*136];    // hv_out bf16
    __shared__ float ps[256], pq[256];
    __shared__ float mu_s[16], rs_s[16];

    // 1. load upd (attn output, in P's Q slots)
    for (int q = t; q < 2048; q += 256) {
        int r = q >> 7, c = q & 127;
        Aus[r*136+c] = __float2bfloat16(P[(size_t)(row0+r)*384 + c]);
    }
    __syncthreads();

    // 2. x = hv + upd @ Wo
    for (int ntl = 0; ntl < 2; ntl++) {
        int nt = wave*2 + ntl;
        f4v acc = {0.f,0.f,0.f,0.f};
#pragma unroll
        for (int ks = 0; ks < 4; ks++) {
            s8v af = *(const s8v*)&Aus[lm*136 + ks*32 + lq*8];
            s8v bf = *(const s8v*)&Wo_t[(nt*16+lm)*128 + ks*32 + lq*8];
            acc = __builtin_amdgcn_mfma_f32_16x16x32_bf16(af, bf, acc, 0,0,0);
        }
        int cc = nt*16 + lm;
#pragma unroll
        for (int r = 0; r < 4; r++) {
            int rr = lq*4 + r;
            xs[rr*132+cc] = hv[(size_t)(row0+rr)*128 + cc] + acc[r];
        }
    }
    __syncthreads();

    // 3. LN1 -> xs (fp32) and ys (bf16)
    {
        int r = t >> 4, s = t & 15;
        float4 a = *(const float4*)&xs[r*132 + s*8];
        float4 b = *(const float4*)&xs[r*132 + s*8 + 4];
        ps[t] = a.x+a.y+a.z+a.w + b.x+b.y+b.z+b.w;
        pq[t] = a.x*a.x+a.y*a.y+a.z*a.z+a.w*a.w + b.x*b.x+b.y*b.y+b.z*b.z+b.w*b.w;
    }
    __syncthreads();
    if (t < 16) {
        float sm = 0.f, sq = 0.f;
        for (int s = 0; s < 16; s++) { sm += ps[t*16+s]; sq += pq[t*16+s]; }
        float mu = sm*(1.0f/H);
        mu_s[t] = mu;
        rs_s[t] = rsqrtf(sq*(1.0f/H) - mu*mu + LN_EPS);
    }
    __syncthreads();
    for (int q = t; q < 2048; q += 256) {
        int r = q >> 7, c = q & 127;
        float v = ln1g[c]*(xs[r*132+c]-mu_s[r])*rs_s[r] + ln1b[c];
        xs[r*132+c] = v;
        ys[r*136+c] = __float2bfloat16(v);
    }
    __syncthreads();

    // 4. FF1 + ReLU -> t1 (bf16)
    for (int ntl = 0; ntl < 8; ntl++) {
        int nt = wave*8 + ntl;
        f4v acc = {0.f,0.f,0.f,0.f};
#pragma unroll
        for (int ks = 0; ks < 4; ks++) {
            s8v af = *(const s8v*)&ys[lm*136 + ks*32 + lq*8];
            s8v bf = *(const s8v*)&Wf1_t[(size_t)(nt*16+lm)*128 + ks*32 + lq*8];
            acc = __builtin_amdgcn_mfma_f32_16x16x32_bf16(af, bf, acc, 0,0,0);
        }
        int cc = nt*16 + lm;
        float b = bf1[cc];
#pragma unroll
        for (int r = 0; r < 4; r++)
            t1[(lq*4+r)*520 + cc] = __float2bfloat16(fmaxf(acc[r]+b, 0.f));
    }
    __syncthreads();

    // 5. x2 = LN1out + FF2(t1) + b
    for (int ntl = 0; ntl < 2; ntl++) {
        int nt = wave*2 + ntl;
        f4v acc = {0.f,0.f,0.f,0.f};
#pragma unroll
        for (int ks = 0; ks < 16; ks++) {
            s8v af = *(const s8v*)&t1[lm*520 + ks*32 + lq*8];
            s8v bf = *(const s8v*)&Wf2_t[(size_t)(nt*16+lm)*512 + ks*32 + lq*8];
            acc = __builtin_amdgcn_mfma_f32_16x16x32_bf16(af, bf, acc, 0,0,0);
        }
        int cc = nt*16 + lm;
        float b = bf2[cc];
#pragma unroll
        for (int r = 0; r < 4; r++) {
            int rr = lq*4 + r;
            xs[rr*132+cc] = xs[rr*132+cc] + acc[r] + b;
        }
    }
    __syncthreads();

    // 6. LN2 + mask -> hv (global) and zs (bf16)
    {
        int r = t >> 4, s = t & 15;
        float4 a = *(const float4*)&xs[r*132 + s*8];
        float4 b = *(const float4*)&xs[r*132 + s*8 + 4];
        ps[t] = a.x+a.y+a.z+a.w + b.x+b.y+b.z+b.w;
        pq[t] = a.x*a.x+a.y*a.y+a.z*a.z+a.w*a.w + b.x*b.x+b.y*b.y+b.z*b.z+b.w*b.w;
    }
    __syncthreads();
    if (t < 16) {
        float sm = 0.f, sq = 0.f;
        for (int s = 0; s < 16; s++) { sm += ps[t*16+s]; sq += pq[t*16+s]; }
        float mu = sm*(1.0f/H);
        mu_s[t] = mu;
        rs_s[t] = rsqrtf(sq*(1.0f/H) - mu*mu + LN_EPS);
    }
    __syncthreads();
    for (int q = t; q < 2048; q += 256) {
        int r = q >> 7, c = q & 127;
        float v = mask[row0+r]*(ln2g[c]*(xs[r*132+c]-mu_s[r])*rs_s[r] + ln2b[c]);
        hv[(size_t)(row0+r)*128 + c] = v;
        zs[r*136+c] = __float2bfloat16(v);
    }
    __syncthreads();

    // 7. next-layer node projections: P = hv_out @ [Wq|Wk_bot|Wv_bot]
    if (Wn_t) {
        for (int ntl = 0; ntl < 6; ntl++) {
            int nt = wave*6 + ntl;
            f4v acc = {0.f,0.f,0.f,0.f};
#pragma unroll
            for (int ks = 0; ks < 4; ks++) {
                s8v af = *(const s8v*)&zs[lm*136 + ks*32 + lq*8];
                s8v bf = *(const s8v*)&Wn_t[(size_t)(nt*16+lm)*128 + ks*32 + lq*8];
                acc = __builtin_amdgcn_mfma_f32_16x16x32_bf16(af, bf, acc, 0,0,0);
            }
            int cc = nt*16 + lm;
#pragma unroll
            for (int r = 0; r < 4; r++)
                P[(size_t)(row0 + lq*4 + r)*384 + cc] = acc[r];
        }
    }
}

// ---------------------------------------------------------------- final projection
__global__ __launch_bounds__(64) void out_kernel(
    const float* __restrict__ hv, const float* __restrict__ W_out,
    const float* __restrict__ b_out, float* __restrict__ out)
{
    int row = blockIdx.x;
    int t = threadIdx.x;
    float a = hv[row*H+t]*W_out[t] + hv[row*H+t+64]*W_out[t+64];
#pragma unroll
    for (int s = 32; s > 0; s >>= 1) a += __shfl_down(a, s, 64);
    if (t == 0) out[row] = a + b_out[0];
}

// ---------------------------------------------------------------- launch
extern "C" void kernel_launch(void* const* d_in, const int* in_sizes, int n_in,
                              void* d_out, int out_size, void* d_ws, size_t ws_size,
                              hipStream_t stream)
{
    const float* X      = (const float*)d_in[0];
    const float* V      = (const float*)d_in[1];
    const float* mask   = (const float*)d_in[2];
    const float* W_v    = (const float*)d_in[3];
    const float* b_v    = (const float*)d_in[4];
    const float* W_e    = (const float*)d_in[5];
    const float* b_e    = (const float*)d_in[6];
    const float* W_edge = (const float*)d_in[7];
    const float* ln_e_g = (const float*)d_in[8];
    const float* ln_e_b = (const float*)d_in[9];
    const float* Wq     = (const float*)d_in[10];
    const float* Wk     = (const float*)d_in[11];
    const float* Wv_a   = (const float*)d_in[12];
    const float* Wo     = (const float*)d_in[13];
    const float* ln1g   = (const float*)d_in[14];
    const float* ln1b   = (const float*)d_in[15];
    const float* ln2g   = (const float*)d_in[16];
    const float* ln2b   = (const float*)d_in[17];
    const float* Wf1    = (const float*)d_in[18];
    const float* bf1    = (const float*)d_in[19];
    const float* Wf2    = (const float*)d_in[20];
    const float* bf2    = (const float*)d_in[21];
    const float* W_out  = (const float*)d_in[22];
    const float* b_out  = (const float*)d_in[23];
    float* out = (float*)d_out;

    // workspace layout (same as R3/R4)
    char* ws = (char*)d_ws;
    int*            E_idx   = (int*)ws;
    float*          D_nb    = (float*)(ws + 720000);
    __hip_bfloat16* E_ln    = (__hip_bfloat16*)(ws + 1440000);
    float*          hv      = (float*)(ws + 47520000);
    __hip_bfloat16* Wt_kv   = (__hip_bfloat16*)(ws + 50592000);
    float*          bias_kv = (float*)(ws + 50854144);
    __hip_bfloat16* Wn_t    = (__hip_bfloat16*)(ws + 50858240);
    __hip_bfloat16* Wo_t    = (__hip_bfloat16*)(ws + 51251456);
    __hip_bfloat16* Wf1_t   = (__hip_bfloat16*)(ws + 51382528);
    __hip_bfloat16* Wf2_t   = (__hip_bfloat16*)(ws + 51906816);
    float*          P       = (float*)(ws + 53664000);

    topk_kernel<<<NROWS, 256, 0, stream>>>(X, mask, E_idx, D_nb);
    edge_kernel<<<NROWS, 128, 0, stream>>>(E_idx, D_nb, W_edge, ln_e_g, ln_e_b, E_ln);
    wprep_kv_kernel<<<1024, 128, 0, stream>>>(W_e, b_e, Wk, Wv_a, Wt_kv, bias_kv);
    wprep_post_kernel<<<3072, 256, 0, stream>>>(Wo, Wf1, Wf2, Wq, Wk, Wv_a,
                                                Wo_t, Wf1_t, Wf2_t, Wn_t);
    hv_init_kernel<<<NROWS/8, 128, 0, stream>>>(V, W_v, b_v, hv);
    node_proj_kernel<<<NROWS/8, 384, 0, stream>>>(hv, Wq, Wk, Wv_a, P);

    for (int l = 0; l < 4; l++) {
        attn_kernel<<<NROWS/2, 256, 0, stream>>>(
            E_ln, Wt_kv + (size_t)l*256*H, bias_kv + l*256, P, E_idx, mask);
        post_kernel<<<NROWS/16, 256, 0, stream>>>(
            hv, P, mask, Wo_t + l*16384,
            ln1g + l*H, ln1b + l*H, ln2g + l*H, ln2b + l*H,
            Wf1_t + (size_t)l*65536, bf1 + l*FFH,
            Wf2_t + (size_t)l*65536, bf2 + l*H,
            (l < 3) ? (Wn_t + (size_t)(l+1)*49152) : (const __hip_bfloat16*)nullptr);
    }
    out_kernel<<<NROWS, 64, 0, stream>>>(hv, W_out, b_out, out);
}

// Round 6
// 586.071 us; speedup vs baseline: 5.9601x; 1.1104x over previous
//
#include <hip/hip_runtime.h>
#include <hip/hip_bf16.h>
#include <math.h>

#define NB 4
#define NN 1500
#define KNB 30
#define H 128
#define NHEADS 4
#define FFH 512
#define NODE_FEAT 1024
#define NROWS (NB*NN)
#define LN_EPS 1e-6f

typedef __attribute__((ext_vector_type(8))) short s8v;   // 8 bf16 = 4 VGPRs (MFMA A/B frag)
typedef __attribute__((ext_vector_type(4))) float f4v;   // MFMA C/D frag

__device__ __forceinline__ float bf_lo(unsigned u){ union{unsigned i; float f;} v; v.i = u<<16; return v.f; }
__device__ __forceinline__ float bf_hi(unsigned u){ union{unsigned i; float f;} v; v.i = u & 0xffff0000u; return v.f; }

// ---------------------------------------------------------------- topk (radix select)
__device__ __forceinline__ void find_bucket30(
    const int* hist, int base0, int t, int lane, int wave,
    int* wsum, int* res)
{
    int h[16], s = 0;
#pragma unroll
    for (int i = 0; i < 16; i++) { h[i] = hist[(i<<8)|t]; s += h[i]; }
    int inc = s;
#pragma unroll
    for (int off = 1; off < 64; off <<= 1) {
        int o = __shfl_up(inc, off, 64);
        if (lane >= off) inc += o;
    }
    if (lane == 63) wsum[wave] = inc;
    __syncthreads();
    int base = base0 + inc - s;
    for (int w = 0; w < wave; w++) base += wsum[w];
    if (base < KNB && base + s >= KNB) {
        int running = base;
#pragma unroll
        for (int i = 0; i < 16; i++) {
            if (running < KNB && running + h[i] >= KNB) { res[0] = (t<<4)|i; res[1] = running; break; }
            running += h[i];
        }
    }
    __syncthreads();
}

__global__ __launch_bounds__(256) void topk_kernel(
    const float* __restrict__ X, const float* __restrict__ mask,
    int* __restrict__ E_idx, float* __restrict__ D_nb)
{
    int row = blockIdx.x;            // b*NN + i
    int b = row / NN;
    int t = threadIdx.x;
    int wave = t >> 6, lane = t & 63;
    __shared__ float d_adj[NN];
    __shared__ int   hist[4096];
    __shared__ float redw[4];
    __shared__ int   wsum[4];
    __shared__ int   res[2];
    __shared__ int   cand[64];
    __shared__ int   ncand;

    float xi0 = X[row*3+0], xi1 = X[row*3+1], xi2 = X[row*3+2];
    float mi = mask[row];

    float dr[6], m2r[6];
    float lmax = -1e30f;
#pragma unroll
    for (int q = 0; q < 6; q++) {
        int j = t + q*256;
        float d = 0.f, m2 = 0.f;
        if (j < NN) {
            float dx = xi0 - X[(b*NN+j)*3+0];
            float dy = xi1 - X[(b*NN+j)*3+1];
            float dz = xi2 - X[(b*NN+j)*3+2];
            d  = sqrtf(dx*dx + dy*dy + dz*dz + 1e-6f);
            m2 = mi * mask[b*NN+j];
            lmax = fmaxf(lmax, m2*d);
        }
        dr[q] = d; m2r[q] = m2;
    }
    for (int q = t; q < 4096; q += 256) hist[q] = 0;
#pragma unroll
    for (int off = 32; off > 0; off >>= 1)
        lmax = fmaxf(lmax, __shfl_xor(lmax, off, 64));
    if (lane == 0) redw[wave] = lmax;
    if (t == 0) ncand = 0;
    __syncthreads();
    float rowmax = fmaxf(fmaxf(redw[0], redw[1]), fmaxf(redw[2], redw[3]));

    unsigned kreg[6];
#pragma unroll
    for (int q = 0; q < 6; q++) {
        int j = t + q*256;
        if (j < NN) {
            float dv = m2r[q]*dr[q] + (1.0f - m2r[q])*rowmax;   // >= 0
            d_adj[j] = dv;
            unsigned key = __float_as_uint(dv);
            kreg[q] = key;
            unsigned bkt = key >> 20;
            atomicAdd(&hist[((bkt & 15) << 8) | (bkt >> 4)], 1);
        } else kreg[q] = 0xFFFFFFFFu;
    }
    __syncthreads();

    find_bucket30(hist, 0, t, lane, wave, wsum, res);
    int B1 = res[0], nb1 = res[1];

    for (int q = t; q < 4096; q += 256) hist[q] = 0;
    __syncthreads();
#pragma unroll
    for (int q = 0; q < 6; q++) {
        if ((kreg[q] >> 20) == (unsigned)B1) {
            unsigned bkt = (kreg[q] >> 8) & 0xFFF;
            atomicAdd(&hist[((bkt & 15) << 8) | (bkt >> 4)], 1);
        }
    }
    __syncthreads();

    find_bucket30(hist, nb1, t, lane, wave, wsum, res);
    unsigned Bfull = ((unsigned)B1 << 12) | (unsigned)res[0];

#pragma unroll
    for (int q = 0; q < 6; q++) {
        if ((kreg[q] >> 8) <= Bfull) {
            int slot = atomicAdd(&ncand, 1);
            if (slot < 64) cand[slot] = t + q*256;
        }
    }
    __syncthreads();

    if (wave == 0) {
        int nc = min(ncand, 64);
        if (lane < nc) {
            int j = cand[lane];
            float v = d_adj[j];
            int rank = 0;
            for (int m = 0; m < nc; m++) {
                int jm = cand[m];
                float vm = d_adj[jm];
                rank += (vm < v || (vm == v && jm < j)) ? 1 : 0;
            }
            if (rank < KNB) {
                E_idx[row*KNB + rank] = j;
                D_nb[row*KNB + rank]  = v;
            }
        }
    }
}

// ---------------------------------------------------------------- edge features -> E_ln (bf16)
__global__ __launch_bounds__(128) void edge_kernel(
    const int* __restrict__ E_idx, const float* __restrict__ D_nb,
    const float* __restrict__ W_edge, const float* __restrict__ ln_g,
    const float* __restrict__ ln_b, __hip_bfloat16* __restrict__ E_ln)
{
    int node = blockIdx.x;
    int i = node % NN;
    int t = threadIdx.x;             // 128 threads, t = output channel
    __shared__ float feat[KNB*32];
    __shared__ float eall[KNB*132];
    __shared__ float mu_s[KNB], rs_s[KNB];

    for (int q = t; q < KNB*32; q += 128) {
        int k = q >> 5, f = q & 31;
        int e = node*KNB + k;
        float val;
        if (f < 16) {
            int ff = f & 7;
            float drel = (float)E_idx[e] - (float)i;
            float fr = expf(-(float)ff * 1.15129254649702284f);
            float ang = drel * fr;
            val = (f < 8) ? cosf(ang) : sinf(ang);
        } else {
            float mu = (20.0f/15.0f) * (float)(f-16);
            float z = (D_nb[e] - mu) * 0.8f;
            val = expf(-z*z);
        }
        feat[q] = val;
    }
    __syncthreads();

    float acc[KNB];
#pragma unroll
    for (int k = 0; k < KNB; k++) acc[k] = 0.f;
    for (int p = 0; p < 32; p += 4) {
        float w0 = W_edge[(p+0)*H+t];
        float w1 = W_edge[(p+1)*H+t];
        float w2 = W_edge[(p+2)*H+t];
        float w3 = W_edge[(p+3)*H+t];
#pragma unroll
        for (int k = 0; k < KNB; k++) {
            float4 f4 = *(const float4*)&feat[k*32+p];
            acc[k] += f4.x*w0 + f4.y*w1 + f4.z*w2 + f4.w*w3;
        }
    }
#pragma unroll
    for (int k = 0; k < KNB; k++) eall[k*132+t] = acc[k];
    __syncthreads();

    if (t < KNB) {
        float s = 0.f;
        for (int c = 0; c < H; c++) s += eall[t*132+c];
        float mu = s * (1.0f/H);
        float v = 0.f;
        for (int c = 0; c < H; c++) { float d = eall[t*132+c] - mu; v += d*d; }
        mu_s[t] = mu;
        rs_s[t] = rsqrtf(v*(1.0f/H) + LN_EPS);
    }
    __syncthreads();
    float g = ln_g[t], bb = ln_b[t];
#pragma unroll
    for (int k = 0; k < KNB; k++)
        E_ln[(node*KNB+k)*H+t] =
            __float2bfloat16(g*(eall[k*132+t]-mu_s[k])*rs_s[k] + bb);
}

// ---------------------------------------------------------------- W_v transpose+cast: Wv_t[n][k] bf16
__global__ __launch_bounds__(256) void wprep_v_kernel(
    const float* __restrict__ W_v, __hip_bfloat16* __restrict__ Wv_t)
{
    int tid = blockIdx.x*256 + threadIdx.x;  // 131072
    int n = tid & 127, k = tid >> 7;
    Wv_t[(size_t)n*NODE_FEAT + k] = __float2bfloat16(W_v[k*H + n]);
}

// ---------------------------------------------------------------- h_V = V @ W_v + b_v  (MFMA)
// + fused layer-0 node projections P = hv @ [Wq|Wk_bot|Wv_bot]
__global__ __launch_bounds__(256) void hv_init_kernel(
    const float* __restrict__ V, const __hip_bfloat16* __restrict__ Wv_t,
    const float* __restrict__ b_v, float* __restrict__ hv,
    const __hip_bfloat16* __restrict__ Wn_t, float* __restrict__ P)
{
    int row0 = blockIdx.x * 16;
    int t = threadIdx.x;
    int wave = t >> 6, lane = t & 63, lm = lane & 15, lq = lane >> 4;
    __shared__ __hip_bfloat16 Vs[16*1032];   // pitch 1032 (2-way bank alias only)
    __shared__ __hip_bfloat16 zs[16*136];

    // stage V rows -> bf16 LDS (coalesced float4 reads)
    for (int q = t; q < 4096; q += 256) {
        int r = q >> 8, c4 = (q & 255) * 4;
        float4 v4 = *(const float4*)&V[(size_t)(row0+r)*NODE_FEAT + c4];
        __hip_bfloat16* d = &Vs[r*1032 + c4];
        d[0] = __float2bfloat16(v4.x);
        d[1] = __float2bfloat16(v4.y);
        d[2] = __float2bfloat16(v4.z);
        d[3] = __float2bfloat16(v4.w);
    }
    __syncthreads();

    // hv = V @ W_v + b_v : 8 n-tiles, 2 per wave, K=1024
#pragma unroll
    for (int ntl = 0; ntl < 2; ntl++) {
        int nt = wave*2 + ntl;
        f4v acc = {0.f,0.f,0.f,0.f};
        for (int ks = 0; ks < 32; ks++) {
            s8v af = *(const s8v*)&Vs[lm*1032 + ks*32 + lq*8];
            s8v bf = *(const s8v*)&Wv_t[(size_t)(nt*16+lm)*NODE_FEAT + ks*32 + lq*8];
            acc = __builtin_amdgcn_mfma_f32_16x16x32_bf16(af, bf, acc, 0,0,0);
        }
        int cc = nt*16 + lm;
        float b = b_v[cc];
#pragma unroll
        for (int r = 0; r < 4; r++) {
            int rr = lq*4 + r;
            float v = acc[r] + b;
            hv[(size_t)(row0+rr)*H + cc] = v;
            zs[rr*136+cc] = __float2bfloat16(v);
        }
    }
    __syncthreads();

    // P = hv @ [Wq|Wk_bot|Wv_bot] : 24 n-tiles, 6 per wave
    for (int ntl = 0; ntl < 6; ntl++) {
        int nt = wave*6 + ntl;
        f4v acc = {0.f,0.f,0.f,0.f};
#pragma unroll
        for (int ks = 0; ks < 4; ks++) {
            s8v af = *(const s8v*)&zs[lm*136 + ks*32 + lq*8];
            s8v bf = *(const s8v*)&Wn_t[(size_t)(nt*16+lm)*H + ks*32 + lq*8];
            acc = __builtin_amdgcn_mfma_f32_16x16x32_bf16(af, bf, acc, 0,0,0);
        }
        int cc = nt*16 + lm;
#pragma unroll
        for (int r = 0; r < 4; r++)
            P[(size_t)(row0 + lq*4 + r)*384 + cc] = acc[r];
    }
}

// ---------------------------------------------------------------- fold W_e into per-layer edge K/V
__global__ __launch_bounds__(128) void wprep_kv_kernel(
    const float* __restrict__ W_e, const float* __restrict__ b_e,
    const float* __restrict__ Wk, const float* __restrict__ Wv,
    __hip_bfloat16* __restrict__ Wt_kv, float* __restrict__ bias_kv)
{
    int l = blockIdx.x >> 8;
    int n = blockIdx.x & 255;
    int t = threadIdx.x;             // t = k (0..127)
    int col = n & 127;
    const float* W = (n < 128) ? (Wk + l*2*H*H) : (Wv + l*2*H*H);
    __shared__ float wcol[128];
    wcol[t] = W[t*H + col];          // rows 0..127 = h_E block
    __syncthreads();
    float a = 0.f;
    for (int c = 0; c < H; c += 4) {
        float4 we = *(const float4*)&W_e[t*H + c];
        a += we.x*wcol[c] + we.y*wcol[c+1] + we.z*wcol[c+2] + we.w*wcol[c+3];
    }
    Wt_kv[(size_t)(l*256 + n)*H + t] = __float2bfloat16(a);
    if (t == 0) {
        float bsum = 0.f;
        for (int c = 0; c < H; c++) bsum += b_e[c]*wcol[c];
        bias_kv[l*256 + n] = bsum;
    }
}

// ---------------------------------------------------------------- transpose+cast weights to bf16 [n][k]
__global__ __launch_bounds__(256) void wprep_post_kernel(
    const float* __restrict__ Wo, const float* __restrict__ Wf1,
    const float* __restrict__ Wf2, const float* __restrict__ Wq,
    const float* __restrict__ Wk, const float* __restrict__ Wv,
    __hip_bfloat16* __restrict__ Wo_t, __hip_bfloat16* __restrict__ Wf1_t,
    __hip_bfloat16* __restrict__ Wf2_t, __hip_bfloat16* __restrict__ Wn_t)
{
    int id = blockIdx.x*256 + threadIdx.x;   // < 786432
    int l = id / 196608;
    int r = id - l*196608;
    float v; __hip_bfloat16* dst;
    if (r < 16384) {
        int n = r >> 7, k = r & 127;
        v = Wo[l*16384 + k*128 + n];
        dst = Wo_t + l*16384 + r;
    } else if (r < 81920) {
        int rr = r - 16384;
        int n = rr >> 7, k = rr & 127;
        v = Wf1[l*65536 + k*512 + n];
        dst = Wf1_t + l*65536 + rr;
    } else if (r < 147456) {
        int rr = r - 81920;
        int n = rr >> 9, k = rr & 511;
        v = Wf2[l*65536 + k*128 + n];
        dst = Wf2_t + l*65536 + rr;
    } else {
        int rr = r - 147456;
        int n = rr >> 7, k = rr & 127;
        if (n < 128)      v = Wq[l*16384 + k*128 + n];
        else if (n < 256) v = Wk[l*32768 + (128+k)*128 + (n-128)];
        else              v = Wv[l*32768 + (128+k)*128 + (n-256)];
        dst = Wn_t + l*49152 + rr;
    }
    *dst = __float2bfloat16(v);
}

// ---------------------------------------------------------------- attention: 2 nodes/block
__global__ __launch_bounds__(256) void attn_kernel(
    const __hip_bfloat16* __restrict__ E_ln, const __hip_bfloat16* __restrict__ Wt,
    const float* __restrict__ bias_kv,
    float* __restrict__ P, const int* __restrict__ E_idx,
    const float* __restrict__ mask)
{
    int g0 = blockIdx.x * 2;
    int t = threadIdx.x;
    __shared__ __hip_bfloat16 Ae[64*136];     // A tile, pitch 136 bf16
    __shared__ __hip_bfloat16 KVs[60*264];    // K|V rows, pitch 264 bf16
    __shared__ float Qs[2*H];
    __shared__ float att_s[2*120];
    __shared__ float mv_s[60];
    __shared__ int   nbr[60];

    const __hip_bfloat16* hebase = E_ln + (size_t)g0*KNB*H;
    for (int q = t; q < 960; q += 256) {
        int r = q >> 4, c8 = (q & 15) * 8;
        *(s8v*)&Ae[r*136 + c8] = *(const s8v*)&hebase[r*H + c8];
    }
    if (t < 60) {
        int gn = g0 + t/30;
        int b = gn / NN;
        int idx = E_idx[gn*KNB + (t%30)];
        nbr[t]  = b*NN + idx;
        mv_s[t] = mask[gn] * mask[b*NN + idx];
    }
    {
        int node = t >> 7, c = t & 127;
        Qs[t] = P[(size_t)(g0+node)*384 + c];
    }
    __syncthreads();

    {
        int wave = t >> 6, lane = t & 63;
        int lm = lane & 15, lq = lane >> 4;
        int cb = wave*64 + lm;
        const __hip_bfloat16* wb = Wt + (size_t)cb*H + lq*8;
        s8v bfr[4][4];
#pragma unroll
        for (int nt = 0; nt < 4; nt++)
#pragma unroll
            for (int ks = 0; ks < 4; ks++)
                bfr[nt][ks] = *(const s8v*)(wb + nt*16*H + ks*32);
        float bias0 = bias_kv[cb], bias1 = bias_kv[cb+16];
        float bias2 = bias_kv[cb+32], bias3 = bias_kv[cb+48];
#pragma unroll
        for (int mt = 0; mt < 4; mt++) {
            f4v a0 = {0.f,0.f,0.f,0.f}, a1 = a0, a2 = a0, a3 = a0;
#pragma unroll
            for (int ks = 0; ks < 4; ks++) {
                s8v af = *(const s8v*)&Ae[(mt*16+lm)*136 + ks*32 + lq*8];
                a0 = __builtin_amdgcn_mfma_f32_16x16x32_bf16(af, bfr[0][ks], a0, 0,0,0);
                a1 = __builtin_amdgcn_mfma_f32_16x16x32_bf16(af, bfr[1][ks], a1, 0,0,0);
                a2 = __builtin_amdgcn_mfma_f32_16x16x32_bf16(af, bfr[2][ks], a2, 0,0,0);
                a3 = __builtin_amdgcn_mfma_f32_16x16x32_bf16(af, bfr[3][ks], a3, 0,0,0);
            }
            int rbase = mt*16 + lq*4;
#pragma unroll
            for (int r = 0; r < 4; r++) {
                int row = rbase + r;
                if (row < 60) {
                    const float* pb = P + (size_t)nbr[row]*384 + 128 + cb;
                    KVs[row*264 + cb     ] = __float2bfloat16(a0[r] + bias0 + pb[0]);
                    KVs[row*264 + cb + 16] = __float2bfloat16(a1[r] + bias1 + pb[16]);
                    KVs[row*264 + cb + 32] = __float2bfloat16(a2[r] + bias2 + pb[32]);
                    KVs[row*264 + cb + 48] = __float2bfloat16(a3[r] + bias3 + pb[48]);
                }
            }
        }
    }
    __syncthreads();

    if (t < 240) {
        int node = t / 120, tt = t % 120;
        int h = tt / 30, kk = tt % 30;
        int r = node*30 + kk;
        const uint4* kp = (const uint4*)&KVs[r*264 + h*32];
        const float* qp = &Qs[node*128 + h*32];
        float a = 0.f;
#pragma unroll
        for (int j = 0; j < 4; j++) {
            uint4 u = kp[j];
            const float* q8 = qp + j*8;
            a += q8[0]*bf_lo(u.x) + q8[1]*bf_hi(u.x)
               + q8[2]*bf_lo(u.y) + q8[3]*bf_hi(u.y)
               + q8[4]*bf_lo(u.z) + q8[5]*bf_hi(u.z)
               + q8[6]*bf_lo(u.w) + q8[7]*bf_hi(u.w);
        }
        att_s[node*120 + h*30 + kk] =
            (mv_s[r] > 0.f) ? a*0.17677669529663687f : -3.4028235e38f;
    }
    __syncthreads();
    if (t < 8) {
        int node = t >> 2, h = t & 3;
        float* ap = &att_s[node*120 + h*30];
        const float* mp = &mv_s[node*30];
        float mx = -3.4028235e38f;
        for (int kk = 0; kk < KNB; kk++) mx = fmaxf(mx, ap[kk]);
        float s = 0.f;
        for (int kk = 0; kk < KNB; kk++) s += __expf(ap[kk]-mx);
        float inv = 1.0f/s;
        for (int kk = 0; kk < KNB; kk++) ap[kk] = __expf(ap[kk]-mx)*inv*mp[kk];
    }
    __syncthreads();

    {
        int node = t >> 7, c = t & 127;
        const float* ap = &att_s[node*120 + (c>>5)*30];
        float u = 0.f;
        for (int kk = 0; kk < KNB; kk++)
            u += ap[kk] * __bfloat162float(KVs[(node*30+kk)*264 + 128 + c]);
        P[(size_t)(g0+node)*384 + c] = u;
    }
}

// ---------------------------------------------------------------- Wo + LN1 + FF + LN2 (+ next-layer node proj), MFMA
__global__ __launch_bounds__(256) void post_kernel(
    float* __restrict__ hv, float* __restrict__ P,
    const float* __restrict__ mask,
    const __hip_bfloat16* __restrict__ Wo_t,
    const float* __restrict__ ln1g, const float* __restrict__ ln1b,
    const float* __restrict__ ln2g, const float* __restrict__ ln2b,
    const __hip_bfloat16* __restrict__ Wf1_t, const float* __restrict__ bf1,
    const __hip_bfloat16* __restrict__ Wf2_t, const float* __restrict__ bf2,
    const __hip_bfloat16* __restrict__ Wn_t)
{
    int row0 = blockIdx.x * 16;
    int t = threadIdx.x;
    int wave = t >> 6, lane = t & 63, lm = lane & 15, lq = lane >> 4;

    __shared__ __hip_bfloat16 Aus[16*136];   // upd bf16
    __shared__ float xs[16*132];             // fp32 working rows
    __shared__ __hip_bfloat16 ys[16*136];    // LN1 out bf16
    __shared__ __hip_bfloat16 t1[16*520];    // relu(FF1) bf16
    __shared__ __hip_bfloat16 zs[16*136];    // hv_out bf16
    __shared__ float ps[256], pq[256];
    __shared__ float mu_s[16], rs_s[16];

    for (int q = t; q < 2048; q += 256) {
        int r = q >> 7, c = q & 127;
        Aus[r*136+c] = __float2bfloat16(P[(size_t)(row0+r)*384 + c]);
    }
    __syncthreads();

    for (int ntl = 0; ntl < 2; ntl++) {
        int nt = wave*2 + ntl;
        f4v acc = {0.f,0.f,0.f,0.f};
#pragma unroll
        for (int ks = 0; ks < 4; ks++) {
            s8v af = *(const s8v*)&Aus[lm*136 + ks*32 + lq*8];
            s8v bf = *(const s8v*)&Wo_t[(nt*16+lm)*128 + ks*32 + lq*8];
            acc = __builtin_amdgcn_mfma_f32_16x16x32_bf16(af, bf, acc, 0,0,0);
        }
        int cc = nt*16 + lm;
#pragma unroll
        for (int r = 0; r < 4; r++) {
            int rr = lq*4 + r;
            xs[rr*132+cc] = hv[(size_t)(row0+rr)*128 + cc] + acc[r];
        }
    }
    __syncthreads();

    {
        int r = t >> 4, s = t & 15;
        float4 a = *(const float4*)&xs[r*132 + s*8];
        float4 b = *(const float4*)&xs[r*132 + s*8 + 4];
        ps[t] = a.x+a.y+a.z+a.w + b.x+b.y+b.z+b.w;
        pq[t] = a.x*a.x+a.y*a.y+a.z*a.z+a.w*a.w + b.x*b.x+b.y*b.y+b.z*b.z+b.w*b.w;
    }
    __syncthreads();
    if (t < 16) {
        float sm = 0.f, sq = 0.f;
        for (int s = 0; s < 16; s++) { sm += ps[t*16+s]; sq += pq[t*16+s]; }
        float mu = sm*(1.0f/H);
        mu_s[t] = mu;
        rs_s[t] = rsqrtf(sq*(1.0f/H) - mu*mu + LN_EPS);
    }
    __syncthreads();
    for (int q = t; q < 2048; q += 256) {
        int r = q >> 7, c = q & 127;
        float v = ln1g[c]*(xs[r*132+c]-mu_s[r])*rs_s[r] + ln1b[c];
        xs[r*132+c] = v;
        ys[r*136+c] = __float2bfloat16(v);
    }
    __syncthreads();

    for (int ntl = 0; ntl < 8; ntl++) {
        int nt = wave*8 + ntl;
        f4v acc = {0.f,0.f,0.f,0.f};
#pragma unroll
        for (int ks = 0; ks < 4; ks++) {
            s8v af = *(const s8v*)&ys[lm*136 + ks*32 + lq*8];
            s8v bf = *(const s8v*)&Wf1_t[(size_t)(nt*16+lm)*128 + ks*32 + lq*8];
            acc = __builtin_amdgcn_mfma_f32_16x16x32_bf16(af, bf, acc, 0,0,0);
        }
        int cc = nt*16 + lm;
        float b = bf1[cc];
#pragma unroll
        for (int r = 0; r < 4; r++)
            t1[(lq*4+r)*520 + cc] = __float2bfloat16(fmaxf(acc[r]+b, 0.f));
    }
    __syncthreads();

    for (int ntl = 0; ntl < 2; ntl++) {
        int nt = wave*2 + ntl;
        f4v acc = {0.f,0.f,0.f,0.f};
#pragma unroll
        for (int ks = 0; ks < 16; ks++) {
            s8v af = *(const s8v*)&t1[lm*520 + ks*32 + lq*8];
            s8v bf = *(const s8v*)&Wf2_t[(size_t)(nt*16+lm)*512 + ks*32 + lq*8];
            acc = __builtin_amdgcn_mfma_f32_16x16x32_bf16(af, bf, acc, 0,0,0);
        }
        int cc = nt*16 + lm;
        float b = bf2[cc];
#pragma unroll
        for (int r = 0; r < 4; r++) {
            int rr = lq*4 + r;
            xs[rr*132+cc] = xs[rr*132+cc] + acc[r] + b;
        }
    }
    __syncthreads();

    {
        int r = t >> 4, s = t & 15;
        float4 a = *(const float4*)&xs[r*132 + s*8];
        float4 b = *(const float4*)&xs[r*132 + s*8 + 4];
        ps[t] = a.x+a.y+a.z+a.w + b.x+b.y+b.z+b.w;
        pq[t] = a.x*a.x+a.y*a.y+a.z*a.z+a.w*a.w + b.x*b.x+b.y*b.y+b.z*b.z+b.w*b.w;
    }
    __syncthreads();
    if (t < 16) {
        float sm = 0.f, sq = 0.f;
        for (int s = 0; s < 16; s++) { sm += ps[t*16+s]; sq += pq[t*16+s]; }
        float mu = sm*(1.0f/H);
        mu_s[t] = mu;
        rs_s[t] = rsqrtf(sq*(1.0f/H) - mu*mu + LN_EPS);
    }
    __syncthreads();
    for (int q = t; q < 2048; q += 256) {
        int r = q >> 7, c = q & 127;
        float v = mask[row0+r]*(ln2g[c]*(xs[r*132+c]-mu_s[r])*rs_s[r] + ln2b[c]);
        hv[(size_t)(row0+r)*128 + c] = v;
        zs[r*136+c] = __float2bfloat16(v);
    }
    __syncthreads();

    if (Wn_t) {
        for (int ntl = 0; ntl < 6; ntl++) {
            int nt = wave*6 + ntl;
            f4v acc = {0.f,0.f,0.f,0.f};
#pragma unroll
            for (int ks = 0; ks < 4; ks++) {
                s8v af = *(const s8v*)&zs[lm*136 + ks*32 + lq*8];
                s8v bf = *(const s8v*)&Wn_t[(size_t)(nt*16+lm)*128 + ks*32 + lq*8];
                acc = __builtin_amdgcn_mfma_f32_16x16x32_bf16(af, bf, acc, 0,0,0);
            }
            int cc = nt*16 + lm;
#pragma unroll
            for (int r = 0; r < 4; r++)
                P[(size_t)(row0 + lq*4 + r)*384 + cc] = acc[r];
        }
    }
}

// ---------------------------------------------------------------- final projection
__global__ __launch_bounds__(64) void out_kernel(
    const float* __restrict__ hv, const float* __restrict__ W_out,
    const float* __restrict__ b_out, float* __restrict__ out)
{
    int row = blockIdx.x;
    int t = threadIdx.x;
    float a = hv[row*H+t]*W_out[t] + hv[row*H+t+64]*W_out[t+64];
#pragma unroll
    for (int s = 32; s > 0; s >>= 1) a += __shfl_down(a, s, 64);
    if (t == 0) out[row] = a + b_out[0];
}

// ---------------------------------------------------------------- launch
extern "C" void kernel_launch(void* const* d_in, const int* in_sizes, int n_in,
                              void* d_out, int out_size, void* d_ws, size_t ws_size,
                              hipStream_t stream)
{
    const float* X      = (const float*)d_in[0];
    const float* V      = (const float*)d_in[1];
    const float* mask   = (const float*)d_in[2];
    const float* W_v    = (const float*)d_in[3];
    const float* b_v    = (const float*)d_in[4];
    const float* W_e    = (const float*)d_in[5];
    const float* b_e    = (const float*)d_in[6];
    const float* W_edge = (const float*)d_in[7];
    const float* ln_e_g = (const float*)d_in[8];
    const float* ln_e_b = (const float*)d_in[9];
    const float* Wq     = (const float*)d_in[10];
    const float* Wk     = (const float*)d_in[11];
    const float* Wv_a   = (const float*)d_in[12];
    const float* Wo     = (const float*)d_in[13];
    const float* ln1g   = (const float*)d_in[14];
    const float* ln1b   = (const float*)d_in[15];
    const float* ln2g   = (const float*)d_in[16];
    const float* ln2b   = (const float*)d_in[17];
    const float* Wf1    = (const float*)d_in[18];
    const float* bf1    = (const float*)d_in[19];
    const float* Wf2    = (const float*)d_in[20];
    const float* bf2    = (const float*)d_in[21];
    const float* W_out  = (const float*)d_in[22];
    const float* b_out  = (const float*)d_in[23];
    float* out = (float*)d_out;

    // workspace layout:
    //   E_idx   :        0 ..   720,000   (int 180000)
    //   D_nb    :  720,000 .. 1,440,000   (f32 180000)
    //   E_ln    : 1,440,000 .. 47,520,000 (bf16 180000*128)
    //   hv      : 47,520,000 .. 50,592,000 (f32 6000*128, in-place across layers)
    //   Wt_kv   : 50,592,000 .. 50,854,144 (bf16 4*256*128)
    //   bias_kv : 50,854,144 .. 50,858,240 (f32 4*256)
    //   Wn_t    : 50,858,240 .. 51,251,456 (bf16 4*384*128)
    //   Wo_t    : 51,251,456 .. 51,382,528 (bf16 4*128*128)
    //   Wf1_t   : 51,382,528 .. 51,906,816 (bf16 4*512*128)
    //   Wf2_t   : 51,906,816 .. 52,431,104 (bf16 4*128*512)
    //   Wv_t    : 52,431,104 .. 52,693,248 (bf16 128*1024)
    //   P       : 53,664,000 .. 62,880,000 (f32 6000*384: Q|Pk|Pv)
    char* ws = (char*)d_ws;
    int*            E_idx   = (int*)ws;
    float*          D_nb    = (float*)(ws + 720000);
    __hip_bfloat16* E_ln    = (__hip_bfloat16*)(ws + 1440000);
    float*          hv      = (float*)(ws + 47520000);
    __hip_bfloat16* Wt_kv   = (__hip_bfloat16*)(ws + 50592000);
    float*          bias_kv = (float*)(ws + 50854144);
    __hip_bfloat16* Wn_t    = (__hip_bfloat16*)(ws + 50858240);
    __hip_bfloat16* Wo_t    = (__hip_bfloat16*)(ws + 51251456);
    __hip_bfloat16* Wf1_t   = (__hip_bfloat16*)(ws + 51382528);
    __hip_bfloat16* Wf2_t   = (__hip_bfloat16*)(ws + 51906816);
    __hip_bfloat16* Wv_t    = (__hip_bfloat16*)(ws + 52431104);
    float*          P       = (float*)(ws + 53664000);

    topk_kernel<<<NROWS, 256, 0, stream>>>(X, mask, E_idx, D_nb);
    edge_kernel<<<NROWS, 128, 0, stream>>>(E_idx, D_nb, W_edge, ln_e_g, ln_e_b, E_ln);
    wprep_kv_kernel<<<1024, 128, 0, stream>>>(W_e, b_e, Wk, Wv_a, Wt_kv, bias_kv);
    wprep_post_kernel<<<3072, 256, 0, stream>>>(Wo, Wf1, Wf2, Wq, Wk, Wv_a,
                                                Wo_t, Wf1_t, Wf2_t, Wn_t);
    wprep_v_kernel<<<512, 256, 0, stream>>>(W_v, Wv_t);
    hv_init_kernel<<<NROWS/16, 256, 0, stream>>>(V, Wv_t, b_v, hv, Wn_t, P);

    for (int l = 0; l < 4; l++) {
        attn_kernel<<<NROWS/2, 256, 0, stream>>>(
            E_ln, Wt_kv + (size_t)l*256*H, bias_kv + l*256, P, E_idx, mask);
        post_kernel<<<NROWS/16, 256, 0, stream>>>(
            hv, P, mask, Wo_t + l*16384,
            ln1g + l*H, ln1b + l*H, ln2g + l*H, ln2b + l*H,
            Wf1_t + (size_t)l*65536, bf1 + l*FFH,
            Wf2_t + (size_t)l*65536, bf2 + l*H,
            (l < 3) ? (Wn_t + (size_t)(l+1)*49152) : (const __hip_bfloat16*)nullptr);
    }
    out_kernel<<<NROWS, 64, 0, stream>>>(hv, W_out, b_out, out);
}

// Round 7
// 545.218 us; speedup vs baseline: 6.4067x; 1.0749x over previous
//
#include <hip/hip_runtime.h>
#include <hip/hip_bf16.h>
#include <math.h>

#define NB 4
#define NN 1500
#define KNB 30
#define H 128
#define NHEADS 4
#define FFH 512
#define NODE_FEAT 1024
#define NROWS (NB*NN)
#define LN_EPS 1e-6f

typedef __attribute__((ext_vector_type(8))) short s8v;   // 8 bf16 = 4 VGPRs (MFMA A/B frag)
typedef __attribute__((ext_vector_type(4))) float f4v;   // MFMA C/D frag

__device__ __forceinline__ float bf_lo(unsigned u){ union{unsigned i; float f;} v; v.i = u<<16; return v.f; }
__device__ __forceinline__ float bf_hi(unsigned u){ union{unsigned i; float f;} v; v.i = u & 0xffff0000u; return v.f; }

// ---------------------------------------------------------------- topk (radix select)
__device__ __forceinline__ void find_bucket30(
    const int* hist, int base0, int t, int lane, int wave,
    int* wsum, int* res)
{
    int h[16], s = 0;
#pragma unroll
    for (int i = 0; i < 16; i++) { h[i] = hist[(i<<8)|t]; s += h[i]; }
    int inc = s;
#pragma unroll
    for (int off = 1; off < 64; off <<= 1) {
        int o = __shfl_up(inc, off, 64);
        if (lane >= off) inc += o;
    }
    if (lane == 63) wsum[wave] = inc;
    __syncthreads();
    int base = base0 + inc - s;
    for (int w = 0; w < wave; w++) base += wsum[w];
    if (base < KNB && base + s >= KNB) {
        int running = base;
#pragma unroll
        for (int i = 0; i < 16; i++) {
            if (running < KNB && running + h[i] >= KNB) { res[0] = (t<<4)|i; res[1] = running; break; }
            running += h[i];
        }
    }
    __syncthreads();
}

__global__ __launch_bounds__(256) void topk_kernel(
    const float* __restrict__ X, const float* __restrict__ mask,
    int* __restrict__ E_idx, float* __restrict__ D_nb)
{
    int row = blockIdx.x;            // b*NN + i
    int b = row / NN;
    int t = threadIdx.x;
    int wave = t >> 6, lane = t & 63;
    __shared__ float d_adj[NN];
    __shared__ int   hist[4096];
    __shared__ float redw[4];
    __shared__ int   wsum[4];
    __shared__ int   res[2];
    __shared__ int   cand[64];
    __shared__ int   ncand;

    float xi0 = X[row*3+0], xi1 = X[row*3+1], xi2 = X[row*3+2];
    float mi = mask[row];

    float dr[6], m2r[6];
    float lmax = -1e30f;
#pragma unroll
    for (int q = 0; q < 6; q++) {
        int j = t + q*256;
        float d = 0.f, m2 = 0.f;
        if (j < NN) {
            float dx = xi0 - X[(b*NN+j)*3+0];
            float dy = xi1 - X[(b*NN+j)*3+1];
            float dz = xi2 - X[(b*NN+j)*3+2];
            d  = sqrtf(dx*dx + dy*dy + dz*dz + 1e-6f);
            m2 = mi * mask[b*NN+j];
            lmax = fmaxf(lmax, m2*d);
        }
        dr[q] = d; m2r[q] = m2;
    }
    for (int q = t; q < 4096; q += 256) hist[q] = 0;
#pragma unroll
    for (int off = 32; off > 0; off >>= 1)
        lmax = fmaxf(lmax, __shfl_xor(lmax, off, 64));
    if (lane == 0) redw[wave] = lmax;
    if (t == 0) ncand = 0;
    __syncthreads();
    float rowmax = fmaxf(fmaxf(redw[0], redw[1]), fmaxf(redw[2], redw[3]));

    unsigned kreg[6];
#pragma unroll
    for (int q = 0; q < 6; q++) {
        int j = t + q*256;
        if (j < NN) {
            float dv = m2r[q]*dr[q] + (1.0f - m2r[q])*rowmax;   // >= 0
            d_adj[j] = dv;
            unsigned key = __float_as_uint(dv);
            kreg[q] = key;
            unsigned bkt = key >> 20;
            atomicAdd(&hist[((bkt & 15) << 8) | (bkt >> 4)], 1);
        } else kreg[q] = 0xFFFFFFFFu;
    }
    __syncthreads();

    find_bucket30(hist, 0, t, lane, wave, wsum, res);
    int B1 = res[0], nb1 = res[1];

    for (int q = t; q < 4096; q += 256) hist[q] = 0;
    __syncthreads();
#pragma unroll
    for (int q = 0; q < 6; q++) {
        if ((kreg[q] >> 20) == (unsigned)B1) {
            unsigned bkt = (kreg[q] >> 8) & 0xFFF;
            atomicAdd(&hist[((bkt & 15) << 8) | (bkt >> 4)], 1);
        }
    }
    __syncthreads();

    find_bucket30(hist, nb1, t, lane, wave, wsum, res);
    unsigned Bfull = ((unsigned)B1 << 12) | (unsigned)res[0];

#pragma unroll
    for (int q = 0; q < 6; q++) {
        if ((kreg[q] >> 8) <= Bfull) {
            int slot = atomicAdd(&ncand, 1);
            if (slot < 64) cand[slot] = t + q*256;
        }
    }
    __syncthreads();

    if (wave == 0) {
        int nc = min(ncand, 64);
        if (lane < nc) {
            int j = cand[lane];
            float v = d_adj[j];
            int rank = 0;
            for (int m = 0; m < nc; m++) {
                int jm = cand[m];
                float vm = d_adj[jm];
                rank += (vm < v || (vm == v && jm < j)) ? 1 : 0;
            }
            if (rank < KNB) {
                E_idx[row*KNB + rank] = j;
                D_nb[row*KNB + rank]  = v;
            }
        }
    }
}

// ---------------------------------------------------------------- W_edge transpose+cast: W_edge_t[n][k] bf16 (128x32)
__global__ __launch_bounds__(256) void wprep_edge_kernel(
    const float* __restrict__ W_edge, __hip_bfloat16* __restrict__ W_edge_t)
{
    int tid = blockIdx.x*256 + threadIdx.x;  // 4096
    int n = tid >> 5, k = tid & 31;
    W_edge_t[tid] = __float2bfloat16(W_edge[k*H + n]);
}

// ---------------------------------------------------------------- edge features -> E_ln (bf16), MFMA
// 2 nodes/block, wave w = m-tile w (16 edge rows). Lane computes its own A-frag
// (8 features), one K=32 MFMA per n-tile, LN via shfl butterflies on C-layout.
__global__ __launch_bounds__(256) void edge_kernel(
    const int* __restrict__ E_idx, const float* __restrict__ D_nb,
    const __hip_bfloat16* __restrict__ W_edge_t, const float* __restrict__ ln_g,
    const float* __restrict__ ln_b, __hip_bfloat16* __restrict__ E_ln)
{
    int g0 = blockIdx.x * 2;
    int t = threadIdx.x;
    int wave = t >> 6, lane = t & 63, lm = lane & 15, lq = lane >> 4;
    __shared__ __hip_bfloat16 Es[64*136];

    // ---- A-frag: 8 features for edge row (wave*16+lm), k-range lq*8..lq*8+7
    int row = wave*16 + lm;
    int rr = row < 60 ? row : 59;
    int node = g0 + (rr >= KNB ? 1 : 0);
    int e = node*KNB + (rr >= KNB ? rr - KNB : rr);
    float drel = (float)(E_idx[e] - (node % NN));
    float dnb  = D_nb[e];

    const float FR[8] = {1.f, 0.31622776601683794f, 0.1f, 0.031622776601683794f,
                         0.01f, 0.0031622776601683794f, 0.001f, 0.00031622776601683794f};
    union { s8v v; __hip_bfloat16 h[8]; } af;
    if (lq == 0) {
#pragma unroll
        for (int j = 0; j < 8; j++) af.h[j] = __float2bfloat16(cosf(drel*FR[j]));
    } else if (lq == 1) {
#pragma unroll
        for (int j = 0; j < 8; j++) af.h[j] = __float2bfloat16(sinf(drel*FR[j]));
    } else {
        int f0 = (lq-2)*8;
#pragma unroll
        for (int j = 0; j < 8; j++) {
            float mu = (20.0f/15.0f) * (float)(f0+j);
            float z = (dnb - mu) * 0.8f;
            af.h[j] = __float2bfloat16(expf(-z*z));
        }
    }

    // ---- B-frags (8 n-tiles) from global, 16B each, L1-resident
    f4v acc[8];
#pragma unroll
    for (int nt = 0; nt < 8; nt++) {
        s8v bf = *(const s8v*)&W_edge_t[(nt*16+lm)*32 + lq*8];
        f4v z = {0.f,0.f,0.f,0.f};
        acc[nt] = __builtin_amdgcn_mfma_f32_16x16x32_bf16(af.v, bf, z, 0,0,0);
    }

    // ---- LN stats in-register: lane holds rows lq*4+r, cols nt*16+lm
    float gv[8], bv[8];
#pragma unroll
    for (int nt = 0; nt < 8; nt++) { gv[nt] = ln_g[nt*16+lm]; bv[nt] = ln_b[nt*16+lm]; }
#pragma unroll
    for (int r = 0; r < 4; r++) {
        float sm = 0.f, sq = 0.f;
#pragma unroll
        for (int nt = 0; nt < 8; nt++) { float x = acc[nt][r]; sm += x; sq += x*x; }
#pragma unroll
        for (int m = 1; m < 16; m <<= 1) {
            sm += __shfl_xor(sm, m, 64);
            sq += __shfl_xor(sq, m, 64);
        }
        float mu = sm * (1.0f/H);
        float rs = rsqrtf(sq*(1.0f/H) - mu*mu + LN_EPS);
        int erow = wave*16 + lq*4 + r;
#pragma unroll
        for (int nt = 0; nt < 8; nt++)
            Es[erow*136 + nt*16 + lm] =
                __float2bfloat16(gv[nt]*(acc[nt][r]-mu)*rs + bv[nt]);
    }
    __syncthreads();

    // ---- coalesced store of 60 valid rows
    __hip_bfloat16* dst = E_ln + (size_t)g0*KNB*H;
    for (int q = t; q < 960; q += 256) {
        int r = q >> 4, c8 = (q & 15) * 8;
        *(s8v*)&dst[r*H + c8] = *(const s8v*)&Es[r*136 + c8];
    }
}

// ---------------------------------------------------------------- W_v transpose+cast: Wv_t[n][k] bf16
__global__ __launch_bounds__(256) void wprep_v_kernel(
    const float* __restrict__ W_v, __hip_bfloat16* __restrict__ Wv_t)
{
    int tid = blockIdx.x*256 + threadIdx.x;  // 131072
    int n = tid & 127, k = tid >> 7;
    Wv_t[(size_t)n*NODE_FEAT + k] = __float2bfloat16(W_v[k*H + n]);
}

// ---------------------------------------------------------------- h_V = V @ W_v + b_v  (MFMA)
// + fused layer-0 node projections P = hv @ [Wq|Wk_bot|Wv_bot]
__global__ __launch_bounds__(256) void hv_init_kernel(
    const float* __restrict__ V, const __hip_bfloat16* __restrict__ Wv_t,
    const float* __restrict__ b_v, float* __restrict__ hv,
    const __hip_bfloat16* __restrict__ Wn_t, float* __restrict__ P)
{
    int row0 = blockIdx.x * 16;
    int t = threadIdx.x;
    int wave = t >> 6, lane = t & 63, lm = lane & 15, lq = lane >> 4;
    __shared__ __hip_bfloat16 Vs[16*1032];   // pitch 1032 (2-way bank alias only)
    __shared__ __hip_bfloat16 zs[16*136];

    for (int q = t; q < 4096; q += 256) {
        int r = q >> 8, c4 = (q & 255) * 4;
        float4 v4 = *(const float4*)&V[(size_t)(row0+r)*NODE_FEAT + c4];
        __hip_bfloat16* d = &Vs[r*1032 + c4];
        d[0] = __float2bfloat16(v4.x);
        d[1] = __float2bfloat16(v4.y);
        d[2] = __float2bfloat16(v4.z);
        d[3] = __float2bfloat16(v4.w);
    }
    __syncthreads();

#pragma unroll
    for (int ntl = 0; ntl < 2; ntl++) {
        int nt = wave*2 + ntl;
        f4v acc = {0.f,0.f,0.f,0.f};
        for (int ks = 0; ks < 32; ks++) {
            s8v af = *(const s8v*)&Vs[lm*1032 + ks*32 + lq*8];
            s8v bf = *(const s8v*)&Wv_t[(size_t)(nt*16+lm)*NODE_FEAT + ks*32 + lq*8];
            acc = __builtin_amdgcn_mfma_f32_16x16x32_bf16(af, bf, acc, 0,0,0);
        }
        int cc = nt*16 + lm;
        float b = b_v[cc];
#pragma unroll
        for (int r = 0; r < 4; r++) {
            int rr = lq*4 + r;
            float v = acc[r] + b;
            hv[(size_t)(row0+rr)*H + cc] = v;
            zs[rr*136+cc] = __float2bfloat16(v);
        }
    }
    __syncthreads();

    for (int ntl = 0; ntl < 6; ntl++) {
        int nt = wave*6 + ntl;
        f4v acc = {0.f,0.f,0.f,0.f};
#pragma unroll
        for (int ks = 0; ks < 4; ks++) {
            s8v af = *(const s8v*)&zs[lm*136 + ks*32 + lq*8];
            s8v bf = *(const s8v*)&Wn_t[(size_t)(nt*16+lm)*H + ks*32 + lq*8];
            acc = __builtin_amdgcn_mfma_f32_16x16x32_bf16(af, bf, acc, 0,0,0);
        }
        int cc = nt*16 + lm;
#pragma unroll
        for (int r = 0; r < 4; r++)
            P[(size_t)(row0 + lq*4 + r)*384 + cc] = acc[r];
    }
}

// ---------------------------------------------------------------- fold W_e into per-layer edge K/V
__global__ __launch_bounds__(128) void wprep_kv_kernel(
    const float* __restrict__ W_e, const float* __restrict__ b_e,
    const float* __restrict__ Wk, const float* __restrict__ Wv,
    __hip_bfloat16* __restrict__ Wt_kv, float* __restrict__ bias_kv)
{
    int l = blockIdx.x >> 8;
    int n = blockIdx.x & 255;
    int t = threadIdx.x;             // t = k (0..127)
    int col = n & 127;
    const float* W = (n < 128) ? (Wk + l*2*H*H) : (Wv + l*2*H*H);
    __shared__ float wcol[128];
    wcol[t] = W[t*H + col];          // rows 0..127 = h_E block
    __syncthreads();
    float a = 0.f;
    for (int c = 0; c < H; c += 4) {
        float4 we = *(const float4*)&W_e[t*H + c];
        a += we.x*wcol[c] + we.y*wcol[c+1] + we.z*wcol[c+2] + we.w*wcol[c+3];
    }
    Wt_kv[(size_t)(l*256 + n)*H + t] = __float2bfloat16(a);
    if (t == 0) {
        float bsum = 0.f;
        for (int c = 0; c < H; c++) bsum += b_e[c]*wcol[c];
        bias_kv[l*256 + n] = bsum;
    }
}

// ---------------------------------------------------------------- transpose+cast weights to bf16 [n][k]
__global__ __launch_bounds__(256) void wprep_post_kernel(
    const float* __restrict__ Wo, const float* __restrict__ Wf1,
    const float* __restrict__ Wf2, const float* __restrict__ Wq,
    const float* __restrict__ Wk, const float* __restrict__ Wv,
    __hip_bfloat16* __restrict__ Wo_t, __hip_bfloat16* __restrict__ Wf1_t,
    __hip_bfloat16* __restrict__ Wf2_t, __hip_bfloat16* __restrict__ Wn_t)
{
    int id = blockIdx.x*256 + threadIdx.x;   // < 786432
    int l = id / 196608;
    int r = id - l*196608;
    float v; __hip_bfloat16* dst;
    if (r < 16384) {
        int n = r >> 7, k = r & 127;
        v = Wo[l*16384 + k*128 + n];
        dst = Wo_t + l*16384 + r;
    } else if (r < 81920) {
        int rr = r - 16384;
        int n = rr >> 7, k = rr & 127;
        v = Wf1[l*65536 + k*512 + n];
        dst = Wf1_t + l*65536 + rr;
    } else if (r < 147456) {
        int rr = r - 81920;
        int n = rr >> 9, k = rr & 511;
        v = Wf2[l*65536 + k*128 + n];
        dst = Wf2_t + l*65536 + rr;
    } else {
        int rr = r - 147456;
        int n = rr >> 7, k = rr & 127;
        if (n < 128)      v = Wq[l*16384 + k*128 + n];
        else if (n < 256) v = Wk[l*32768 + (128+k)*128 + (n-128)];
        else              v = Wv[l*32768 + (128+k)*128 + (n-256)];
        dst = Wn_t + l*49152 + rr;
    }
    *dst = __float2bfloat16(v);
}

// ---------------------------------------------------------------- attention: 2 nodes/block
__global__ __launch_bounds__(256) void attn_kernel(
    const __hip_bfloat16* __restrict__ E_ln, const __hip_bfloat16* __restrict__ Wt,
    const float* __restrict__ bias_kv,
    float* __restrict__ P, const int* __restrict__ E_idx,
    const float* __restrict__ mask)
{
    int g0 = blockIdx.x * 2;
    int t = threadIdx.x;
    __shared__ __hip_bfloat16 Ae[64*136];     // A tile, pitch 136 bf16
    __shared__ __hip_bfloat16 KVs[60*264];    // K|V rows, pitch 264 bf16
    __shared__ float Qs[2*H];
    __shared__ float att_s[2*120];
    __shared__ float mv_s[60];
    __shared__ int   nbr[60];

    const __hip_bfloat16* hebase = E_ln + (size_t)g0*KNB*H;
    for (int q = t; q < 960; q += 256) {
        int r = q >> 4, c8 = (q & 15) * 8;
        *(s8v*)&Ae[r*136 + c8] = *(const s8v*)&hebase[r*H + c8];
    }
    if (t < 60) {
        int gn = g0 + t/30;
        int b = gn / NN;
        int idx = E_idx[gn*KNB + (t%30)];
        nbr[t]  = b*NN + idx;
        mv_s[t] = mask[gn] * mask[b*NN + idx];
    }
    {
        int node = t >> 7, c = t & 127;
        Qs[t] = P[(size_t)(g0+node)*384 + c];
    }
    __syncthreads();

    {
        int wave = t >> 6, lane = t & 63;
        int lm = lane & 15, lq = lane >> 4;
        int cb = wave*64 + lm;
        const __hip_bfloat16* wb = Wt + (size_t)cb*H + lq*8;
        s8v bfr[4][4];
#pragma unroll
        for (int nt = 0; nt < 4; nt++)
#pragma unroll
            for (int ks = 0; ks < 4; ks++)
                bfr[nt][ks] = *(const s8v*)(wb + nt*16*H + ks*32);
        float bias0 = bias_kv[cb], bias1 = bias_kv[cb+16];
        float bias2 = bias_kv[cb+32], bias3 = bias_kv[cb+48];
#pragma unroll
        for (int mt = 0; mt < 4; mt++) {
            f4v a0 = {0.f,0.f,0.f,0.f}, a1 = a0, a2 = a0, a3 = a0;
#pragma unroll
            for (int ks = 0; ks < 4; ks++) {
                s8v af = *(const s8v*)&Ae[(mt*16+lm)*136 + ks*32 + lq*8];
                a0 = __builtin_amdgcn_mfma_f32_16x16x32_bf16(af, bfr[0][ks], a0, 0,0,0);
                a1 = __builtin_amdgcn_mfma_f32_16x16x32_bf16(af, bfr[1][ks], a1, 0,0,0);
                a2 = __builtin_amdgcn_mfma_f32_16x16x32_bf16(af, bfr[2][ks], a2, 0,0,0);
                a3 = __builtin_amdgcn_mfma_f32_16x16x32_bf16(af, bfr[3][ks], a3, 0,0,0);
            }
            int rbase = mt*16 + lq*4;
#pragma unroll
            for (int r = 0; r < 4; r++) {
                int row = rbase + r;
                if (row < 60) {
                    const float* pb = P + (size_t)nbr[row]*384 + 128 + cb;
                    KVs[row*264 + cb     ] = __float2bfloat16(a0[r] + bias0 + pb[0]);
                    KVs[row*264 + cb + 16] = __float2bfloat16(a1[r] + bias1 + pb[16]);
                    KVs[row*264 + cb + 32] = __float2bfloat16(a2[r] + bias2 + pb[32]);
                    KVs[row*264 + cb + 48] = __float2bfloat16(a3[r] + bias3 + pb[48]);
                }
            }
        }
    }
    __syncthreads();

    if (t < 240) {
        int node = t / 120, tt = t % 120;
        int h = tt / 30, kk = tt % 30;
        int r = node*30 + kk;
        const uint4* kp = (const uint4*)&KVs[r*264 + h*32];
        const float* qp = &Qs[node*128 + h*32];
        float a = 0.f;
#pragma unroll
        for (int j = 0; j < 4; j++) {
            uint4 u = kp[j];
            const float* q8 = qp + j*8;
            a += q8[0]*bf_lo(u.x) + q8[1]*bf_hi(u.x)
               + q8[2]*bf_lo(u.y) + q8[3]*bf_hi(u.y)
               + q8[4]*bf_lo(u.z) + q8[5]*bf_hi(u.z)
               + q8[6]*bf_lo(u.w) + q8[7]*bf_hi(u.w);
        }
        att_s[node*120 + h*30 + kk] =
            (mv_s[r] > 0.f) ? a*0.17677669529663687f : -3.4028235e38f;
    }
    __syncthreads();
    if (t < 8) {
        int node = t >> 2, h = t & 3;
        float* ap = &att_s[node*120 + h*30];
        const float* mp = &mv_s[node*30];
        float mx = -3.4028235e38f;
        for (int kk = 0; kk < KNB; kk++) mx = fmaxf(mx, ap[kk]);
        float s = 0.f;
        for (int kk = 0; kk < KNB; kk++) s += __expf(ap[kk]-mx);
        float inv = 1.0f/s;
        for (int kk = 0; kk < KNB; kk++) ap[kk] = __expf(ap[kk]-mx)*inv*mp[kk];
    }
    __syncthreads();

    {
        int node = t >> 7, c = t & 127;
        const float* ap = &att_s[node*120 + (c>>5)*30];
        float u = 0.f;
        for (int kk = 0; kk < KNB; kk++)
            u += ap[kk] * __bfloat162float(KVs[(node*30+kk)*264 + 128 + c]);
        P[(size_t)(g0+node)*384 + c] = u;
    }
}

// ---------------------------------------------------------------- Wo + LN1 + FF + LN2 (+ next-layer node proj), MFMA
__global__ __launch_bounds__(256) void post_kernel(
    float* __restrict__ hv, float* __restrict__ P,
    const float* __restrict__ mask,
    const __hip_bfloat16* __restrict__ Wo_t,
    const float* __restrict__ ln1g, const float* __restrict__ ln1b,
    const float* __restrict__ ln2g, const float* __restrict__ ln2b,
    const __hip_bfloat16* __restrict__ Wf1_t, const float* __restrict__ bf1,
    const __hip_bfloat16* __restrict__ Wf2_t, const float* __restrict__ bf2,
    const __hip_bfloat16* __restrict__ Wn_t)
{
    int row0 = blockIdx.x * 16;
    int t = threadIdx.x;
    int wave = t >> 6, lane = t & 63, lm = lane & 15, lq = lane >> 4;

    __shared__ __hip_bfloat16 Aus[16*136];   // upd bf16
    __shared__ float xs[16*132];             // fp32 working rows
    __shared__ __hip_bfloat16 ys[16*136];    // LN1 out bf16
    __shared__ __hip_bfloat16 t1[16*520];    // relu(FF1) bf16
    __shared__ __hip_bfloat16 zs[16*136];    // hv_out bf16
    __shared__ float ps[256], pq[256];
    __shared__ float mu_s[16], rs_s[16];

    for (int q = t; q < 2048; q += 256) {
        int r = q >> 7, c = q & 127;
        Aus[r*136+c] = __float2bfloat16(P[(size_t)(row0+r)*384 + c]);
    }
    __syncthreads();

    for (int ntl = 0; ntl < 2; ntl++) {
        int nt = wave*2 + ntl;
        f4v acc = {0.f,0.f,0.f,0.f};
#pragma unroll
        for (int ks = 0; ks < 4; ks++) {
            s8v af = *(const s8v*)&Aus[lm*136 + ks*32 + lq*8];
            s8v bf = *(const s8v*)&Wo_t[(nt*16+lm)*128 + ks*32 + lq*8];
            acc = __builtin_amdgcn_mfma_f32_16x16x32_bf16(af, bf, acc, 0,0,0);
        }
        int cc = nt*16 + lm;
#pragma unroll
        for (int r = 0; r < 4; r++) {
            int rr = lq*4 + r;
            xs[rr*132+cc] = hv[(size_t)(row0+rr)*128 + cc] + acc[r];
        }
    }
    __syncthreads();

    {
        int r = t >> 4, s = t & 15;
        float4 a = *(const float4*)&xs[r*132 + s*8];
        float4 b = *(const float4*)&xs[r*132 + s*8 + 4];
        ps[t] = a.x+a.y+a.z+a.w + b.x+b.y+b.z+b.w;
        pq[t] = a.x*a.x+a.y*a.y+a.z*a.z+a.w*a.w + b.x*b.x+b.y*b.y+b.z*b.z+b.w*b.w;
    }
    __syncthreads();
    if (t < 16) {
        float sm = 0.f, sq = 0.f;
        for (int s = 0; s < 16; s++) { sm += ps[t*16+s]; sq += pq[t*16+s]; }
        float mu = sm*(1.0f/H);
        mu_s[t] = mu;
        rs_s[t] = rsqrtf(sq*(1.0f/H) - mu*mu + LN_EPS);
    }
    __syncthreads();
    for (int q = t; q < 2048; q += 256) {
        int r = q >> 7, c = q & 127;
        float v = ln1g[c]*(xs[r*132+c]-mu_s[r])*rs_s[r] + ln1b[c];
        xs[r*132+c] = v;
        ys[r*136+c] = __float2bfloat16(v);
    }
    __syncthreads();

    for (int ntl = 0; ntl < 8; ntl++) {
        int nt = wave*8 + ntl;
        f4v acc = {0.f,0.f,0.f,0.f};
#pragma unroll
        for (int ks = 0; ks < 4; ks++) {
            s8v af = *(const s8v*)&ys[lm*136 + ks*32 + lq*8];
            s8v bf = *(const s8v*)&Wf1_t[(size_t)(nt*16+lm)*128 + ks*32 + lq*8];
            acc = __builtin_amdgcn_mfma_f32_16x16x32_bf16(af, bf, acc, 0,0,0);
        }
        int cc = nt*16 + lm;
        float b = bf1[cc];
#pragma unroll
        for (int r = 0; r < 4; r++)
            t1[(lq*4+r)*520 + cc] = __float2bfloat16(fmaxf(acc[r]+b, 0.f));
    }
    __syncthreads();

    for (int ntl = 0; ntl < 2; ntl++) {
        int nt = wave*2 + ntl;
        f4v acc = {0.f,0.f,0.f,0.f};
#pragma unroll
        for (int ks = 0; ks < 16; ks++) {
            s8v af = *(const s8v*)&t1[lm*520 + ks*32 + lq*8];
            s8v bf = *(const s8v*)&Wf2_t[(size_t)(nt*16+lm)*512 + ks*32 + lq*8];
            acc = __builtin_amdgcn_mfma_f32_16x16x32_bf16(af, bf, acc, 0,0,0);
        }
        int cc = nt*16 + lm;
        float b = bf2[cc];
#pragma unroll
        for (int r = 0; r < 4; r++) {
            int rr = lq*4 + r;
            xs[rr*132+cc] = xs[rr*132+cc] + acc[r] + b;
        }
    }
    __syncthreads();

    {
        int r = t >> 4, s = t & 15;
        float4 a = *(const float4*)&xs[r*132 + s*8];
        float4 b = *(const float4*)&xs[r*132 + s*8 + 4];
        ps[t] = a.x+a.y+a.z+a.w + b.x+b.y+b.z+b.w;
        pq[t] = a.x*a.x+a.y*a.y+a.z*a.z+a.w*a.w + b.x*b.x+b.y*b.y+b.z*b.z+b.w*b.w;
    }
    __syncthreads();
    if (t < 16) {
        float sm = 0.f, sq = 0.f;
        for (int s = 0; s < 16; s++) { sm += ps[t*16+s]; sq += pq[t*16+s]; }
        float mu = sm*(1.0f/H);
        mu_s[t] = mu;
        rs_s[t] = rsqrtf(sq*(1.0f/H) - mu*mu + LN_EPS);
    }
    __syncthreads();
    for (int q = t; q < 2048; q += 256) {
        int r = q >> 7, c = q & 127;
        float v = mask[row0+r]*(ln2g[c]*(xs[r*132+c]-mu_s[r])*rs_s[r] + ln2b[c]);
        hv[(size_t)(row0+r)*128 + c] = v;
        zs[r*136+c] = __float2bfloat16(v);
    }
    __syncthreads();

    if (Wn_t) {
        for (int ntl = 0; ntl < 6; ntl++) {
            int nt = wave*6 + ntl;
            f4v acc = {0.f,0.f,0.f,0.f};
#pragma unroll
            for (int ks = 0; ks < 4; ks++) {
                s8v af = *(const s8v*)&zs[lm*136 + ks*32 + lq*8];
                s8v bf = *(const s8v*)&Wn_t[(size_t)(nt*16+lm)*128 + ks*32 + lq*8];
                acc = __builtin_amdgcn_mfma_f32_16x16x32_bf16(af, bf, acc, 0,0,0);
            }
            int cc = nt*16 + lm;
#pragma unroll
            for (int r = 0; r < 4; r++)
                P[(size_t)(row0 + lq*4 + r)*384 + cc] = acc[r];
        }
    }
}

// ---------------------------------------------------------------- final projection
__global__ __launch_bounds__(64) void out_kernel(
    const float* __restrict__ hv, const float* __restrict__ W_out,
    const float* __restrict__ b_out, float* __restrict__ out)
{
    int row = blockIdx.x;
    int t = threadIdx.x;
    float a = hv[row*H+t]*W_out[t] + hv[row*H+t+64]*W_out[t+64];
#pragma unroll
    for (int s = 32; s > 0; s >>= 1) a += __shfl_down(a, s, 64);
    if (t == 0) out[row] = a + b_out[0];
}

// ---------------------------------------------------------------- launch
extern "C" void kernel_launch(void* const* d_in, const int* in_sizes, int n_in,
                              void* d_out, int out_size, void* d_ws, size_t ws_size,
                              hipStream_t stream)
{
    const float* X      = (const float*)d_in[0];
    const float* V      = (const float*)d_in[1];
    const float* mask   = (const float*)d_in[2];
    const float* W_v    = (const float*)d_in[3];
    const float* b_v    = (const float*)d_in[4];
    const float* W_e    = (const float*)d_in[5];
    const float* b_e    = (const float*)d_in[6];
    const float* W_edge = (const float*)d_in[7];
    const float* ln_e_g = (const float*)d_in[8];
    const float* ln_e_b = (const float*)d_in[9];
    const float* Wq     = (const float*)d_in[10];
    const float* Wk     = (const float*)d_in[11];
    const float* Wv_a   = (const float*)d_in[12];
    const float* Wo     = (const float*)d_in[13];
    const float* ln1g   = (const float*)d_in[14];
    const float* ln1b   = (const float*)d_in[15];
    const float* ln2g   = (const float*)d_in[16];
    const float* ln2b   = (const float*)d_in[17];
    const float* Wf1    = (const float*)d_in[18];
    const float* bf1    = (const float*)d_in[19];
    const float* Wf2    = (const float*)d_in[20];
    const float* bf2    = (const float*)d_in[21];
    const float* W_out  = (const float*)d_in[22];
    const float* b_out  = (const float*)d_in[23];
    float* out = (float*)d_out;

    // workspace layout:
    //   E_idx    :        0 ..   720,000   (int 180000)
    //   D_nb     :  720,000 .. 1,440,000   (f32 180000)
    //   E_ln     : 1,440,000 .. 47,520,000 (bf16 180000*128)
    //   hv       : 47,520,000 .. 50,592,000 (f32 6000*128, in-place across layers)
    //   Wt_kv    : 50,592,000 .. 50,854,144 (bf16 4*256*128)
    //   bias_kv  : 50,854,144 .. 50,858,240 (f32 4*256)
    //   Wn_t     : 50,858,240 .. 51,251,456 (bf16 4*384*128)
    //   Wo_t     : 51,251,456 .. 51,382,528 (bf16 4*128*128)
    //   Wf1_t    : 51,382,528 .. 51,906,816 (bf16 4*512*128)
    //   Wf2_t    : 51,906,816 .. 52,431,104 (bf16 4*128*512)
    //   Wv_t     : 52,431,104 .. 52,693,248 (bf16 128*1024)
    //   W_edge_t : 52,693,248 .. 52,701,440 (bf16 128*32)
    //   P        : 53,664,000 .. 62,880,000 (f32 6000*384: Q|Pk|Pv)
    char* ws = (char*)d_ws;
    int*            E_idx    = (int*)ws;
    float*          D_nb     = (float*)(ws + 720000);
    __hip_bfloat16* E_ln     = (__hip_bfloat16*)(ws + 1440000);
    float*          hv       = (float*)(ws + 47520000);
    __hip_bfloat16* Wt_kv    = (__hip_bfloat16*)(ws + 50592000);
    float*          bias_kv  = (float*)(ws + 50854144);
    __hip_bfloat16* Wn_t     = (__hip_bfloat16*)(ws + 50858240);
    __hip_bfloat16* Wo_t     = (__hip_bfloat16*)(ws + 51251456);
    __hip_bfloat16* Wf1_t    = (__hip_bfloat16*)(ws + 51382528);
    __hip_bfloat16* Wf2_t    = (__hip_bfloat16*)(ws + 51906816);
    __hip_bfloat16* Wv_t     = (__hip_bfloat16*)(ws + 52431104);
    __hip_bfloat16* W_edge_t = (__hip_bfloat16*)(ws + 52693248);
    float*          P        = (float*)(ws + 53664000);

    topk_kernel<<<NROWS, 256, 0, stream>>>(X, mask, E_idx, D_nb);
    wprep_edge_kernel<<<16, 256, 0, stream>>>(W_edge, W_edge_t);
    edge_kernel<<<NROWS/2, 256, 0, stream>>>(E_idx, D_nb, W_edge_t, ln_e_g, ln_e_b, E_ln);
    wprep_kv_kernel<<<1024, 128, 0, stream>>>(W_e, b_e, Wk, Wv_a, Wt_kv, bias_kv);
    wprep_post_kernel<<<3072, 256, 0, stream>>>(Wo, Wf1, Wf2, Wq, Wk, Wv_a,
                                                Wo_t, Wf1_t, Wf2_t, Wn_t);
    wprep_v_kernel<<<512, 256, 0, stream>>>(W_v, Wv_t);
    hv_init_kernel<<<NROWS/16, 256, 0, stream>>>(V, Wv_t, b_v, hv, Wn_t, P);

    for (int l = 0; l < 4; l++) {
        attn_kernel<<<NROWS/2, 256, 0, stream>>>(
            E_ln, Wt_kv + (size_t)l*256*H, bias_kv + l*256, P, E_idx, mask);
        post_kernel<<<NROWS/16, 256, 0, stream>>>(
            hv, P, mask, Wo_t + l*16384,
            ln1g + l*H, ln1b + l*H, ln2g + l*H, ln2b + l*H,
            Wf1_t + (size_t)l*65536, bf1 + l*FFH,
            Wf2_t + (size_t)l*65536, bf2 + l*H,
            (l < 3) ? (Wn_t + (size_t)(l+1)*49152) : (const __hip_bfloat16*)nullptr);
    }
    out_kernel<<<NROWS, 64, 0, stream>>>(hv, W_out, b_out, out);
}